// Round 9
// baseline (485.530 us; speedup 1.0000x reference)
//
#include <hip/hip_runtime.h>

#define NN 50000
#define EE 500000
#define BB 64
#define TT 50
#define FN 128
#define FS 64
#define HD 64
#define ETOT (EE + NN)
#define NPAD 50176   // 1024*49, k_scan guard-free

typedef __attribute__((ext_vector_type(8))) short short8v;
typedef __attribute__((ext_vector_type(4))) short short4v;
typedef __attribute__((ext_vector_type(4))) float f4v;

__device__ __forceinline__ float b2f(short u){
  union { unsigned int i; float f; } v; v.i = ((unsigned int)(unsigned short)u) << 16; return v.f;
}
__device__ __forceinline__ short f2b(float f){
  union { float f; unsigned int i; } v; v.f = f;
  unsigned int x = v.i;
  return (short)((x + 0x7fffu + ((x >> 16) & 1u)) >> 16);
}
__device__ __forceinline__ f4v mfma16(short8v a, short8v b, f4v c){
  return __builtin_amdgcn_mfma_f32_16x16x32_bf16(a, b, c, 0, 0, 0);
}
__device__ __forceinline__ float frcp(float x){ return __builtin_amdgcn_rcpf(x); }
__device__ __forceinline__ float fsig(float x){ return frcp(1.f + __expf(-x)); }
__device__ __forceinline__ float ftanh(float x){ return 1.f - 2.f*frcp(1.f + __expf(2.f*x)); }

// ---------------- input dtype detect + convert to bf16 arena ----------------
constexpr int SEG_CUM[25] = {0, 6400000, 6604800, 6637568, 6637824, 6638080,
  6638336, 6654720, 6654784, 6654848, 6654912, 6671296, 6687680, 6687936,
  6688192, 6704576, 6720960, 6721216, 6721472, 6770624, 6771008, 6787392,
  6787520, 6787904, 6787906};
#define ARENA_VEC (6787904/8)

struct Ptrs { const void* p[24]; };

__global__ __launch_bounds__(256) void k_detect(const unsigned short* x16, int* flag){
  __shared__ int cnt;
  if (threadIdx.x == 0) cnt = 0;
  __syncthreads();
  int c = 0;
  for (int i = threadIdx.x; i < 2048; i += 256){
    unsigned short v = x16[2*i];         // even shorts: f32 low-halves (random) vs bf16 values
    int e = (v >> 7) & 0xFF;
    if (e >= 64 && e < 160) c++;
  }
  atomicAdd(&cnt, c);
  __syncthreads();
  if (threadIdx.x == 0) *flag = (cnt >= 1536) ? 1 : 0;   // 1 = inputs are bf16
}

__global__ __launch_bounds__(256) void k_cvt(Ptrs P, short* arena, const int* flag){
  bool isb = (*flag != 0);
  int idx = blockIdx.x*256 + threadIdx.x;
  for (int v = idx; v < ARENA_VEC; v += gridDim.x*256){
    int i = v*8;
    int s = 0;
#pragma unroll
    for (int k = 1; k < 24; ++k) if (i >= SEG_CUM[k]) s = k;
    int j = i - SEG_CUM[s];
    short8v o;
    if (isb){
      o = *(const short8v*)((const short*)P.p[s] + j);
    } else {
      const float* f = (const float*)P.p[s] + j;
      f4v lo = *(const f4v*)f;
      f4v hi = *(const f4v*)(f + 4);
#pragma unroll
      for (int q = 0; q < 4; ++q){ o[q] = f2b(lo[q]); o[4+q] = f2b(hi[q]); }
    }
    *(short8v*)(arena + i) = o;
  }
  if (blockIdx.x == 0 && threadIdx.x == 0){
    for (int j = 0; j < 2; ++j)
      arena[6787904 + j] = isb ? ((const short*)P.p[23])[j] : f2b(((const float*)P.p[23])[j]);
  }
}

// ---------------- CSR build ----------------
__global__ __launch_bounds__(256) void k_init(int* deg, float* pool){
  int i = blockIdx.x*256 + threadIdx.x;
  if (i < NN) deg[i] = 1;            // self loop
  else if (i < NPAD) deg[i] = 0;     // pad for guard-free scan
  if (i < BB*HD) pool[i] = 0.f;
}

__global__ __launch_bounds__(256) void k_count(const int* ei, int* deg){
  int e = blockIdx.x*256 + threadIdx.x;
  if (e < EE) atomicAdd(&deg[ei[EE + e]], 1);
}

// single-pass scan: 49 values/thread held in REGISTERS (guard-free, unrolled)
__global__ __launch_bounds__(1024) void k_scan(const int* __restrict__ deg, int* __restrict__ off){
  __shared__ int buf[1024];
  int tid = threadIdx.x;
  int start = tid*49;
  int v[49];
#pragma unroll
  for (int j = 0; j < 49; ++j) v[j] = deg[start + j];
  int s = 0;
#pragma unroll
  for (int j = 0; j < 49; ++j) s += v[j];
  buf[tid] = s;
  __syncthreads();
  for (int st = 1; st < 1024; st <<= 1){
    int t = (tid >= st) ? buf[tid - st] : 0;
    __syncthreads();
    buf[tid] += t;
    __syncthreads();
  }
  int run = buf[tid] - s;            // exclusive base for this chunk
#pragma unroll
  for (int j = 0; j < 49; ++j){
    int i = start + j;
    if (i < NN) off[i] = run;
    run += v[j];
  }
  if (tid == 1023) off[NN] = run;
}

__global__ __launch_bounds__(256) void k_self(const int* off, int* cur, int* csr){
  int v = blockIdx.x*256 + threadIdx.x;
  if (v < NN){ int o = off[v]; csr[o] = v; cur[v] = o + 1; }
}

__global__ __launch_bounds__(256) void k_scatter(const int* ei, int* cur, int* csr){
  int e = blockIdx.x*256 + threadIdx.x;
  if (e < EE){
    int d = ei[EE + e];
    int pos = atomicAdd(&cur[d], 1);
    csr[pos] = ei[e];
  }
}

// ---------------- GAT layer 1: h1c = x @ W1^T, CHUNK-major [8][NN][32] ----------------
__global__ __launch_bounds__(256) void k_gemm1(const short* __restrict__ x, const short* __restrict__ W, short* __restrict__ h1c){
  int wv = blockIdx.x*4 + (threadIdx.x >> 6);
  if (wv >= NN/16) return;
  int l = threadIdx.x & 63;
  int row = wv*16 + (l & 15);
  int koff = (l >> 4)*8;
  short8v a[4];
#pragma unroll
  for (int k = 0; k < 4; ++k) a[k] = *(const short8v*)(x + (size_t)row*128 + k*32 + koff);
  int r0 = wv*16 + (l >> 4)*4;
#pragma unroll
  for (int nt = 0; nt < 16; ++nt){
    f4v acc = {0.f,0.f,0.f,0.f};
#pragma unroll
    for (int k = 0; k < 4; ++k){
      short8v b = *(const short8v*)(W + (size_t)(nt*16 + (l & 15))*128 + k*32 + koff);
      acc = mfma16(a[k], b, acc);
    }
    int col = nt*16 + (l & 15);
    size_t cb = (size_t)(col >> 5)*NN*32 + (col & 31);
#pragma unroll
    for (int r = 0; r < 4; ++r) h1c[cb + (size_t)(r0 + r)*32] = f2b(acc[r]);
  }
}

__global__ __launch_bounds__(256) void k_score1(const short* __restrict__ h1c, const short* __restrict__ as, const short* __restrict__ ad, float* a1s, float* a1d){
  int i = blockIdx.x*256 + threadIdx.x;
  if (i >= NN*4) return;
  int n = i >> 2, h = i & 3;
  float ss = 0.f, sd = 0.f;
#pragma unroll
  for (int cc = 0; cc < 2; ++cc){
    const short* hb = h1c + (size_t)(h*2 + cc)*NN*32 + (size_t)n*32;
#pragma unroll
    for (int q = 0; q < 4; ++q){
      short8v hv = *(const short8v*)(hb + q*8);
      short8v sv = *(const short8v*)(as + h*64 + cc*32 + q*8);
      short8v dv = *(const short8v*)(ad + h*64 + cc*32 + q*8);
#pragma unroll
      for (int j = 0; j < 8; ++j){ float v = b2f(hv[j]); ss += v*b2f(sv[j]); sd += v*b2f(dv[j]); }
    }
  }
  a1s[i] = ss; a1d[i] = sd;
}

// ---- agg layer 1: chunk = bid&7 -> XCD-resident 3.2MB h1 slice; wave per (dst, chunk).
// PhaseA: lane=edge, ONE head's online softmax. PhaseB: 8 edges/iter (lane = edge x 4ch).
__global__ __launch_bounds__(256) void k_agg1(const int* __restrict__ off, const int* __restrict__ csr,
                                              const short* __restrict__ h1c, const float* __restrict__ a1s,
                                              const float* __restrict__ a1d, const short* __restrict__ b1,
                                              short* __restrict__ g1){
  __shared__ int   s_u[4][64];
  __shared__ float s_p[4][64];
  int bid = blockIdx.x;
  int c = bid & 7;                       // chunk == XCD affinity
  int v = (bid >> 3)*4 + (threadIdx.x >> 6);
  if (v >= NN) return;
  int w = threadIdx.x >> 6;
  int l = threadIdx.x & 63;
  int hh = c >> 1;                       // the single head this chunk belongs to
  int ch4 = (l & 7)*4;
  int ei = l >> 3;
  const short* h1b = h1c + (size_t)c*NN*32;
  float adst = a1d[v*4 + hh];
  int e0 = off[v], e1 = off[v+1];
  float m = -1e30f, s = 0.f;
  f4v acc = {0.f,0.f,0.f,0.f};

  for (int base = e0; base < e1; base += 64){
    int nc = e1 - base; if (nc > 64) nc = 64;
    int u = (l < nc) ? csr[base + l] : v;
    float ef = -1e30f;
    if (l < nc){
      float t = a1s[u*4 + hh] + adst;
      ef = (t >= 0.f) ? t : 0.2f*t;
    }
    float cm = ef;
#pragma unroll
    for (int st = 1; st < 64; st <<= 1) cm = fmaxf(cm, __shfl_xor(cm, st, 64));
    float nm = fmaxf(m, cm);
    float rs = __expf(m - nm);
    float p  = (l < nc) ? __expf(ef - nm) : 0.f;
    float q = p;
#pragma unroll
    for (int st = 1; st < 64; st <<= 1) q += __shfl_xor(q, st, 64);
    s = s*rs + q;
    m = nm;
    s_u[w][l] = u;
    s_p[w][l] = p;
    asm volatile("s_waitcnt lgkmcnt(0)" ::: "memory");
    acc[0]*=rs; acc[1]*=rs; acc[2]*=rs; acc[3]*=rs;
    int nit = (nc + 7) >> 3;
    for (int i = 0; i < nit; ++i){
      int idx = i*8 + ei;
      int   ui = s_u[w][idx];
      float pi = s_p[w][idx];
      short4v hv = *(const short4v*)(h1b + (size_t)ui*32 + ch4);
      acc[0] += pi*b2f(hv[0]);
      acc[1] += pi*b2f(hv[1]);
      acc[2] += pi*b2f(hv[2]);
      acc[3] += pi*b2f(hv[3]);
    }
    asm volatile("s_waitcnt lgkmcnt(0)" ::: "memory");
  }
  float inv = 1.f/s;
#pragma unroll
  for (int mask = 8; mask < 64; mask <<= 1){
    acc[0] += __shfl_xor(acc[0], mask, 64);
    acc[1] += __shfl_xor(acc[1], mask, 64);
    acc[2] += __shfl_xor(acc[2], mask, 64);
    acc[3] += __shfl_xor(acc[3], mask, 64);
  }
  if (l < 8){
    int cb = c*32 + l*4;
    short4v o;
    o[0] = f2b(fmaxf(acc[0]*inv + b2f(b1[cb+0]), 0.f));
    o[1] = f2b(fmaxf(acc[1]*inv + b2f(b1[cb+1]), 0.f));
    o[2] = f2b(fmaxf(acc[2]*inv + b2f(b1[cb+2]), 0.f));
    o[3] = f2b(fmaxf(acc[3]*inv + b2f(b1[cb+3]), 0.f));
    *(short4v*)(g1 + (size_t)v*256 + cb) = o;
  }
}

// ---------------- GAT layer 2: h2c = g1 @ W2^T, CHUNK-major [2][NN][32] ----------------
__global__ __launch_bounds__(256) void k_gemm2(const short* __restrict__ g1, const short* __restrict__ W, short* __restrict__ h2c){
  int wv = blockIdx.x*4 + (threadIdx.x >> 6);
  if (wv >= NN/16) return;
  int l = threadIdx.x & 63;
  int row = wv*16 + (l & 15);
  int koff = (l >> 4)*8;
  short8v a[8];
#pragma unroll
  for (int k = 0; k < 8; ++k) a[k] = *(const short8v*)(g1 + (size_t)row*256 + k*32 + koff);
  int r0 = wv*16 + (l >> 4)*4;
#pragma unroll
  for (int nt = 0; nt < 4; ++nt){
    f4v acc = {0.f,0.f,0.f,0.f};
#pragma unroll
    for (int k = 0; k < 8; ++k){
      short8v b = *(const short8v*)(W + (size_t)(nt*16 + (l & 15))*256 + k*32 + koff);
      acc = mfma16(a[k], b, acc);
    }
    int col = nt*16 + (l & 15);
    size_t cb = (size_t)(col >> 5)*NN*32 + (col & 31);
#pragma unroll
    for (int r = 0; r < 4; ++r) h2c[cb + (size_t)(r0 + r)*32] = f2b(acc[r]);
  }
}

__global__ __launch_bounds__(256) void k_score2(const short* __restrict__ h2c, const short* __restrict__ as, const short* __restrict__ ad, float* a2s, float* a2d){
  int n = blockIdx.x*256 + threadIdx.x;
  if (n >= NN) return;
  float ss = 0.f, sd = 0.f;
#pragma unroll
  for (int cc = 0; cc < 2; ++cc){
    const short* hb = h2c + (size_t)cc*NN*32 + (size_t)n*32;
#pragma unroll
    for (int q = 0; q < 4; ++q){
      short8v hv = *(const short8v*)(hb + q*8);
      short8v sv = *(const short8v*)(as + cc*32 + q*8);
      short8v dv = *(const short8v*)(ad + cc*32 + q*8);
#pragma unroll
      for (int j = 0; j < 8; ++j){ float v = b2f(hv[j]); ss += v*b2f(sv[j]); sd += v*b2f(dv[j]); }
    }
  }
  a2s[n] = ss; a2d[n] = sd;
}

// ---- agg layer 2: 2 chunks of 32ch (3.2MB each), chunk = XCD-half; writes g2 rows
__global__ __launch_bounds__(256) void k_agg2(const int* __restrict__ off, const int* __restrict__ csr,
                                              const short* __restrict__ h2c, const float* __restrict__ a2s,
                                              const float* __restrict__ a2d, const short* __restrict__ b2,
                                              short* __restrict__ g2){
  __shared__ int   s_u[4][64];
  __shared__ float s_p[4][64];
  int bid = blockIdx.x;
  int c = (bid & 7) >> 2;                // chunk = XCD-half
  int q0 = (bid >> 3)*4 + (bid & 3);     // 0..12499
  int v = q0*4 + (threadIdx.x >> 6);
  if (v >= NN) return;
  int w = threadIdx.x >> 6;
  int l = threadIdx.x & 63;
  int ch4 = (l & 7)*4;
  int ei = l >> 3;
  const short* h2b = h2c + (size_t)c*NN*32;
  float adst = a2d[v];
  int e0 = off[v], e1 = off[v+1];
  float m = -1e30f, s = 0.f;
  f4v acc = {0.f,0.f,0.f,0.f};

  for (int base = e0; base < e1; base += 64){
    int nc = e1 - base; if (nc > 64) nc = 64;
    int u = (l < nc) ? csr[base + l] : v;
    float ef = -1e30f;
    if (l < nc){
      float t = a2s[u] + adst;
      ef = (t >= 0.f) ? t : 0.2f*t;
    }
    float cm = ef;
#pragma unroll
    for (int st = 1; st < 64; st <<= 1) cm = fmaxf(cm, __shfl_xor(cm, st, 64));
    float nm = fmaxf(m, cm);
    float rs = __expf(m - nm);
    float p  = (l < nc) ? __expf(ef - nm) : 0.f;
    float q = p;
#pragma unroll
    for (int st = 1; st < 64; st <<= 1) q += __shfl_xor(q, st, 64);
    s = s*rs + q;
    m = nm;
    s_u[w][l] = u;
    s_p[w][l] = p;
    asm volatile("s_waitcnt lgkmcnt(0)" ::: "memory");
    acc[0]*=rs; acc[1]*=rs; acc[2]*=rs; acc[3]*=rs;
    int nit = (nc + 7) >> 3;
    for (int i = 0; i < nit; ++i){
      int idx = i*8 + ei;
      int   ui = s_u[w][idx];
      float pi = s_p[w][idx];
      short4v hv = *(const short4v*)(h2b + (size_t)ui*32 + ch4);
      acc[0] += pi*b2f(hv[0]);
      acc[1] += pi*b2f(hv[1]);
      acc[2] += pi*b2f(hv[2]);
      acc[3] += pi*b2f(hv[3]);
    }
    asm volatile("s_waitcnt lgkmcnt(0)" ::: "memory");
  }
  float inv = 1.f/s;
#pragma unroll
  for (int mask = 8; mask < 64; mask <<= 1){
    acc[0] += __shfl_xor(acc[0], mask, 64);
    acc[1] += __shfl_xor(acc[1], mask, 64);
    acc[2] += __shfl_xor(acc[2], mask, 64);
    acc[3] += __shfl_xor(acc[3], mask, 64);
  }
  if (l < 8){
    int cb = c*32 + l*4;
    short4v o;
    o[0] = f2b(fmaxf(acc[0]*inv + b2f(b2[cb+0]), 0.f));
    o[1] = f2b(fmaxf(acc[1]*inv + b2f(b2[cb+1]), 0.f));
    o[2] = f2b(fmaxf(acc[2]*inv + b2f(b2[cb+2]), 0.f));
    o[3] = f2b(fmaxf(acc[3]*inv + b2f(b2[cb+3]), 0.f));
    *(short4v*)(g2 + (size_t)v*64 + cb) = o;
  }
}

// ---- segment mean-pool over sorted batch: grid (8 splits, 64 segments)
__global__ __launch_bounds__(256) void k_pool(const short* __restrict__ g2, const int* __restrict__ batch,
                                              float* __restrict__ pool, float* __restrict__ cntf){
  int b = blockIdx.y;
  int split = blockIdx.x;       // 0..7
  __shared__ int seg[2];
  __shared__ float red[4][64];
  int tid = threadIdx.x;
  if (tid == 0){
    int lo = 0, hi = NN;
    while (lo < hi){ int mid = (lo+hi)>>1; if (batch[mid] < b) lo = mid+1; else hi = mid; }
    seg[0] = lo;
    lo = 0; hi = NN;
    while (lo < hi){ int mid = (lo+hi)>>1; if (batch[mid] < b+1) lo = mid+1; else hi = mid; }
    seg[1] = lo;
  }
  __syncthreads();
  int lo = seg[0], hi = seg[1];
  int c = tid & 63;
  int rg = tid >> 6;            // 0..3
  float acc = 0.f;
  for (int r = lo + split*4 + rg; r < hi; r += 32)
    acc += b2f(g2[(size_t)r*64 + c]);
  red[rg][c] = acc;
  __syncthreads();
  if (tid < 64){
    float sum = red[0][tid] + red[1][tid] + red[2][tid] + red[3][tid];
    atomicAdd(&pool[b*HD + tid], sum);
  }
  if (split == 0 && tid == 0) cntf[b] = (float)(hi - lo);
}

// ---------------- LSTM pre-GEMM: Xp stored in PERMUTED gate order ----------------
__global__ __launch_bounds__(256) void k_xp(const short* __restrict__ seq,
                                            const short* __restrict__ WihF, const short* __restrict__ bihF, const short* __restrict__ bhhF,
                                            const short* __restrict__ WihB, const short* __restrict__ bihB, const short* __restrict__ bhhB,
                                            float* __restrict__ Xp){
  int dir = blockIdx.y;
  const short* Wih = dir ? WihB : WihF;
  const short* bih = dir ? bihB : bihF;
  const short* bhh = dir ? bhhB : bhhF;
  int wv = blockIdx.x*4 + (threadIdx.x >> 6);   // 200 waves
  int l = threadIdx.x & 63;
  int row = wv*16 + (l & 15);
  int koff = (l >> 4)*8;
  short8v a[2];
#pragma unroll
  for (int k = 0; k < 2; ++k) a[k] = *(const short8v*)(seq + (size_t)row*64 + k*32 + koff);
  int r0 = wv*16 + (l >> 4)*4;
  float* Xpd = Xp + (size_t)dir*TT*BB*256;
#pragma unroll
  for (int nt = 0; nt < 16; ++nt){
    f4v acc = {0.f,0.f,0.f,0.f};
#pragma unroll
    for (int k = 0; k < 2; ++k){
      short8v b = *(const short8v*)(Wih + (size_t)(nt*16 + (l & 15))*64 + k*32 + koff);
      acc = mfma16(a[k], b, acc);
    }
    int col = nt*16 + (l & 15);
    float bias = b2f(bih[col]) + b2f(bhh[col]);
    int gate = col >> 6, ch = col & 63;
    int pcol = ((ch>>5)*8 + ((ch>>4)&1)*4 + gate)*16 + (ch & 15);
#pragma unroll
    for (int r = 0; r < 4; ++r){
      int rr = r0 + r;
      int bidx = rr / TT, t = rr % TT;
      Xpd[((size_t)t*BB + bidx)*256 + pcol] = acc[r] + bias;
    }
  }
}

// persistent LSTM: 8 blocks (2 dir x 4 batch-groups of 16 rows), 256 threads (4 waves).
__global__ __launch_bounds__(256) void k_lstm(const float* __restrict__ Xp,
                                              const short* __restrict__ WhhF, const short* __restrict__ WhhB,
                                              short* __restrict__ lout){
  int bg  = blockIdx.x;            // 0..3 batch-group
  int dir = blockIdx.y;
  const short* Whh = dir ? WhhB : WhhF;
  const float* Xpd = Xp + (size_t)dir*TT*BB*256 + (size_t)bg*16*256;
  __shared__ short hl[2][16][72];     // stride 36 words: 2-way banks (free)
  __shared__ short whl[256][72];
  int tid = threadIdx.x;
  {
    int p = tid;
    int nt = p >> 4, c16p = p & 15;
    int jj = nt & 7, half = nt >> 3;
    int gate = jj & 3, ch = half*32 + (jj>>2)*16 + c16p;
    int src = gate*64 + ch;
#pragma unroll
    for (int q = 0; q < 8; ++q){
      short8v vv = *(const short8v*)(Whh + (size_t)src*64 + q*8);
      *(short8v*)&whl[p][q*8] = vv;
    }
  }
  for (int i = tid; i < 16*64; i += 256) hl[0][i>>6][i&63] = 0;

  int l = tid & 63;
  int w = tid >> 6;                 // wave = gate-group
  int c16 = l & 15;
  int koff = (l >> 4)*8;
  int r0 = (l >> 4)*4;
  int ch = (w>>1)*32 + (w&1)*16 + c16;
  float creg[4] = {0.f,0.f,0.f,0.f};

  float xg[4][4];
  {
    int t0 = dir ? (TT-1) : 0;
    const float* xpb = Xpd + (size_t)t0*BB*256;
#pragma unroll
    for (int j = 0; j < 4; ++j){
      int p = (w*4 + j)*16 + c16;
#pragma unroll
      for (int r = 0; r < 4; ++r) xg[j][r] = xpb[(size_t)(r0 + r)*256 + p];
    }
  }

  int cur = 0;
  for (int s = 0; s < TT; ++s){
    int t = dir ? (TT - 1 - s) : s;
    __syncthreads();
    float xgn[4][4];
    if (s + 1 < TT){
      int tn = dir ? (TT - 2 - s) : (s + 1);
      const float* xpb = Xpd + (size_t)tn*BB*256;
#pragma unroll
      for (int j = 0; j < 4; ++j){
        int p = (w*4 + j)*16 + c16;
#pragma unroll
        for (int r = 0; r < 4; ++r) xgn[j][r] = xpb[(size_t)(r0 + r)*256 + p];
      }
    }
    short8v a0 = *(const short8v*)&hl[cur][c16][koff];
    short8v a1 = *(const short8v*)&hl[cur][c16][32 + koff];
    f4v acc[4];
#pragma unroll
    for (int j = 0; j < 4; ++j){
      int nt = w*4 + j;
      short8v b0 = *(const short8v*)&whl[nt*16 + c16][koff];
      short8v b1 = *(const short8v*)&whl[nt*16 + c16][32 + koff];
      f4v z = {0.f,0.f,0.f,0.f};
      z = mfma16(a0, b0, z);
      z = mfma16(a1, b1, z);
      acc[j] = z;
    }
    int nxt = cur ^ 1;
#pragma unroll
    for (int r = 0; r < 4; ++r){
      float gi = acc[0][r] + xg[0][r];
      float gf = acc[1][r] + xg[1][r];
      float gg = acc[2][r] + xg[2][r];
      float go = acc[3][r] + xg[3][r];
      float cn = fsig(gf)*creg[r] + fsig(gi)*ftanh(gg);
      creg[r] = cn;
      float hv = fsig(go)*ftanh(cn);
      short hb = f2b(hv);
      int row = r0 + r;
      hl[nxt][row][ch] = hb;
      lout[((size_t)(bg*16 + row)*TT + t)*128 + dir*64 + ch] = hb;
    }
#pragma unroll
    for (int j = 0; j < 4; ++j)
#pragma unroll
      for (int r = 0; r < 4; ++r) xg[j][r] = xgn[j][r];
    cur = nxt;
  }
}

// ---------------- attention: qkv = lstm_out @ Win^T + b ----------------
__global__ __launch_bounds__(256) void k_qkv(const short* __restrict__ lout, const short* __restrict__ W, const short* __restrict__ bias, short* __restrict__ qkv){
  int wv = blockIdx.x*4 + (threadIdx.x >> 6);   // 200 waves
  int l = threadIdx.x & 63;
  int row = wv*16 + (l & 15);
  int koff = (l >> 4)*8;
  short8v a[4];
#pragma unroll
  for (int k = 0; k < 4; ++k) a[k] = *(const short8v*)(lout + (size_t)row*128 + k*32 + koff);
  int r0 = wv*16 + (l >> 4)*4;
#pragma unroll
  for (int nt = 0; nt < 24; ++nt){
    f4v acc = {0.f,0.f,0.f,0.f};
#pragma unroll
    for (int k = 0; k < 4; ++k){
      short8v b = *(const short8v*)(W + (size_t)(nt*16 + (l & 15))*128 + k*32 + koff);
      acc = mfma16(a[k], b, acc);
    }
    int col = nt*16 + (l & 15);
    float bv = b2f(bias[col]);
#pragma unroll
    for (int r = 0; r < 4; ++r) qkv[(size_t)(r0 + r)*384 + col] = f2b(acc[r] + bv);
  }
}

// one wave per (batch, head); mean over T fused (output projection deferred)
__global__ __launch_bounds__(64) void k_attn(const short* __restrict__ qkv, float* __restrict__ omean){
  int b = blockIdx.x >> 2, h = blockIdx.x & 3;
  int l = threadIdx.x;
  __shared__ float kl[50][32], vl[50][32], ol[50][32];
  for (int i = l; i < 1600; i += 64){
    int t = i >> 5, c = i & 31;
    kl[t][c] = b2f(qkv[((size_t)b*TT + t)*384 + 128 + h*32 + c]);
    vl[t][c] = b2f(qkv[((size_t)b*TT + t)*384 + 256 + h*32 + c]);
  }
  __syncthreads();
  float o[32];
#pragma unroll
  for (int c = 0; c < 32; ++c) o[c] = 0.f;
  if (l < TT){
    float q[32];
#pragma unroll
    for (int qq = 0; qq < 4; ++qq){
      short8v vq = *(const short8v*)(qkv + ((size_t)b*TT + l)*384 + h*32 + qq*8);
#pragma unroll
      for (int j = 0; j < 8; ++j) q[qq*8 + j] = b2f(vq[j]);
    }
    float sc[50];
    float mx = -1e30f;
    const float scale = 0.17677669529663687f;  // 1/sqrt(32)
#pragma unroll
    for (int j = 0; j < 50; ++j){
      float d = 0.f;
#pragma unroll
      for (int c = 0; c < 32; ++c) d += q[c]*kl[j][c];
      d *= scale;
      sc[j] = d;
      mx = fmaxf(mx, d);
    }
    float sum = 0.f;
#pragma unroll
    for (int j = 0; j < 50; ++j){ float p = __expf(sc[j] - mx); sc[j] = p; sum += p; }
    float inv = 1.f/sum;
#pragma unroll
    for (int j = 0; j < 50; ++j){
      float p = sc[j]*inv;
#pragma unroll
      for (int c = 0; c < 32; ++c) o[c] += p*vl[j][c];
    }
#pragma unroll
    for (int c = 0; c < 32; ++c) ol[l][c] = o[c];
  }
  __syncthreads();
  if (l < 32){
    float s = 0.f;
#pragma unroll
    for (int t = 0; t < TT; ++t) s += ol[t][l];
    omean[(size_t)b*128 + h*32 + l] = s*0.02f;  // mean over T=50
  }
}

// final: combined = [pool/cnt (64), omean @ Wout^T + bout (128)]; out = combined @ fc^T + fcb
__global__ __launch_bounds__(192) void k_final(const float* __restrict__ pool, const float* __restrict__ cntf,
                                               const float* __restrict__ omean,
                                               const short* __restrict__ Woutw, const short* __restrict__ Woutb,
                                               const short* __restrict__ fcw, const short* __restrict__ fcb,
                                               const int* __restrict__ flag, void* __restrict__ outv){
  int b = blockIdx.x;
  int tid = threadIdx.x;
  __shared__ float comb[192];
  if (tid < 64){
    float cnt = cntf[b];
    comb[tid] = pool[b*HD + tid] / fmaxf(cnt, 1.f);
  } else {
    int e = tid - 64;
    float s = b2f(Woutb[e]);
    for (int j = 0; j < 128; ++j) s += omean[(size_t)b*128 + j]*b2f(Woutw[e*128 + j]);
    comb[tid] = s;
  }
  __syncthreads();
  if (tid < 2){
    float s = b2f(fcb[tid]);
    for (int j = 0; j < 192; ++j) s += comb[j]*b2f(fcw[tid*192 + j]);
    if (*flag) ((short*)outv)[b*2 + tid] = f2b(s);
    else       ((float*)outv)[b*2 + tid] = s;
  }
}

extern "C" void kernel_launch(void* const* d_in, const int* in_sizes, int n_in,
                              void* d_out, int out_size, void* d_ws, size_t ws_size,
                              hipStream_t stream){
  const int* ei    = (const int*)d_in[1];
  const int* batch = (const int*)d_in[2];

  char* ws = (char*)d_ws;
  size_t o = 0;
  auto alloc = [&](size_t bytes)->char*{
    char* r = ws + o;
    o = (o + bytes + 255) & ~(size_t)255;
    return r;
  };
  short* arena = (short*)alloc((size_t)6787912*2);
  int*   flag  = (int*)alloc(256);
  char*  bufA  = alloc((size_t)NN*256*2);   // h1c, later h2c+g2
  char*  bufB  = alloc((size_t)NN*256*2);   // g1, later Xp/lout/qkv/omean
  float* a1s  = (float*)alloc((size_t)NN*4*4);
  float* a1d  = (float*)alloc((size_t)NN*4*4);
  float* a2s  = (float*)alloc((size_t)NN*4);
  float* a2d  = (float*)alloc((size_t)NN*4);
  int*   deg  = (int*)alloc((size_t)NPAD*4);
  int*   offv = (int*)alloc((size_t)(NN+1)*4);
  int*   cur  = (int*)alloc((size_t)NN*4);
  int*   csr  = (int*)alloc((size_t)ETOT*4);
  float* pool = (float*)alloc((size_t)BB*HD*4);
  float* cntf = (float*)alloc((size_t)BB*4);

  short* h1c = (short*)bufA;                      // [8][NN][32]
  short* h2c = (short*)bufA;                      // [2][NN][32] overlay (h1c dead after k_agg1)
  short* g2 = (short*)(bufA + 12800000);          // [NN][64] bf16, disjoint from h2c
  short* g1 = (short*)bufB;
  float* Xp   = (float*)bufB;                     // overlay (g1 dead after k_gemm2)
  short* lout = (short*)(bufB + 6553600);
  short* qkv  = (short*)(bufB + 6553600 + 819200);
  float* omean= (float*)(bufB + 6553600 + 819200 + 2457600);

  // arena views
  const short* xb    = arena + 0;
  const short* seqb  = arena + 6400000;
  const short* w1b   = arena + 6604800;
  const short* as1b  = arena + 6637568;
  const short* ad1b  = arena + 6637824;
  const short* b1b   = arena + 6638080;
  const short* w2b   = arena + 6638336;
  const short* as2b  = arena + 6654720;
  const short* ad2b  = arena + 6654784;
  const short* b2b   = arena + 6654848;
  const short* wihFb = arena + 6654912;
  const short* whhFb = arena + 6671296;
  const short* bihFb = arena + 6687680;
  const short* bhhFb = arena + 6687936;
  const short* wihBb = arena + 6688192;
  const short* whhBb = arena + 6704576;
  const short* bihBb = arena + 6720960;
  const short* bhhBb = arena + 6721216;
  const short* winwb = arena + 6721472;
  const short* winbb = arena + 6770624;
  const short* woutwb= arena + 6771008;
  const short* woutbb= arena + 6787392;
  const short* fcwb  = arena + 6787520;
  const short* fcbb  = arena + 6787904;

  Ptrs P;
  P.p[0]=d_in[0];  P.p[1]=d_in[3];  P.p[2]=d_in[4];  P.p[3]=d_in[5];
  P.p[4]=d_in[6];  P.p[5]=d_in[7];  P.p[6]=d_in[8];  P.p[7]=d_in[9];
  P.p[8]=d_in[10]; P.p[9]=d_in[11]; P.p[10]=d_in[12];P.p[11]=d_in[13];
  P.p[12]=d_in[14];P.p[13]=d_in[15];P.p[14]=d_in[16];P.p[15]=d_in[17];
  P.p[16]=d_in[18];P.p[17]=d_in[19];P.p[18]=d_in[20];P.p[19]=d_in[21];
  P.p[20]=d_in[22];P.p[21]=d_in[23];P.p[22]=d_in[24];P.p[23]=d_in[25];

  // dtype detect + convert
  k_detect<<<1, 256, 0, stream>>>((const unsigned short*)d_in[0], flag);
  k_cvt<<<2048, 256, 0, stream>>>(P, arena, flag);

  // CSR build
  k_init<<<(NPAD+255)/256, 256, 0, stream>>>(deg, pool);
  k_count<<<(EE+255)/256, 256, 0, stream>>>(ei, deg);
  k_scan<<<1, 1024, 0, stream>>>(deg, offv);
  k_self<<<(NN+255)/256, 256, 0, stream>>>(offv, cur, csr);
  k_scatter<<<(EE+255)/256, 256, 0, stream>>>(ei, cur, csr);

  // GAT layer 1
  k_gemm1<<<(NN/16+3)/4, 256, 0, stream>>>(xb, w1b, h1c);
  k_score1<<<(NN*4+255)/256, 256, 0, stream>>>(h1c, as1b, ad1b, a1s, a1d);
  k_agg1<<<(NN/4)*8, 256, 0, stream>>>(offv, csr, h1c, a1s, a1d, b1b, g1);

  // GAT layer 2 + pool
  k_gemm2<<<(NN/16+3)/4, 256, 0, stream>>>(g1, w2b, h2c);
  k_score2<<<(NN+255)/256, 256, 0, stream>>>(h2c, as2b, ad2b, a2s, a2d);
  k_agg2<<<(NN/4)*2, 256, 0, stream>>>(offv, csr, h2c, a2s, a2d, b2b, g2);
  k_pool<<<dim3(8, BB), 256, 0, stream>>>(g2, batch, pool, cntf);

  // LSTM
  k_xp<<<dim3(50, 2), 256, 0, stream>>>(seqb, wihFb, bihFb, bhhFb, wihBb, bihBb, bhhBb, Xp);
  k_lstm<<<dim3(4, 2), 256, 0, stream>>>(Xp, whhFb, whhBb, lout);

  // attention
  k_qkv<<<50, 256, 0, stream>>>(lout, winwb, winbb, qkv);
  k_attn<<<BB*4, 64, 0, stream>>>(qkv, omean);

  // final
  k_final<<<BB, 192, 0, stream>>>(pool, cntf, omean, woutwb, woutbb, fcwb, fcbb, flag, d_out);
}

// Round 10
// 473.156 us; speedup vs baseline: 1.0262x; 1.0262x over previous
//
#include <hip/hip_runtime.h>

#define NN 50000
#define EE 500000
#define BB 64
#define TT 50
#define FN 128
#define FS 64
#define HD 64
#define ETOT (EE + NN)
#define NPAD 50176   // 1024*49, k_scan guard-free

typedef __attribute__((ext_vector_type(8))) short short8v;
typedef __attribute__((ext_vector_type(4))) short short4v;
typedef __attribute__((ext_vector_type(4))) float f4v;

__device__ __forceinline__ float b2f(short u){
  union { unsigned int i; float f; } v; v.i = ((unsigned int)(unsigned short)u) << 16; return v.f;
}
__device__ __forceinline__ short f2b(float f){
  union { float f; unsigned int i; } v; v.f = f;
  unsigned int x = v.i;
  return (short)((x + 0x7fffu + ((x >> 16) & 1u)) >> 16);
}
__device__ __forceinline__ f4v mfma16(short8v a, short8v b, f4v c){
  return __builtin_amdgcn_mfma_f32_16x16x32_bf16(a, b, c, 0, 0, 0);
}
__device__ __forceinline__ float frcp(float x){ return __builtin_amdgcn_rcpf(x); }
__device__ __forceinline__ float fsig(float x){ return frcp(1.f + __expf(-x)); }
__device__ __forceinline__ float ftanh(float x){ return 1.f - 2.f*frcp(1.f + __expf(2.f*x)); }

// ---------------- input dtype detect + convert to bf16 arena ----------------
constexpr int SEG_CUM[25] = {0, 6400000, 6604800, 6637568, 6637824, 6638080,
  6638336, 6654720, 6654784, 6654848, 6654912, 6671296, 6687680, 6687936,
  6688192, 6704576, 6720960, 6721216, 6721472, 6770624, 6771008, 6787392,
  6787520, 6787904, 6787906};
#define ARENA_VEC (6787904/8)

struct Ptrs { const void* p[24]; };

__global__ __launch_bounds__(256) void k_detect(const unsigned short* x16, int* flag){
  __shared__ int cnt;
  if (threadIdx.x == 0) cnt = 0;
  __syncthreads();
  int c = 0;
  for (int i = threadIdx.x; i < 2048; i += 256){
    unsigned short v = x16[2*i];         // even shorts: f32 low-halves (random) vs bf16 values
    int e = (v >> 7) & 0xFF;
    if (e >= 64 && e < 160) c++;
  }
  atomicAdd(&cnt, c);
  __syncthreads();
  if (threadIdx.x == 0) *flag = (cnt >= 1536) ? 1 : 0;   // 1 = inputs are bf16
}

__global__ __launch_bounds__(256) void k_cvt(Ptrs P, short* arena, const int* flag){
  bool isb = (*flag != 0);
  int idx = blockIdx.x*256 + threadIdx.x;
  for (int v = idx; v < ARENA_VEC; v += gridDim.x*256){
    int i = v*8;
    int s = 0;
#pragma unroll
    for (int k = 1; k < 24; ++k) if (i >= SEG_CUM[k]) s = k;
    int j = i - SEG_CUM[s];
    short8v o;
    if (isb){
      o = *(const short8v*)((const short*)P.p[s] + j);
    } else {
      const float* f = (const float*)P.p[s] + j;
      f4v lo = *(const f4v*)f;
      f4v hi = *(const f4v*)(f + 4);
#pragma unroll
      for (int q = 0; q < 4; ++q){ o[q] = f2b(lo[q]); o[4+q] = f2b(hi[q]); }
    }
    *(short8v*)(arena + i) = o;
  }
  if (blockIdx.x == 0 && threadIdx.x == 0){
    for (int j = 0; j < 2; ++j)
      arena[6787904 + j] = isb ? ((const short*)P.p[23])[j] : f2b(((const float*)P.p[23])[j]);
  }
}

// ---------------- CSR build ----------------
__global__ __launch_bounds__(256) void k_init(int* deg, float* pool){
  int i = blockIdx.x*256 + threadIdx.x;
  if (i < NN) deg[i] = 1;            // self loop
  else if (i < NPAD) deg[i] = 0;     // pad for guard-free scan
  if (i < BB*HD) pool[i] = 0.f;
}

__global__ __launch_bounds__(256) void k_count(const int* ei, int* deg){
  int e = blockIdx.x*256 + threadIdx.x;
  if (e < EE) atomicAdd(&deg[ei[EE + e]], 1);
}

// single-pass scan: 49 values/thread held in REGISTERS (guard-free, unrolled)
__global__ __launch_bounds__(1024) void k_scan(const int* __restrict__ deg, int* __restrict__ off){
  __shared__ int buf[1024];
  int tid = threadIdx.x;
  int start = tid*49;
  int v[49];
#pragma unroll
  for (int j = 0; j < 49; ++j) v[j] = deg[start + j];
  int s = 0;
#pragma unroll
  for (int j = 0; j < 49; ++j) s += v[j];
  buf[tid] = s;
  __syncthreads();
  for (int st = 1; st < 1024; st <<= 1){
    int t = (tid >= st) ? buf[tid - st] : 0;
    __syncthreads();
    buf[tid] += t;
    __syncthreads();
  }
  int run = buf[tid] - s;            // exclusive base for this chunk
#pragma unroll
  for (int j = 0; j < 49; ++j){
    int i = start + j;
    if (i < NN) off[i] = run;
    run += v[j];
  }
  if (tid == 1023) off[NN] = run;
}

__global__ __launch_bounds__(256) void k_self(const int* off, int* cur, int* csr){
  int v = blockIdx.x*256 + threadIdx.x;
  if (v < NN){ int o = off[v]; csr[o] = v; cur[v] = o + 1; }
}

__global__ __launch_bounds__(256) void k_scatter(const int* ei, int* cur, int* csr){
  int e = blockIdx.x*256 + threadIdx.x;
  if (e < EE){
    int d = ei[EE + e];
    int pos = atomicAdd(&cur[d], 1);
    csr[pos] = ei[e];
  }
}

// ---------------- GAT layer 1: h1c = x @ W1^T, CHUNK-major [8][NN][32] ----------------
__global__ __launch_bounds__(256) void k_gemm1(const short* __restrict__ x, const short* __restrict__ W, short* __restrict__ h1c){
  int wv = blockIdx.x*4 + (threadIdx.x >> 6);
  if (wv >= NN/16) return;
  int l = threadIdx.x & 63;
  int row = wv*16 + (l & 15);
  int koff = (l >> 4)*8;
  short8v a[4];
#pragma unroll
  for (int k = 0; k < 4; ++k) a[k] = *(const short8v*)(x + (size_t)row*128 + k*32 + koff);
  int r0 = wv*16 + (l >> 4)*4;
#pragma unroll
  for (int nt = 0; nt < 16; ++nt){
    f4v acc = {0.f,0.f,0.f,0.f};
#pragma unroll
    for (int k = 0; k < 4; ++k){
      short8v b = *(const short8v*)(W + (size_t)(nt*16 + (l & 15))*128 + k*32 + koff);
      acc = mfma16(a[k], b, acc);
    }
    int col = nt*16 + (l & 15);
    size_t cb = (size_t)(col >> 5)*NN*32 + (col & 31);
#pragma unroll
    for (int r = 0; r < 4; ++r) h1c[cb + (size_t)(r0 + r)*32] = f2b(acc[r]);
  }
}

__global__ __launch_bounds__(256) void k_score1(const short* __restrict__ h1c, const short* __restrict__ as, const short* __restrict__ ad, float* a1s, float* a1d){
  int i = blockIdx.x*256 + threadIdx.x;
  if (i >= NN*4) return;
  int n = i >> 2, h = i & 3;
  float ss = 0.f, sd = 0.f;
#pragma unroll
  for (int cc = 0; cc < 2; ++cc){
    const short* hb = h1c + (size_t)(h*2 + cc)*NN*32 + (size_t)n*32;
#pragma unroll
    for (int q = 0; q < 4; ++q){
      short8v hv = *(const short8v*)(hb + q*8);
      short8v sv = *(const short8v*)(as + h*64 + cc*32 + q*8);
      short8v dv = *(const short8v*)(ad + h*64 + cc*32 + q*8);
#pragma unroll
      for (int j = 0; j < 8; ++j){ float v = b2f(hv[j]); ss += v*b2f(sv[j]); sd += v*b2f(dv[j]); }
    }
  }
  a1s[i] = ss; a1d[i] = sd;
}

// ---- alpha layer 1: one wave per node, ONCE. p = exp(min(leaky,30)); 1/s -> sinv (over a1d)
__global__ __launch_bounds__(256) void k_alpha1(const int* __restrict__ off, const int* __restrict__ csr,
                                                const float* __restrict__ a1s, float* __restrict__ sinv,
                                                float* __restrict__ alphaE){
  int v = blockIdx.x*4 + (threadIdx.x >> 6);
  if (v >= NN) return;
  int l = threadIdx.x & 63;
  const f4v ad4 = *(const f4v*)(sinv + v*4);     // a1d values (read before overwrite)
  int e0 = off[v], e1 = off[v+1];
  float s0=0.f,s1=0.f,s2=0.f,s3=0.f;
  for (int base = e0; base < e1; base += 64){
    int nc = e1 - base; if (nc > 64) nc = 64;
    float p0=0.f,p1=0.f,p2=0.f,p3=0.f;
    if (l < nc){
      int u = csr[base + l];
      f4v as4 = *(const f4v*)(a1s + u*4);
      float t0 = as4[0]+ad4[0]; t0 = (t0>=0.f)?t0:0.2f*t0; p0 = __expf(fminf(t0,30.f));
      float t1 = as4[1]+ad4[1]; t1 = (t1>=0.f)?t1:0.2f*t1; p1 = __expf(fminf(t1,30.f));
      float t2 = as4[2]+ad4[2]; t2 = (t2>=0.f)?t2:0.2f*t2; p2 = __expf(fminf(t2,30.f));
      float t3 = as4[3]+ad4[3]; t3 = (t3>=0.f)?t3:0.2f*t3; p3 = __expf(fminf(t3,30.f));
      f4v pv; pv[0]=p0; pv[1]=p1; pv[2]=p2; pv[3]=p3;
      *(f4v*)(alphaE + (size_t)(base+l)*4) = pv;
    }
    float q0=p0,q1=p1,q2=p2,q3=p3;
#pragma unroll
    for (int st = 1; st < 64; st <<= 1){
      q0 += __shfl_xor(q0, st, 64);
      q1 += __shfl_xor(q1, st, 64);
      q2 += __shfl_xor(q2, st, 64);
      q3 += __shfl_xor(q3, st, 64);
    }
    s0 += q0; s1 += q1; s2 += q2; s3 += q3;
  }
  if (l == 0){
    f4v sv; sv[0]=1.f/s0; sv[1]=1.f/s1; sv[2]=1.f/s2; sv[3]=1.f/s3;
    *(f4v*)(sinv + v*4) = sv;
  }
}

// ---- gather layer 1: chunk = bid&7 -> XCD-resident 3.2MB slice; 8 edges x (8 lanes x 4ch)
__global__ __launch_bounds__(256) void k_gath1(const int* __restrict__ off, const int* __restrict__ csr,
                                               const short* __restrict__ h1c, const float* __restrict__ alphaE,
                                               const float* __restrict__ sinv, const short* __restrict__ b1,
                                               short* __restrict__ g1){
  int bid = blockIdx.x;
  int c = bid & 7;                       // chunk == XCD affinity
  int v = (bid >> 3)*4 + (threadIdx.x >> 6);
  if (v >= NN) return;
  int l = threadIdx.x & 63;
  int hh = c >> 1;
  int ch4 = (l & 7)*4;
  int ei = l >> 3;
  const short* h1b = h1c + (size_t)c*NN*32;
  int e0 = off[v], e1 = off[v+1];
  f4v acc = {0.f,0.f,0.f,0.f};
  for (int e = e0 + ei; e < e1; e += 8){
    int u = csr[e];
    float p = alphaE[(size_t)e*4 + hh];
    short4v hv = *(const short4v*)(h1b + (size_t)u*32 + ch4);
    acc[0] += p*b2f(hv[0]);
    acc[1] += p*b2f(hv[1]);
    acc[2] += p*b2f(hv[2]);
    acc[3] += p*b2f(hv[3]);
  }
#pragma unroll
  for (int mask = 8; mask < 64; mask <<= 1){
    acc[0] += __shfl_xor(acc[0], mask, 64);
    acc[1] += __shfl_xor(acc[1], mask, 64);
    acc[2] += __shfl_xor(acc[2], mask, 64);
    acc[3] += __shfl_xor(acc[3], mask, 64);
  }
  if (l < 8){
    float inv = sinv[v*4 + hh];
    int cb = c*32 + l*4;
    short4v o;
    o[0] = f2b(fmaxf(acc[0]*inv + b2f(b1[cb+0]), 0.f));
    o[1] = f2b(fmaxf(acc[1]*inv + b2f(b1[cb+1]), 0.f));
    o[2] = f2b(fmaxf(acc[2]*inv + b2f(b1[cb+2]), 0.f));
    o[3] = f2b(fmaxf(acc[3]*inv + b2f(b1[cb+3]), 0.f));
    *(short4v*)(g1 + (size_t)v*256 + cb) = o;
  }
}

// ---------------- GAT layer 2: h2c = g1 @ W2^T, CHUNK-major [2][NN][32] ----------------
__global__ __launch_bounds__(256) void k_gemm2(const short* __restrict__ g1, const short* __restrict__ W, short* __restrict__ h2c){
  int wv = blockIdx.x*4 + (threadIdx.x >> 6);
  if (wv >= NN/16) return;
  int l = threadIdx.x & 63;
  int row = wv*16 + (l & 15);
  int koff = (l >> 4)*8;
  short8v a[8];
#pragma unroll
  for (int k = 0; k < 8; ++k) a[k] = *(const short8v*)(g1 + (size_t)row*256 + k*32 + koff);
  int r0 = wv*16 + (l >> 4)*4;
#pragma unroll
  for (int nt = 0; nt < 4; ++nt){
    f4v acc = {0.f,0.f,0.f,0.f};
#pragma unroll
    for (int k = 0; k < 8; ++k){
      short8v b = *(const short8v*)(W + (size_t)(nt*16 + (l & 15))*256 + k*32 + koff);
      acc = mfma16(a[k], b, acc);
    }
    int col = nt*16 + (l & 15);
    size_t cb = (size_t)(col >> 5)*NN*32 + (col & 31);
#pragma unroll
    for (int r = 0; r < 4; ++r) h2c[cb + (size_t)(r0 + r)*32] = f2b(acc[r]);
  }
}

__global__ __launch_bounds__(256) void k_score2(const short* __restrict__ h2c, const short* __restrict__ as, const short* __restrict__ ad, float* a2s, float* a2d){
  int n = blockIdx.x*256 + threadIdx.x;
  if (n >= NN) return;
  float ss = 0.f, sd = 0.f;
#pragma unroll
  for (int cc = 0; cc < 2; ++cc){
    const short* hb = h2c + (size_t)cc*NN*32 + (size_t)n*32;
#pragma unroll
    for (int q = 0; q < 4; ++q){
      short8v hv = *(const short8v*)(hb + q*8);
      short8v sv = *(const short8v*)(as + cc*32 + q*8);
      short8v dv = *(const short8v*)(ad + cc*32 + q*8);
#pragma unroll
      for (int j = 0; j < 8; ++j){ float v = b2f(hv[j]); ss += v*b2f(sv[j]); sd += v*b2f(dv[j]); }
    }
  }
  a2s[n] = ss; a2d[n] = sd;
}

// ---- alpha layer 2: one wave per node, single head; sinv over a2d
__global__ __launch_bounds__(256) void k_alpha2(const int* __restrict__ off, const int* __restrict__ csr,
                                                const float* __restrict__ a2s, float* __restrict__ sinv,
                                                float* __restrict__ alphaE){
  int v = blockIdx.x*4 + (threadIdx.x >> 6);
  if (v >= NN) return;
  int l = threadIdx.x & 63;
  float adst = sinv[v];                  // a2d value (read before overwrite)
  int e0 = off[v], e1 = off[v+1];
  float s = 0.f;
  for (int base = e0; base < e1; base += 64){
    int nc = e1 - base; if (nc > 64) nc = 64;
    float p = 0.f;
    if (l < nc){
      int u = csr[base + l];
      float t = a2s[u] + adst;
      t = (t>=0.f)?t:0.2f*t;
      p = __expf(fminf(t,30.f));
      alphaE[base + l] = p;
    }
    float q = p;
#pragma unroll
    for (int st = 1; st < 64; st <<= 1) q += __shfl_xor(q, st, 64);
    s += q;
  }
  if (l == 0) sinv[v] = 1.f/s;
}

// ---- gather layer 2: 2 chunks of 32ch (3.2MB), chunk = XCD-half
__global__ __launch_bounds__(256) void k_gath2(const int* __restrict__ off, const int* __restrict__ csr,
                                               const short* __restrict__ h2c, const float* __restrict__ alphaE,
                                               const float* __restrict__ sinv, const short* __restrict__ b2,
                                               short* __restrict__ g2){
  int bid = blockIdx.x;
  int c = (bid & 7) >> 2;                // chunk = XCD-half
  int q0 = (bid >> 3)*4 + (bid & 3);     // 0..12499
  int v = q0*4 + (threadIdx.x >> 6);
  if (v >= NN) return;
  int l = threadIdx.x & 63;
  int ch4 = (l & 7)*4;
  int ei = l >> 3;
  const short* h2b = h2c + (size_t)c*NN*32;
  int e0 = off[v], e1 = off[v+1];
  f4v acc = {0.f,0.f,0.f,0.f};
  for (int e = e0 + ei; e < e1; e += 8){
    int u = csr[e];
    float p = alphaE[e];
    short4v hv = *(const short4v*)(h2b + (size_t)u*32 + ch4);
    acc[0] += p*b2f(hv[0]);
    acc[1] += p*b2f(hv[1]);
    acc[2] += p*b2f(hv[2]);
    acc[3] += p*b2f(hv[3]);
  }
#pragma unroll
  for (int mask = 8; mask < 64; mask <<= 1){
    acc[0] += __shfl_xor(acc[0], mask, 64);
    acc[1] += __shfl_xor(acc[1], mask, 64);
    acc[2] += __shfl_xor(acc[2], mask, 64);
    acc[3] += __shfl_xor(acc[3], mask, 64);
  }
  if (l < 8){
    float inv = sinv[v];
    int cb = c*32 + l*4;
    short4v o;
    o[0] = f2b(fmaxf(acc[0]*inv + b2f(b2[cb+0]), 0.f));
    o[1] = f2b(fmaxf(acc[1]*inv + b2f(b2[cb+1]), 0.f));
    o[2] = f2b(fmaxf(acc[2]*inv + b2f(b2[cb+2]), 0.f));
    o[3] = f2b(fmaxf(acc[3]*inv + b2f(b2[cb+3]), 0.f));
    *(short4v*)(g2 + (size_t)v*64 + cb) = o;
  }
}

// ---- segment mean-pool over sorted batch: grid (8 splits, 64 segments)
__global__ __launch_bounds__(256) void k_pool(const short* __restrict__ g2, const int* __restrict__ batch,
                                              float* __restrict__ pool, float* __restrict__ cntf){
  int b = blockIdx.y;
  int split = blockIdx.x;       // 0..7
  __shared__ int seg[2];
  __shared__ float red[4][64];
  int tid = threadIdx.x;
  if (tid == 0){
    int lo = 0, hi = NN;
    while (lo < hi){ int mid = (lo+hi)>>1; if (batch[mid] < b) lo = mid+1; else hi = mid; }
    seg[0] = lo;
    lo = 0; hi = NN;
    while (lo < hi){ int mid = (lo+hi)>>1; if (batch[mid] < b+1) lo = mid+1; else hi = mid; }
    seg[1] = lo;
  }
  __syncthreads();
  int lo = seg[0], hi = seg[1];
  int c = tid & 63;
  int rg = tid >> 6;            // 0..3
  float acc = 0.f;
  for (int r = lo + split*4 + rg; r < hi; r += 32)
    acc += b2f(g2[(size_t)r*64 + c]);
  red[rg][c] = acc;
  __syncthreads();
  if (tid < 64){
    float sum = red[0][tid] + red[1][tid] + red[2][tid] + red[3][tid];
    atomicAdd(&pool[b*HD + tid], sum);
  }
  if (split == 0 && tid == 0) cntf[b] = (float)(hi - lo);
}

// ---------------- LSTM pre-GEMM: Xp stored in PERMUTED gate order ----------------
__global__ __launch_bounds__(256) void k_xp(const short* __restrict__ seq,
                                            const short* __restrict__ WihF, const short* __restrict__ bihF, const short* __restrict__ bhhF,
                                            const short* __restrict__ WihB, const short* __restrict__ bihB, const short* __restrict__ bhhB,
                                            float* __restrict__ Xp){
  int dir = blockIdx.y;
  const short* Wih = dir ? WihB : WihF;
  const short* bih = dir ? bihB : bihF;
  const short* bhh = dir ? bhhB : bhhF;
  int wv = blockIdx.x*4 + (threadIdx.x >> 6);   // 200 waves
  int l = threadIdx.x & 63;
  int row = wv*16 + (l & 15);
  int koff = (l >> 4)*8;
  short8v a[2];
#pragma unroll
  for (int k = 0; k < 2; ++k) a[k] = *(const short8v*)(seq + (size_t)row*64 + k*32 + koff);
  int r0 = wv*16 + (l >> 4)*4;
  float* Xpd = Xp + (size_t)dir*TT*BB*256;
#pragma unroll
  for (int nt = 0; nt < 16; ++nt){
    f4v acc = {0.f,0.f,0.f,0.f};
#pragma unroll
    for (int k = 0; k < 2; ++k){
      short8v b = *(const short8v*)(Wih + (size_t)(nt*16 + (l & 15))*64 + k*32 + koff);
      acc = mfma16(a[k], b, acc);
    }
    int col = nt*16 + (l & 15);
    float bias = b2f(bih[col]) + b2f(bhh[col]);
    int gate = col >> 6, ch = col & 63;
    int pcol = ((ch>>5)*8 + ((ch>>4)&1)*4 + gate)*16 + (ch & 15);
#pragma unroll
    for (int r = 0; r < 4; ++r){
      int rr = r0 + r;
      int bidx = rr / TT, t = rr % TT;
      Xpd[((size_t)t*BB + bidx)*256 + pcol] = acc[r] + bias;
    }
  }
}

// persistent LSTM: 8 blocks (2 dir x 4 batch-groups of 16 rows), 256 threads (4 waves).
__global__ __launch_bounds__(256) void k_lstm(const float* __restrict__ Xp,
                                              const short* __restrict__ WhhF, const short* __restrict__ WhhB,
                                              short* __restrict__ lout){
  int bg  = blockIdx.x;            // 0..3 batch-group
  int dir = blockIdx.y;
  const short* Whh = dir ? WhhB : WhhF;
  const float* Xpd = Xp + (size_t)dir*TT*BB*256 + (size_t)bg*16*256;
  __shared__ short hl[2][16][72];     // stride 36 words: 2-way banks (free)
  __shared__ short whl[256][72];
  int tid = threadIdx.x;
  {
    int p = tid;
    int nt = p >> 4, c16p = p & 15;
    int jj = nt & 7, half = nt >> 3;
    int gate = jj & 3, ch = half*32 + (jj>>2)*16 + c16p;
    int src = gate*64 + ch;
#pragma unroll
    for (int q = 0; q < 8; ++q){
      short8v vv = *(const short8v*)(Whh + (size_t)src*64 + q*8);
      *(short8v*)&whl[p][q*8] = vv;
    }
  }
  for (int i = tid; i < 16*64; i += 256) hl[0][i>>6][i&63] = 0;

  int l = tid & 63;
  int w = tid >> 6;                 // wave = gate-group
  int c16 = l & 15;
  int koff = (l >> 4)*8;
  int r0 = (l >> 4)*4;
  int ch = (w>>1)*32 + (w&1)*16 + c16;
  float creg[4] = {0.f,0.f,0.f,0.f};

  float xg[4][4];
  {
    int t0 = dir ? (TT-1) : 0;
    const float* xpb = Xpd + (size_t)t0*BB*256;
#pragma unroll
    for (int j = 0; j < 4; ++j){
      int p = (w*4 + j)*16 + c16;
#pragma unroll
      for (int r = 0; r < 4; ++r) xg[j][r] = xpb[(size_t)(r0 + r)*256 + p];
    }
  }

  int cur = 0;
  for (int s = 0; s < TT; ++s){
    int t = dir ? (TT - 1 - s) : s;
    __syncthreads();
    float xgn[4][4];
    if (s + 1 < TT){
      int tn = dir ? (TT - 2 - s) : (s + 1);
      const float* xpb = Xpd + (size_t)tn*BB*256;
#pragma unroll
      for (int j = 0; j < 4; ++j){
        int p = (w*4 + j)*16 + c16;
#pragma unroll
        for (int r = 0; r < 4; ++r) xgn[j][r] = xpb[(size_t)(r0 + r)*256 + p];
      }
    }
    short8v a0 = *(const short8v*)&hl[cur][c16][koff];
    short8v a1 = *(const short8v*)&hl[cur][c16][32 + koff];
    f4v acc[4];
#pragma unroll
    for (int j = 0; j < 4; ++j){
      int nt = w*4 + j;
      short8v b0 = *(const short8v*)&whl[nt*16 + c16][koff];
      short8v b1 = *(const short8v*)&whl[nt*16 + c16][32 + koff];
      f4v z = {0.f,0.f,0.f,0.f};
      z = mfma16(a0, b0, z);
      z = mfma16(a1, b1, z);
      acc[j] = z;
    }
    int nxt = cur ^ 1;
#pragma unroll
    for (int r = 0; r < 4; ++r){
      float gi = acc[0][r] + xg[0][r];
      float gf = acc[1][r] + xg[1][r];
      float gg = acc[2][r] + xg[2][r];
      float go = acc[3][r] + xg[3][r];
      float cn = fsig(gf)*creg[r] + fsig(gi)*ftanh(gg);
      creg[r] = cn;
      float hv = fsig(go)*ftanh(cn);
      short hb = f2b(hv);
      int row = r0 + r;
      hl[nxt][row][ch] = hb;
      lout[((size_t)(bg*16 + row)*TT + t)*128 + dir*64 + ch] = hb;
    }
#pragma unroll
    for (int j = 0; j < 4; ++j)
#pragma unroll
      for (int r = 0; r < 4; ++r) xg[j][r] = xgn[j][r];
    cur = nxt;
  }
}

// ---------------- attention: qkv = lstm_out @ Win^T + b ----------------
__global__ __launch_bounds__(256) void k_qkv(const short* __restrict__ lout, const short* __restrict__ W, const short* __restrict__ bias, short* __restrict__ qkv){
  int wv = blockIdx.x*4 + (threadIdx.x >> 6);   // 200 waves
  int l = threadIdx.x & 63;
  int row = wv*16 + (l & 15);
  int koff = (l >> 4)*8;
  short8v a[4];
#pragma unroll
  for (int k = 0; k < 4; ++k) a[k] = *(const short8v*)(lout + (size_t)row*128 + k*32 + koff);
  int r0 = wv*16 + (l >> 4)*4;
#pragma unroll
  for (int nt = 0; nt < 24; ++nt){
    f4v acc = {0.f,0.f,0.f,0.f};
#pragma unroll
    for (int k = 0; k < 4; ++k){
      short8v b = *(const short8v*)(W + (size_t)(nt*16 + (l & 15))*128 + k*32 + koff);
      acc = mfma16(a[k], b, acc);
    }
    int col = nt*16 + (l & 15);
    float bv = b2f(bias[col]);
#pragma unroll
    for (int r = 0; r < 4; ++r) qkv[(size_t)(r0 + r)*384 + col] = f2b(acc[r] + bv);
  }
}

// one wave per (batch, head); mean over T fused (output projection deferred)
__global__ __launch_bounds__(64) void k_attn(const short* __restrict__ qkv, float* __restrict__ omean){
  int b = blockIdx.x >> 2, h = blockIdx.x & 3;
  int l = threadIdx.x;
  __shared__ float kl[50][32], vl[50][32], ol[50][32];
  for (int i = l; i < 1600; i += 64){
    int t = i >> 5, c = i & 31;
    kl[t][c] = b2f(qkv[((size_t)b*TT + t)*384 + 128 + h*32 + c]);
    vl[t][c] = b2f(qkv[((size_t)b*TT + t)*384 + 256 + h*32 + c]);
  }
  __syncthreads();
  float o[32];
#pragma unroll
  for (int c = 0; c < 32; ++c) o[c] = 0.f;
  if (l < TT){
    float q[32];
#pragma unroll
    for (int qq = 0; qq < 4; ++qq){
      short8v vq = *(const short8v*)(qkv + ((size_t)b*TT + l)*384 + h*32 + qq*8);
#pragma unroll
      for (int j = 0; j < 8; ++j) q[qq*8 + j] = b2f(vq[j]);
    }
    float sc[50];
    float mx = -1e30f;
    const float scale = 0.17677669529663687f;  // 1/sqrt(32)
#pragma unroll
    for (int j = 0; j < 50; ++j){
      float d = 0.f;
#pragma unroll
      for (int c = 0; c < 32; ++c) d += q[c]*kl[j][c];
      d *= scale;
      sc[j] = d;
      mx = fmaxf(mx, d);
    }
    float sum = 0.f;
#pragma unroll
    for (int j = 0; j < 50; ++j){ float p = __expf(sc[j] - mx); sc[j] = p; sum += p; }
    float inv = 1.f/sum;
#pragma unroll
    for (int j = 0; j < 50; ++j){
      float p = sc[j]*inv;
#pragma unroll
      for (int c = 0; c < 32; ++c) o[c] += p*vl[j][c];
    }
#pragma unroll
    for (int c = 0; c < 32; ++c) ol[l][c] = o[c];
  }
  __syncthreads();
  if (l < 32){
    float s = 0.f;
#pragma unroll
    for (int t = 0; t < TT; ++t) s += ol[t][l];
    omean[(size_t)b*128 + h*32 + l] = s*0.02f;  // mean over T=50
  }
}

// final: combined = [pool/cnt (64), omean @ Wout^T + bout (128)]; out = combined @ fc^T + fcb
__global__ __launch_bounds__(192) void k_final(const float* __restrict__ pool, const float* __restrict__ cntf,
                                               const float* __restrict__ omean,
                                               const short* __restrict__ Woutw, const short* __restrict__ Woutb,
                                               const short* __restrict__ fcw, const short* __restrict__ fcb,
                                               const int* __restrict__ flag, void* __restrict__ outv){
  int b = blockIdx.x;
  int tid = threadIdx.x;
  __shared__ float comb[192];
  if (tid < 64){
    float cnt = cntf[b];
    comb[tid] = pool[b*HD + tid] / fmaxf(cnt, 1.f);
  } else {
    int e = tid - 64;
    float s = b2f(Woutb[e]);
    for (int j = 0; j < 128; ++j) s += omean[(size_t)b*128 + j]*b2f(Woutw[e*128 + j]);
    comb[tid] = s;
  }
  __syncthreads();
  if (tid < 2){
    float s = b2f(fcb[tid]);
    for (int j = 0; j < 192; ++j) s += comb[j]*b2f(fcw[tid*192 + j]);
    if (*flag) ((short*)outv)[b*2 + tid] = f2b(s);
    else       ((float*)outv)[b*2 + tid] = s;
  }
}

extern "C" void kernel_launch(void* const* d_in, const int* in_sizes, int n_in,
                              void* d_out, int out_size, void* d_ws, size_t ws_size,
                              hipStream_t stream){
  const int* ei    = (const int*)d_in[1];
  const int* batch = (const int*)d_in[2];

  char* ws = (char*)d_ws;
  size_t o = 0;
  auto alloc = [&](size_t bytes)->char*{
    char* r = ws + o;
    o = (o + bytes + 255) & ~(size_t)255;
    return r;
  };
  short* arena = (short*)alloc((size_t)6787912*2);
  int*   flag  = (int*)alloc(256);
  char*  bufA  = alloc((size_t)NN*256*2);   // h1c, later h2c+alphaE2+g2
  char*  bufB  = alloc((size_t)NN*256*2);   // g1, later Xp/lout/qkv/omean
  float* a1s  = (float*)alloc((size_t)NN*4*4);
  float* a1d  = (float*)alloc((size_t)NN*4*4);  // becomes sinv1 in k_alpha1
  float* a2s  = (float*)alloc((size_t)NN*4);
  float* a2d  = (float*)alloc((size_t)NN*4);    // becomes sinv2 in k_alpha2
  int*   deg  = (int*)alloc((size_t)NPAD*4);
  int*   offv = (int*)alloc((size_t)(NN+1)*4);
  int*   cur  = (int*)alloc((size_t)NN*4);
  int*   csr  = (int*)alloc((size_t)ETOT*4);
  float* pool = (float*)alloc((size_t)BB*HD*4);
  float* cntf = (float*)alloc((size_t)BB*4);
  float* alphaE1 = (float*)alloc((size_t)ETOT*4*4);   // [ETOT][4] f32

  short* h1c = (short*)bufA;                      // [8][NN][32]
  short* h2c = (short*)bufA;                      // [2][NN][32] overlay (h1c dead after k_gath1)
  float* alphaE2 = (float*)(bufA + 6553600);      // [ETOT] f32, in gap after h2c
  short* g2 = (short*)(bufA + 12800000);          // [NN][64] bf16
  short* g1 = (short*)bufB;
  float* Xp   = (float*)bufB;                     // overlay (g1 dead after k_gemm2)
  short* lout = (short*)(bufB + 6553600);
  short* qkv  = (short*)(bufB + 6553600 + 819200);
  float* omean= (float*)(bufB + 6553600 + 819200 + 2457600);

  // arena views
  const short* xb    = arena + 0;
  const short* seqb  = arena + 6400000;
  const short* w1b   = arena + 6604800;
  const short* as1b  = arena + 6637568;
  const short* ad1b  = arena + 6637824;
  const short* b1b   = arena + 6638080;
  const short* w2b   = arena + 6638336;
  const short* as2b  = arena + 6654720;
  const short* ad2b  = arena + 6654784;
  const short* b2b   = arena + 6654848;
  const short* wihFb = arena + 6654912;
  const short* whhFb = arena + 6671296;
  const short* bihFb = arena + 6687680;
  const short* bhhFb = arena + 6687936;
  const short* wihBb = arena + 6688192;
  const short* whhBb = arena + 6704576;
  const short* bihBb = arena + 6720960;
  const short* bhhBb = arena + 6721216;
  const short* winwb = arena + 6721472;
  const short* winbb = arena + 6770624;
  const short* woutwb= arena + 6771008;
  const short* woutbb= arena + 6787392;
  const short* fcwb  = arena + 6787520;
  const short* fcbb  = arena + 6787904;

  Ptrs P;
  P.p[0]=d_in[0];  P.p[1]=d_in[3];  P.p[2]=d_in[4];  P.p[3]=d_in[5];
  P.p[4]=d_in[6];  P.p[5]=d_in[7];  P.p[6]=d_in[8];  P.p[7]=d_in[9];
  P.p[8]=d_in[10]; P.p[9]=d_in[11]; P.p[10]=d_in[12];P.p[11]=d_in[13];
  P.p[12]=d_in[14];P.p[13]=d_in[15];P.p[14]=d_in[16];P.p[15]=d_in[17];
  P.p[16]=d_in[18];P.p[17]=d_in[19];P.p[18]=d_in[20];P.p[19]=d_in[21];
  P.p[20]=d_in[22];P.p[21]=d_in[23];P.p[22]=d_in[24];P.p[23]=d_in[25];

  // dtype detect + convert
  k_detect<<<1, 256, 0, stream>>>((const unsigned short*)d_in[0], flag);
  k_cvt<<<2048, 256, 0, stream>>>(P, arena, flag);

  // CSR build
  k_init<<<(NPAD+255)/256, 256, 0, stream>>>(deg, pool);
  k_count<<<(EE+255)/256, 256, 0, stream>>>(ei, deg);
  k_scan<<<1, 1024, 0, stream>>>(deg, offv);
  k_self<<<(NN+255)/256, 256, 0, stream>>>(offv, cur, csr);
  k_scatter<<<(EE+255)/256, 256, 0, stream>>>(ei, cur, csr);

  // GAT layer 1
  k_gemm1<<<(NN/16+3)/4, 256, 0, stream>>>(xb, w1b, h1c);
  k_score1<<<(NN*4+255)/256, 256, 0, stream>>>(h1c, as1b, ad1b, a1s, a1d);
  k_alpha1<<<(NN+3)/4, 256, 0, stream>>>(offv, csr, a1s, a1d, alphaE1);
  k_gath1<<<(NN/4)*8, 256, 0, stream>>>(offv, csr, h1c, alphaE1, a1d, b1b, g1);

  // GAT layer 2 + pool
  k_gemm2<<<(NN/16+3)/4, 256, 0, stream>>>(g1, w2b, h2c);
  k_score2<<<(NN+255)/256, 256, 0, stream>>>(h2c, as2b, ad2b, a2s, a2d);
  k_alpha2<<<(NN+3)/4, 256, 0, stream>>>(offv, csr, a2s, a2d, alphaE2);
  k_gath2<<<(NN/4)*2, 256, 0, stream>>>(offv, csr, h2c, alphaE2, a2d, b2b, g2);
  k_pool<<<dim3(8, BB), 256, 0, stream>>>(g2, batch, pool, cntf);

  // LSTM
  k_xp<<<dim3(50, 2), 256, 0, stream>>>(seqb, wihFb, bihFb, bhhFb, wihBb, bihBb, bhhBb, Xp);
  k_lstm<<<dim3(4, 2), 256, 0, stream>>>(Xp, whhFb, whhBb, lout);

  // attention
  k_qkv<<<50, 256, 0, stream>>>(lout, winwb, winbb, qkv);
  k_attn<<<BB*4, 64, 0, stream>>>(qkv, omean);

  // final
  k_final<<<BB, 192, 0, stream>>>(pool, cntf, omean, woutwb, woutbb, fcwb, fcbb, flag, d_out);
}

// Round 11
// 386.663 us; speedup vs baseline: 1.2557x; 1.2237x over previous
//
#include <hip/hip_runtime.h>

#define NN 50000
#define EE 500000
#define BB 64
#define TT 50
#define FN 128
#define FS 64
#define HD 64
#define ETOT (EE + NN)
#define NPAD 50176   // 1024*49, k_scan guard-free

typedef __attribute__((ext_vector_type(8))) short short8v;
typedef __attribute__((ext_vector_type(4))) short short4v;
typedef __attribute__((ext_vector_type(4))) float f4v;

__device__ __forceinline__ float b2f(short u){
  union { unsigned int i; float f; } v; v.i = ((unsigned int)(unsigned short)u) << 16; return v.f;
}
__device__ __forceinline__ short f2b(float f){
  union { float f; unsigned int i; } v; v.f = f;
  unsigned int x = v.i;
  return (short)((x + 0x7fffu + ((x >> 16) & 1u)) >> 16);
}
__device__ __forceinline__ f4v mfma16(short8v a, short8v b, f4v c){
  return __builtin_amdgcn_mfma_f32_16x16x32_bf16(a, b, c, 0, 0, 0);
}
__device__ __forceinline__ float frcp(float x){ return __builtin_amdgcn_rcpf(x); }
__device__ __forceinline__ float fsig(float x){ return frcp(1.f + __expf(-x)); }
__device__ __forceinline__ float ftanh(float x){ return 1.f - 2.f*frcp(1.f + __expf(2.f*x)); }

// ---------------- input dtype detect + convert to bf16 arena ----------------
constexpr int SEG_CUM[25] = {0, 6400000, 6604800, 6637568, 6637824, 6638080,
  6638336, 6654720, 6654784, 6654848, 6654912, 6671296, 6687680, 6687936,
  6688192, 6704576, 6720960, 6721216, 6721472, 6770624, 6771008, 6787392,
  6787520, 6787904, 6787906};
#define ARENA_VEC (6787904/8)

struct Ptrs { const void* p[24]; };

__global__ __launch_bounds__(256) void k_detect(const unsigned short* x16, int* flag){
  __shared__ int cnt;
  if (threadIdx.x == 0) cnt = 0;
  __syncthreads();
  int c = 0;
  for (int i = threadIdx.x; i < 2048; i += 256){
    unsigned short v = x16[2*i];         // even shorts: f32 low-halves (random) vs bf16 values
    int e = (v >> 7) & 0xFF;
    if (e >= 64 && e < 160) c++;
  }
  atomicAdd(&cnt, c);
  __syncthreads();
  if (threadIdx.x == 0) *flag = (cnt >= 1536) ? 1 : 0;   // 1 = inputs are bf16
}

__global__ __launch_bounds__(256) void k_cvt(Ptrs P, short* arena, const int* flag){
  bool isb = (*flag != 0);
  int idx = blockIdx.x*256 + threadIdx.x;
  for (int v = idx; v < ARENA_VEC; v += gridDim.x*256){
    int i = v*8;
    int s = 0;
#pragma unroll
    for (int k = 1; k < 24; ++k) if (i >= SEG_CUM[k]) s = k;
    int j = i - SEG_CUM[s];
    short8v o;
    if (isb){
      o = *(const short8v*)((const short*)P.p[s] + j);
    } else {
      const float* f = (const float*)P.p[s] + j;
      f4v lo = *(const f4v*)f;
      f4v hi = *(const f4v*)(f + 4);
#pragma unroll
      for (int q = 0; q < 4; ++q){ o[q] = f2b(lo[q]); o[4+q] = f2b(hi[q]); }
    }
    *(short8v*)(arena + i) = o;
  }
  if (blockIdx.x == 0 && threadIdx.x == 0){
    for (int j = 0; j < 2; ++j)
      arena[6787904 + j] = isb ? ((const short*)P.p[23])[j] : f2b(((const float*)P.p[23])[j]);
  }
}

// ---------------- CSR build ----------------
__global__ __launch_bounds__(256) void k_init(int* deg, float* pool){
  int i = blockIdx.x*256 + threadIdx.x;
  if (i < NN) deg[i] = 1;            // self loop
  else if (i < NPAD) deg[i] = 0;     // pad for guard-free scan
  if (i < BB*HD) pool[i] = 0.f;
}

__global__ __launch_bounds__(256) void k_count(const int* ei, int* deg){
  int e = blockIdx.x*256 + threadIdx.x;
  if (e < EE) atomicAdd(&deg[ei[EE + e]], 1);
}

// single-pass scan: 49 values/thread held in REGISTERS (guard-free, unrolled)
__global__ __launch_bounds__(1024) void k_scan(const int* __restrict__ deg, int* __restrict__ off){
  __shared__ int buf[1024];
  int tid = threadIdx.x;
  int start = tid*49;
  int v[49];
#pragma unroll
  for (int j = 0; j < 49; ++j) v[j] = deg[start + j];
  int s = 0;
#pragma unroll
  for (int j = 0; j < 49; ++j) s += v[j];
  buf[tid] = s;
  __syncthreads();
  for (int st = 1; st < 1024; st <<= 1){
    int t = (tid >= st) ? buf[tid - st] : 0;
    __syncthreads();
    buf[tid] += t;
    __syncthreads();
  }
  int run = buf[tid] - s;            // exclusive base for this chunk
#pragma unroll
  for (int j = 0; j < 49; ++j){
    int i = start + j;
    if (i < NN) off[i] = run;
    run += v[j];
  }
  if (tid == 1023) off[NN] = run;
}

__global__ __launch_bounds__(256) void k_self(const int* off, int* cur, int* csr){
  int v = blockIdx.x*256 + threadIdx.x;
  if (v < NN){ int o = off[v]; csr[o] = v; cur[v] = o + 1; }
}

__global__ __launch_bounds__(256) void k_scatter(const int* ei, int* cur, int* csr){
  int e = blockIdx.x*256 + threadIdx.x;
  if (e < EE){
    int d = ei[EE + e];
    int pos = atomicAdd(&cur[d], 1);
    csr[pos] = ei[e];
  }
}

// ---------------- GAT layer 1: h1 = x @ W1^T  (50000x128 @ 128x256), row-major ----------------
__global__ __launch_bounds__(256) void k_gemm1(const short* __restrict__ x, const short* __restrict__ W, short* __restrict__ h1){
  int wv = blockIdx.x*4 + (threadIdx.x >> 6);
  if (wv >= NN/16) return;
  int l = threadIdx.x & 63;
  int row = wv*16 + (l & 15);
  int koff = (l >> 4)*8;
  short8v a[4];
#pragma unroll
  for (int k = 0; k < 4; ++k) a[k] = *(const short8v*)(x + (size_t)row*128 + k*32 + koff);
  int r0 = wv*16 + (l >> 4)*4;
#pragma unroll
  for (int nt = 0; nt < 16; ++nt){
    f4v acc = {0.f,0.f,0.f,0.f};
#pragma unroll
    for (int k = 0; k < 4; ++k){
      short8v b = *(const short8v*)(W + (size_t)(nt*16 + (l & 15))*128 + k*32 + koff);
      acc = mfma16(a[k], b, acc);
    }
    int col = nt*16 + (l & 15);
#pragma unroll
    for (int r = 0; r < 4; ++r) h1[(size_t)(r0 + r)*256 + col] = f2b(acc[r]);
  }
}

__global__ __launch_bounds__(256) void k_score1(const short* __restrict__ h1, const short* __restrict__ as, const short* __restrict__ ad, float* a1s, float* a1d){
  int i = blockIdx.x*256 + threadIdx.x;
  if (i >= NN*4) return;
  int n = i >> 2, h = i & 3;
  float ss = 0.f, sd = 0.f;
#pragma unroll
  for (int q = 0; q < 8; ++q){
    short8v hv = *(const short8v*)(h1 + (size_t)n*256 + h*64 + q*8);
    short8v sv = *(const short8v*)(as + h*64 + q*8);
    short8v dv = *(const short8v*)(ad + h*64 + q*8);
#pragma unroll
    for (int j = 0; j < 8; ++j){ float v = b2f(hv[j]); ss += v*b2f(sv[j]); sd += v*b2f(dv[j]); }
  }
  a1s[i] = ss; a1d[i] = sd;
}

// ---- alpha layer 1: one wave per node, ONCE. p = exp(min(leaky,30)); 1/s -> sinv (over a1d)
__global__ __launch_bounds__(256) void k_alpha1(const int* __restrict__ off, const int* __restrict__ csr,
                                                const float* __restrict__ a1s, float* __restrict__ sinv,
                                                float* __restrict__ alphaE){
  int v = blockIdx.x*4 + (threadIdx.x >> 6);
  if (v >= NN) return;
  int l = threadIdx.x & 63;
  const f4v ad4 = *(const f4v*)(sinv + v*4);     // a1d values (read before overwrite)
  int e0 = off[v], e1 = off[v+1];
  float s0=0.f,s1=0.f,s2=0.f,s3=0.f;
  for (int base = e0; base < e1; base += 64){
    int nc = e1 - base; if (nc > 64) nc = 64;
    float p0=0.f,p1=0.f,p2=0.f,p3=0.f;
    if (l < nc){
      int u = csr[base + l];
      f4v as4 = *(const f4v*)(a1s + u*4);
      float t0 = as4[0]+ad4[0]; t0 = (t0>=0.f)?t0:0.2f*t0; p0 = __expf(fminf(t0,30.f));
      float t1 = as4[1]+ad4[1]; t1 = (t1>=0.f)?t1:0.2f*t1; p1 = __expf(fminf(t1,30.f));
      float t2 = as4[2]+ad4[2]; t2 = (t2>=0.f)?t2:0.2f*t2; p2 = __expf(fminf(t2,30.f));
      float t3 = as4[3]+ad4[3]; t3 = (t3>=0.f)?t3:0.2f*t3; p3 = __expf(fminf(t3,30.f));
      f4v pv; pv[0]=p0; pv[1]=p1; pv[2]=p2; pv[3]=p3;
      *(f4v*)(alphaE + (size_t)(base+l)*4) = pv;
    }
    float q0=p0,q1=p1,q2=p2,q3=p3;
#pragma unroll
    for (int st = 1; st < 64; st <<= 1){
      q0 += __shfl_xor(q0, st, 64);
      q1 += __shfl_xor(q1, st, 64);
      q2 += __shfl_xor(q2, st, 64);
      q3 += __shfl_xor(q3, st, 64);
    }
    s0 += q0; s1 += q1; s2 += q2; s3 += q3;
  }
  if (l == 0){
    f4v sv; sv[0]=1.f/s0; sv[1]=1.f/s1; sv[2]=1.f/s2; sv[3]=1.f/s3;
    *(f4v*)(sinv + v*4) = sv;
  }
}

// ---- gather layer 1: one wave per node, lane = 4 channels of full 256-ch row
__global__ __launch_bounds__(256) void k_gath1(const int* __restrict__ off, const int* __restrict__ csr,
                                               const short* __restrict__ h1, const float* __restrict__ alphaE,
                                               const float* __restrict__ sinv, const short* __restrict__ b1,
                                               short* __restrict__ g1){
  int v = blockIdx.x*4 + (threadIdx.x >> 6);
  if (v >= NN) return;
  int l = threadIdx.x & 63;
  int hh = l >> 4;
  int c0 = l*4;
  int e0 = off[v], e1 = off[v+1];
  f4v acc = {0.f,0.f,0.f,0.f};
#pragma unroll 4
  for (int e = e0; e < e1; ++e){
    int u = csr[e];
    float p = alphaE[(size_t)e*4 + hh];
    short4v hv = *(const short4v*)(h1 + (size_t)u*256 + c0);
    acc[0] += p*b2f(hv[0]);
    acc[1] += p*b2f(hv[1]);
    acc[2] += p*b2f(hv[2]);
    acc[3] += p*b2f(hv[3]);
  }
  float inv = sinv[v*4 + hh];
  short4v o;
  o[0] = f2b(fmaxf(acc[0]*inv + b2f(b1[c0+0]), 0.f));
  o[1] = f2b(fmaxf(acc[1]*inv + b2f(b1[c0+1]), 0.f));
  o[2] = f2b(fmaxf(acc[2]*inv + b2f(b1[c0+2]), 0.f));
  o[3] = f2b(fmaxf(acc[3]*inv + b2f(b1[c0+3]), 0.f));
  *(short4v*)(g1 + (size_t)v*256 + c0) = o;
}

// ---------------- GAT layer 2: h2 = g1 @ W2^T (50000x256 @ 256x64), row-major ----------------
__global__ __launch_bounds__(256) void k_gemm2(const short* __restrict__ g1, const short* __restrict__ W, short* __restrict__ h2){
  int wv = blockIdx.x*4 + (threadIdx.x >> 6);
  if (wv >= NN/16) return;
  int l = threadIdx.x & 63;
  int row = wv*16 + (l & 15);
  int koff = (l >> 4)*8;
  short8v a[8];
#pragma unroll
  for (int k = 0; k < 8; ++k) a[k] = *(const short8v*)(g1 + (size_t)row*256 + k*32 + koff);
  int r0 = wv*16 + (l >> 4)*4;
#pragma unroll
  for (int nt = 0; nt < 4; ++nt){
    f4v acc = {0.f,0.f,0.f,0.f};
#pragma unroll
    for (int k = 0; k < 8; ++k){
      short8v b = *(const short8v*)(W + (size_t)(nt*16 + (l & 15))*256 + k*32 + koff);
      acc = mfma16(a[k], b, acc);
    }
    int col = nt*16 + (l & 15);
#pragma unroll
    for (int r = 0; r < 4; ++r) h2[(size_t)(r0 + r)*64 + col] = f2b(acc[r]);
  }
}

__global__ __launch_bounds__(256) void k_score2(const short* __restrict__ h2, const short* __restrict__ as, const short* __restrict__ ad, float* a2s, float* a2d){
  int n = blockIdx.x*256 + threadIdx.x;
  if (n >= NN) return;
  float ss = 0.f, sd = 0.f;
#pragma unroll
  for (int q = 0; q < 8; ++q){
    short8v hv = *(const short8v*)(h2 + (size_t)n*64 + q*8);
    short8v sv = *(const short8v*)(as + q*8);
    short8v dv = *(const short8v*)(ad + q*8);
#pragma unroll
    for (int j = 0; j < 8; ++j){ float v = b2f(hv[j]); ss += v*b2f(sv[j]); sd += v*b2f(dv[j]); }
  }
  a2s[n] = ss; a2d[n] = sd;
}

// ---- alpha layer 2: one wave per node, single head; sinv over a2d
__global__ __launch_bounds__(256) void k_alpha2(const int* __restrict__ off, const int* __restrict__ csr,
                                                const float* __restrict__ a2s, float* __restrict__ sinv,
                                                float* __restrict__ alphaE){
  int v = blockIdx.x*4 + (threadIdx.x >> 6);
  if (v >= NN) return;
  int l = threadIdx.x & 63;
  float adst = sinv[v];                  // a2d value (read before overwrite)
  int e0 = off[v], e1 = off[v+1];
  float s = 0.f;
  for (int base = e0; base < e1; base += 64){
    int nc = e1 - base; if (nc > 64) nc = 64;
    float p = 0.f;
    if (l < nc){
      int u = csr[base + l];
      float t = a2s[u] + adst;
      t = (t>=0.f)?t:0.2f*t;
      p = __expf(fminf(t,30.f));
      alphaE[base + l] = p;
    }
    float q = p;
#pragma unroll
    for (int st = 1; st < 64; st <<= 1) q += __shfl_xor(q, st, 64);
    s += q;
  }
  if (l == 0) sinv[v] = 1.f/s;
}

// ---- gather layer 2: one wave per node, lane = channel (64ch row)
__global__ __launch_bounds__(256) void k_gath2(const int* __restrict__ off, const int* __restrict__ csr,
                                               const short* __restrict__ h2, const float* __restrict__ alphaE,
                                               const float* __restrict__ sinv, const short* __restrict__ b2,
                                               short* __restrict__ g2){
  int v = blockIdx.x*4 + (threadIdx.x >> 6);
  if (v >= NN) return;
  int l = threadIdx.x & 63;
  int e0 = off[v], e1 = off[v+1];
  float acc = 0.f;
#pragma unroll 4
  for (int e = e0; e < e1; ++e){
    int u = csr[e];
    float p = alphaE[e];
    acc += p*b2f(h2[(size_t)u*64 + l]);
  }
  float val = fmaxf(acc*sinv[v] + b2f(b2[l]), 0.f);
  g2[(size_t)v*64 + l] = f2b(val);
}

// ---- segment mean-pool over sorted batch: grid (8 splits, 64 segments)
__global__ __launch_bounds__(256) void k_pool(const short* __restrict__ g2, const int* __restrict__ batch,
                                              float* __restrict__ pool, float* __restrict__ cntf){
  int b = blockIdx.y;
  int split = blockIdx.x;       // 0..7
  __shared__ int seg[2];
  __shared__ float red[4][64];
  int tid = threadIdx.x;
  if (tid == 0){
    int lo = 0, hi = NN;
    while (lo < hi){ int mid = (lo+hi)>>1; if (batch[mid] < b) lo = mid+1; else hi = mid; }
    seg[0] = lo;
    lo = 0; hi = NN;
    while (lo < hi){ int mid = (lo+hi)>>1; if (batch[mid] < b+1) lo = mid+1; else hi = mid; }
    seg[1] = lo;
  }
  __syncthreads();
  int lo = seg[0], hi = seg[1];
  int c = tid & 63;
  int rg = tid >> 6;            // 0..3
  float acc = 0.f;
  for (int r = lo + split*4 + rg; r < hi; r += 32)
    acc += b2f(g2[(size_t)r*64 + c]);
  red[rg][c] = acc;
  __syncthreads();
  if (tid < 64){
    float sum = red[0][tid] + red[1][tid] + red[2][tid] + red[3][tid];
    atomicAdd(&pool[b*HD + tid], sum);
  }
  if (split == 0 && tid == 0) cntf[b] = (float)(hi - lo);
}

// ---------------- LSTM pre-GEMM: Xp stored in PERMUTED gate order ----------------
__global__ __launch_bounds__(256) void k_xp(const short* __restrict__ seq,
                                            const short* __restrict__ WihF, const short* __restrict__ bihF, const short* __restrict__ bhhF,
                                            const short* __restrict__ WihB, const short* __restrict__ bihB, const short* __restrict__ bhhB,
                                            float* __restrict__ Xp){
  int dir = blockIdx.y;
  const short* Wih = dir ? WihB : WihF;
  const short* bih = dir ? bihB : bihF;
  const short* bhh = dir ? bhhB : bhhF;
  int wv = blockIdx.x*4 + (threadIdx.x >> 6);   // 200 waves
  int l = threadIdx.x & 63;
  int row = wv*16 + (l & 15);
  int koff = (l >> 4)*8;
  short8v a[2];
#pragma unroll
  for (int k = 0; k < 2; ++k) a[k] = *(const short8v*)(seq + (size_t)row*64 + k*32 + koff);
  int r0 = wv*16 + (l >> 4)*4;
  float* Xpd = Xp + (size_t)dir*TT*BB*256;
#pragma unroll
  for (int nt = 0; nt < 16; ++nt){
    f4v acc = {0.f,0.f,0.f,0.f};
#pragma unroll
    for (int k = 0; k < 2; ++k){
      short8v b = *(const short8v*)(Wih + (size_t)(nt*16 + (l & 15))*64 + k*32 + koff);
      acc = mfma16(a[k], b, acc);
    }
    int col = nt*16 + (l & 15);
    float bias = b2f(bih[col]) + b2f(bhh[col]);
    int gate = col >> 6, ch = col & 63;
    int pcol = ((ch>>5)*8 + ((ch>>4)&1)*4 + gate)*16 + (ch & 15);
#pragma unroll
    for (int r = 0; r < 4; ++r){
      int rr = r0 + r;
      int bidx = rr / TT, t = rr % TT;
      Xpd[((size_t)t*BB + bidx)*256 + pcol] = acc[r] + bias;
    }
  }
}

// persistent LSTM: 8 blocks (2 dir x 4 batch-groups of 16 rows), 256 threads (4 waves).
__global__ __launch_bounds__(256) void k_lstm(const float* __restrict__ Xp,
                                              const short* __restrict__ WhhF, const short* __restrict__ WhhB,
                                              short* __restrict__ lout){
  int bg  = blockIdx.x;            // 0..3 batch-group
  int dir = blockIdx.y;
  const short* Whh = dir ? WhhB : WhhF;
  const float* Xpd = Xp + (size_t)dir*TT*BB*256 + (size_t)bg*16*256;
  __shared__ short hl[2][16][72];     // stride 36 words: 2-way banks (free)
  __shared__ short whl[256][72];
  int tid = threadIdx.x;
  {
    int p = tid;
    int nt = p >> 4, c16p = p & 15;
    int jj = nt & 7, half = nt >> 3;
    int gate = jj & 3, ch = half*32 + (jj>>2)*16 + c16p;
    int src = gate*64 + ch;
#pragma unroll
    for (int q = 0; q < 8; ++q){
      short8v vv = *(const short8v*)(Whh + (size_t)src*64 + q*8);
      *(short8v*)&whl[p][q*8] = vv;
    }
  }
  for (int i = tid; i < 16*64; i += 256) hl[0][i>>6][i&63] = 0;

  int l = tid & 63;
  int w = tid >> 6;                 // wave = gate-group
  int c16 = l & 15;
  int koff = (l >> 4)*8;
  int r0 = (l >> 4)*4;
  int ch = (w>>1)*32 + (w&1)*16 + c16;
  float creg[4] = {0.f,0.f,0.f,0.f};

  float xg[4][4];
  {
    int t0 = dir ? (TT-1) : 0;
    const float* xpb = Xpd + (size_t)t0*BB*256;
#pragma unroll
    for (int j = 0; j < 4; ++j){
      int p = (w*4 + j)*16 + c16;
#pragma unroll
      for (int r = 0; r < 4; ++r) xg[j][r] = xpb[(size_t)(r0 + r)*256 + p];
    }
  }

  int cur = 0;
  for (int s = 0; s < TT; ++s){
    int t = dir ? (TT - 1 - s) : s;
    __syncthreads();
    float xgn[4][4];
    if (s + 1 < TT){
      int tn = dir ? (TT - 2 - s) : (s + 1);
      const float* xpb = Xpd + (size_t)tn*BB*256;
#pragma unroll
      for (int j = 0; j < 4; ++j){
        int p = (w*4 + j)*16 + c16;
#pragma unroll
        for (int r = 0; r < 4; ++r) xgn[j][r] = xpb[(size_t)(r0 + r)*256 + p];
      }
    }
    short8v a0 = *(const short8v*)&hl[cur][c16][koff];
    short8v a1 = *(const short8v*)&hl[cur][c16][32 + koff];
    f4v acc[4];
#pragma unroll
    for (int j = 0; j < 4; ++j){
      int nt = w*4 + j;
      short8v b0 = *(const short8v*)&whl[nt*16 + c16][koff];
      short8v b1 = *(const short8v*)&whl[nt*16 + c16][32 + koff];
      f4v z = {0.f,0.f,0.f,0.f};
      z = mfma16(a0, b0, z);
      z = mfma16(a1, b1, z);
      acc[j] = z;
    }
    int nxt = cur ^ 1;
#pragma unroll
    for (int r = 0; r < 4; ++r){
      float gi = acc[0][r] + xg[0][r];
      float gf = acc[1][r] + xg[1][r];
      float gg = acc[2][r] + xg[2][r];
      float go = acc[3][r] + xg[3][r];
      float cn = fsig(gf)*creg[r] + fsig(gi)*ftanh(gg);
      creg[r] = cn;
      float hv = fsig(go)*ftanh(cn);
      short hb = f2b(hv);
      int row = r0 + r;
      hl[nxt][row][ch] = hb;
      lout[((size_t)(bg*16 + row)*TT + t)*128 + dir*64 + ch] = hb;
    }
#pragma unroll
    for (int j = 0; j < 4; ++j)
#pragma unroll
      for (int r = 0; r < 4; ++r) xg[j][r] = xgn[j][r];
    cur = nxt;
  }
}

// ---------------- attention: qkv = lstm_out @ Win^T + b ----------------
__global__ __launch_bounds__(256) void k_qkv(const short* __restrict__ lout, const short* __restrict__ W, const short* __restrict__ bias, short* __restrict__ qkv){
  int wv = blockIdx.x*4 + (threadIdx.x >> 6);   // 200 waves
  int l = threadIdx.x & 63;
  int row = wv*16 + (l & 15);
  int koff = (l >> 4)*8;
  short8v a[4];
#pragma unroll
  for (int k = 0; k < 4; ++k) a[k] = *(const short8v*)(lout + (size_t)row*128 + k*32 + koff);
  int r0 = wv*16 + (l >> 4)*4;
#pragma unroll
  for (int nt = 0; nt < 24; ++nt){
    f4v acc = {0.f,0.f,0.f,0.f};
#pragma unroll
    for (int k = 0; k < 4; ++k){
      short8v b = *(const short8v*)(W + (size_t)(nt*16 + (l & 15))*128 + k*32 + koff);
      acc = mfma16(a[k], b, acc);
    }
    int col = nt*16 + (l & 15);
    float bv = b2f(bias[col]);
#pragma unroll
    for (int r = 0; r < 4; ++r) qkv[(size_t)(r0 + r)*384 + col] = f2b(acc[r] + bv);
  }
}

// one wave per (batch, head); mean over T fused (output projection deferred)
__global__ __launch_bounds__(64) void k_attn(const short* __restrict__ qkv, float* __restrict__ omean){
  int b = blockIdx.x >> 2, h = blockIdx.x & 3;
  int l = threadIdx.x;
  __shared__ float kl[50][32], vl[50][32], ol[50][32];
  for (int i = l; i < 1600; i += 64){
    int t = i >> 5, c = i & 31;
    kl[t][c] = b2f(qkv[((size_t)b*TT + t)*384 + 128 + h*32 + c]);
    vl[t][c] = b2f(qkv[((size_t)b*TT + t)*384 + 256 + h*32 + c]);
  }
  __syncthreads();
  float o[32];
#pragma unroll
  for (int c = 0; c < 32; ++c) o[c] = 0.f;
  if (l < TT){
    float q[32];
#pragma unroll
    for (int qq = 0; qq < 4; ++qq){
      short8v vq = *(const short8v*)(qkv + ((size_t)b*TT + l)*384 + h*32 + qq*8);
#pragma unroll
      for (int j = 0; j < 8; ++j) q[qq*8 + j] = b2f(vq[j]);
    }
    float sc[50];
    float mx = -1e30f;
    const float scale = 0.17677669529663687f;  // 1/sqrt(32)
#pragma unroll
    for (int j = 0; j < 50; ++j){
      float d = 0.f;
#pragma unroll
      for (int c = 0; c < 32; ++c) d += q[c]*kl[j][c];
      d *= scale;
      sc[j] = d;
      mx = fmaxf(mx, d);
    }
    float sum = 0.f;
#pragma unroll
    for (int j = 0; j < 50; ++j){ float p = __expf(sc[j] - mx); sc[j] = p; sum += p; }
    float inv = 1.f/sum;
#pragma unroll
    for (int j = 0; j < 50; ++j){
      float p = sc[j]*inv;
#pragma unroll
      for (int c = 0; c < 32; ++c) o[c] += p*vl[j][c];
    }
#pragma unroll
    for (int c = 0; c < 32; ++c) ol[l][c] = o[c];
  }
  __syncthreads();
  if (l < 32){
    float s = 0.f;
#pragma unroll
    for (int t = 0; t < TT; ++t) s += ol[t][l];
    omean[(size_t)b*128 + h*32 + l] = s*0.02f;  // mean over T=50
  }
}

// final: combined = [pool/cnt (64), omean @ Wout^T + bout (128)]; out = combined @ fc^T + fcb
__global__ __launch_bounds__(192) void k_final(const float* __restrict__ pool, const float* __restrict__ cntf,
                                               const float* __restrict__ omean,
                                               const short* __restrict__ Woutw, const short* __restrict__ Woutb,
                                               const short* __restrict__ fcw, const short* __restrict__ fcb,
                                               const int* __restrict__ flag, void* __restrict__ outv){
  int b = blockIdx.x;
  int tid = threadIdx.x;
  __shared__ float comb[192];
  if (tid < 64){
    float cnt = cntf[b];
    comb[tid] = pool[b*HD + tid] / fmaxf(cnt, 1.f);
  } else {
    int e = tid - 64;
    float s = b2f(Woutb[e]);
    for (int j = 0; j < 128; ++j) s += omean[(size_t)b*128 + j]*b2f(Woutw[e*128 + j]);
    comb[tid] = s;
  }
  __syncthreads();
  if (tid < 2){
    float s = b2f(fcb[tid]);
    for (int j = 0; j < 192; ++j) s += comb[j]*b2f(fcw[tid*192 + j]);
    if (*flag) ((short*)outv)[b*2 + tid] = f2b(s);
    else       ((float*)outv)[b*2 + tid] = s;
  }
}

extern "C" void kernel_launch(void* const* d_in, const int* in_sizes, int n_in,
                              void* d_out, int out_size, void* d_ws, size_t ws_size,
                              hipStream_t stream){
  const int* ei    = (const int*)d_in[1];
  const int* batch = (const int*)d_in[2];

  char* ws = (char*)d_ws;
  size_t o = 0;
  auto alloc = [&](size_t bytes)->char*{
    char* r = ws + o;
    o = (o + bytes + 255) & ~(size_t)255;
    return r;
  };
  short* arena = (short*)alloc((size_t)6787912*2);
  int*   flag  = (int*)alloc(256);
  char*  bufA  = alloc((size_t)NN*256*2);   // h1, later h2+alphaE2+g2
  char*  bufB  = alloc((size_t)NN*256*2);   // g1, later Xp/lout/qkv/omean
  float* a1s  = (float*)alloc((size_t)NN*4*4);
  float* a1d  = (float*)alloc((size_t)NN*4*4);  // becomes sinv1 in k_alpha1
  float* a2s  = (float*)alloc((size_t)NN*4);
  float* a2d  = (float*)alloc((size_t)NN*4);    // becomes sinv2 in k_alpha2
  int*   deg  = (int*)alloc((size_t)NPAD*4);
  int*   offv = (int*)alloc((size_t)(NN+1)*4);
  int*   cur  = (int*)alloc((size_t)NN*4);
  int*   csr  = (int*)alloc((size_t)ETOT*4);
  float* pool = (float*)alloc((size_t)BB*HD*4);
  float* cntf = (float*)alloc((size_t)BB*4);
  float* alphaE1 = (float*)alloc((size_t)ETOT*4*4);   // [ETOT][4] f32

  short* h1 = (short*)bufA;                       // [NN][256]
  short* h2 = (short*)bufA;                       // [NN][64] overlay (h1 dead after k_gath1)
  float* alphaE2 = (float*)(bufA + 6553600);      // [ETOT] f32, after h2
  short* g2 = (short*)(bufA + 12800000);          // [NN][64] bf16
  short* g1 = (short*)bufB;
  float* Xp   = (float*)bufB;                     // overlay (g1 dead after k_gemm2)
  short* lout = (short*)(bufB + 6553600);
  short* qkv  = (short*)(bufB + 6553600 + 819200);
  float* omean= (float*)(bufB + 6553600 + 819200 + 2457600);

  // arena views
  const short* xb    = arena + 0;
  const short* seqb  = arena + 6400000;
  const short* w1b   = arena + 6604800;
  const short* as1b  = arena + 6637568;
  const short* ad1b  = arena + 6637824;
  const short* b1b   = arena + 6638080;
  const short* w2b   = arena + 6638336;
  const short* as2b  = arena + 6654720;
  const short* ad2b  = arena + 6654784;
  const short* b2b   = arena + 6654848;
  const short* wihFb = arena + 6654912;
  const short* whhFb = arena + 6671296;
  const short* bihFb = arena + 6687680;
  const short* bhhFb = arena + 6687936;
  const short* wihBb = arena + 6688192;
  const short* whhBb = arena + 6704576;
  const short* bihBb = arena + 6720960;
  const short* bhhBb = arena + 6721216;
  const short* winwb = arena + 6721472;
  const short* winbb = arena + 6770624;
  const short* woutwb= arena + 6771008;
  const short* woutbb= arena + 6787392;
  const short* fcwb  = arena + 6787520;
  const short* fcbb  = arena + 6787904;

  Ptrs P;
  P.p[0]=d_in[0];  P.p[1]=d_in[3];  P.p[2]=d_in[4];  P.p[3]=d_in[5];
  P.p[4]=d_in[6];  P.p[5]=d_in[7];  P.p[6]=d_in[8];  P.p[7]=d_in[9];
  P.p[8]=d_in[10]; P.p[9]=d_in[11]; P.p[10]=d_in[12];P.p[11]=d_in[13];
  P.p[12]=d_in[14];P.p[13]=d_in[15];P.p[14]=d_in[16];P.p[15]=d_in[17];
  P.p[16]=d_in[18];P.p[17]=d_in[19];P.p[18]=d_in[20];P.p[19]=d_in[21];
  P.p[20]=d_in[22];P.p[21]=d_in[23];P.p[22]=d_in[24];P.p[23]=d_in[25];

  // dtype detect + convert
  k_detect<<<1, 256, 0, stream>>>((const unsigned short*)d_in[0], flag);
  k_cvt<<<2048, 256, 0, stream>>>(P, arena, flag);

  // CSR build
  k_init<<<(NPAD+255)/256, 256, 0, stream>>>(deg, pool);
  k_count<<<(EE+255)/256, 256, 0, stream>>>(ei, deg);
  k_scan<<<1, 1024, 0, stream>>>(deg, offv);
  k_self<<<(NN+255)/256, 256, 0, stream>>>(offv, cur, csr);
  k_scatter<<<(EE+255)/256, 256, 0, stream>>>(ei, cur, csr);

  // GAT layer 1
  k_gemm1<<<(NN/16+3)/4, 256, 0, stream>>>(xb, w1b, h1);
  k_score1<<<(NN*4+255)/256, 256, 0, stream>>>(h1, as1b, ad1b, a1s, a1d);
  k_alpha1<<<(NN+3)/4, 256, 0, stream>>>(offv, csr, a1s, a1d, alphaE1);
  k_gath1<<<(NN+3)/4, 256, 0, stream>>>(offv, csr, h1, alphaE1, a1d, b1b, g1);

  // GAT layer 2 + pool
  k_gemm2<<<(NN/16+3)/4, 256, 0, stream>>>(g1, w2b, h2);
  k_score2<<<(NN+255)/256, 256, 0, stream>>>(h2, as2b, ad2b, a2s, a2d);
  k_alpha2<<<(NN+3)/4, 256, 0, stream>>>(offv, csr, a2s, a2d, alphaE2);
  k_gath2<<<(NN+3)/4, 256, 0, stream>>>(offv, csr, h2, alphaE2, a2d, b2b, g2);
  k_pool<<<dim3(8, BB), 256, 0, stream>>>(g2, batch, pool, cntf);

  // LSTM
  k_xp<<<dim3(50, 2), 256, 0, stream>>>(seqb, wihFb, bihFb, bhhFb, wihBb, bihBb, bhhBb, Xp);
  k_lstm<<<dim3(4, 2), 256, 0, stream>>>(Xp, whhFb, whhBb, lout);

  // attention
  k_qkv<<<50, 256, 0, stream>>>(lout, winwb, winbb, qkv);
  k_attn<<<BB*4, 64, 0, stream>>>(qkv, omean);

  // final
  k_final<<<BB, 192, 0, stream>>>(pool, cntf, omean, woutwb, woutbb, fcwb, fcbb, flag, d_out);
}

// Round 12
// 358.670 us; speedup vs baseline: 1.3537x; 1.0780x over previous
//
#include <hip/hip_runtime.h>

#define NN 50000
#define EE 500000
#define BB 64
#define TT 50
#define FN 128
#define FS 64
#define HD 64
#define ETOT (EE + NN)
#define NPAD 50176   // 1024*49, k_scan guard-free

typedef __attribute__((ext_vector_type(8))) short short8v;
typedef __attribute__((ext_vector_type(4))) short short4v;
typedef __attribute__((ext_vector_type(4))) float f4v;

__device__ __forceinline__ float b2f(short u){
  union { unsigned int i; float f; } v; v.i = ((unsigned int)(unsigned short)u) << 16; return v.f;
}
__device__ __forceinline__ short f2b(float f){
  union { float f; unsigned int i; } v; v.f = f;
  unsigned int x = v.i;
  return (short)((x + 0x7fffu + ((x >> 16) & 1u)) >> 16);
}
__device__ __forceinline__ f4v mfma16(short8v a, short8v b, f4v c){
  return __builtin_amdgcn_mfma_f32_16x16x32_bf16(a, b, c, 0, 0, 0);
}
__device__ __forceinline__ float frcp(float x){ return __builtin_amdgcn_rcpf(x); }
__device__ __forceinline__ float fsig(float x){ return frcp(1.f + __expf(-x)); }
__device__ __forceinline__ float ftanh(float x){ return 1.f - 2.f*frcp(1.f + __expf(2.f*x)); }

// ---------------- input convert to bf16 arena (dtype detect folded in) ----------------
constexpr int SEG_CUM[25] = {0, 6400000, 6604800, 6637568, 6637824, 6638080,
  6638336, 6654720, 6654784, 6654848, 6654912, 6671296, 6687680, 6687936,
  6688192, 6704576, 6720960, 6721216, 6721472, 6770624, 6771008, 6787392,
  6787520, 6787904, 6787906};
#define ARENA_VEC (6787904/8)

struct Ptrs { const void* p[24]; };

__global__ __launch_bounds__(256) void k_cvt(Ptrs P, short* arena, int* flag){
  // per-block local dtype detect (deterministic, same data -> same result)
  __shared__ int cnt;
  if (threadIdx.x == 0) cnt = 0;
  __syncthreads();
  {
    const unsigned short* x16 = (const unsigned short*)P.p[0];
    int c = 0;
    for (int i = threadIdx.x; i < 2048; i += 256){
      unsigned short vv = x16[2*i];     // even shorts: f32 low-halves (random) vs bf16 values
      int e = (vv >> 7) & 0xFF;
      if (e >= 64 && e < 160) c++;
    }
    atomicAdd(&cnt, c);
  }
  __syncthreads();
  bool isb = (cnt >= 1536);             // 1 = inputs are bf16
  if (blockIdx.x == 0 && threadIdx.x == 0) *flag = isb ? 1 : 0;

  int idx = blockIdx.x*256 + threadIdx.x;
  for (int v = idx; v < ARENA_VEC; v += gridDim.x*256){
    int i = v*8;
    int s = 0;
#pragma unroll
    for (int k = 1; k < 24; ++k) if (i >= SEG_CUM[k]) s = k;
    int j = i - SEG_CUM[s];
    short8v o;
    if (isb){
      o = *(const short8v*)((const short*)P.p[s] + j);
    } else {
      const float* f = (const float*)P.p[s] + j;
      f4v lo = *(const f4v*)f;
      f4v hi = *(const f4v*)(f + 4);
#pragma unroll
      for (int q = 0; q < 4; ++q){ o[q] = f2b(lo[q]); o[4+q] = f2b(hi[q]); }
    }
    *(short8v*)(arena + i) = o;
  }
  if (blockIdx.x == 0 && threadIdx.x == 0){
    for (int j = 0; j < 2; ++j)
      arena[6787904 + j] = isb ? ((const short*)P.p[23])[j] : f2b(((const float*)P.p[23])[j]);
  }
}

// ---------------- CSR build ----------------
__global__ __launch_bounds__(256) void k_init(int* deg, float* pool){
  int i = blockIdx.x*256 + threadIdx.x;
  if (i < NN) deg[i] = 1;            // self loop
  else if (i < NPAD) deg[i] = 0;     // pad for guard-free scan
  if (i < BB*HD) pool[i] = 0.f;
}

__global__ __launch_bounds__(256) void k_count(const int* ei, int* deg){
  int e = blockIdx.x*256 + threadIdx.x;
  if (e < EE) atomicAdd(&deg[ei[EE + e]], 1);
}

// single-pass scan: 49 values/thread held in REGISTERS (guard-free, unrolled)
__global__ __launch_bounds__(1024) void k_scan(const int* __restrict__ deg, int* __restrict__ off){
  __shared__ int buf[1024];
  int tid = threadIdx.x;
  int start = tid*49;
  int v[49];
#pragma unroll
  for (int j = 0; j < 49; ++j) v[j] = deg[start + j];
  int s = 0;
#pragma unroll
  for (int j = 0; j < 49; ++j) s += v[j];
  buf[tid] = s;
  __syncthreads();
  for (int st = 1; st < 1024; st <<= 1){
    int t = (tid >= st) ? buf[tid - st] : 0;
    __syncthreads();
    buf[tid] += t;
    __syncthreads();
  }
  int run = buf[tid] - s;            // exclusive base for this chunk
#pragma unroll
  for (int j = 0; j < 49; ++j){
    int i = start + j;
    if (i < NN) off[i] = run;
    run += v[j];
  }
  if (tid == 1023) off[NN] = run;
}

__global__ __launch_bounds__(256) void k_self(const int* off, int* cur, int* csr){
  int v = blockIdx.x*256 + threadIdx.x;
  if (v < NN){ int o = off[v]; csr[o] = v; cur[v] = o + 1; }
}

__global__ __launch_bounds__(256) void k_scatter(const int* ei, int* cur, int* csr){
  int e = blockIdx.x*256 + threadIdx.x;
  if (e < EE){
    int d = ei[EE + e];
    int pos = atomicAdd(&cur[d], 1);
    csr[pos] = ei[e];
  }
}

// ---------------- GAT layer 1 GEMM + fused scores: h1 = x @ W1^T; a1s/a1d from f32 acc ----------------
__global__ __launch_bounds__(256) void k_gemm1(const short* __restrict__ x, const short* __restrict__ W,
                                               const short* __restrict__ as, const short* __restrict__ ad,
                                               short* __restrict__ h1, float* __restrict__ a1s, float* __restrict__ a1d){
  int wv = blockIdx.x*4 + (threadIdx.x >> 6);
  if (wv >= NN/16) return;
  int l = threadIdx.x & 63;
  int row = wv*16 + (l & 15);
  int koff = (l >> 4)*8;
  short8v a[4];
#pragma unroll
  for (int k = 0; k < 4; ++k) a[k] = *(const short8v*)(x + (size_t)row*128 + k*32 + koff);
  int r0 = wv*16 + (l >> 4)*4;
  float ssA[4][4], sdA[4][4];      // [head][r]
#pragma unroll
  for (int h = 0; h < 4; ++h)
#pragma unroll
    for (int r = 0; r < 4; ++r){ ssA[h][r] = 0.f; sdA[h][r] = 0.f; }
#pragma unroll
  for (int nt = 0; nt < 16; ++nt){
    f4v acc = {0.f,0.f,0.f,0.f};
#pragma unroll
    for (int k = 0; k < 4; ++k){
      short8v b = *(const short8v*)(W + (size_t)(nt*16 + (l & 15))*128 + k*32 + koff);
      acc = mfma16(a[k], b, acc);
    }
    int col = nt*16 + (l & 15);
    float asv = b2f(as[col]), adv = b2f(ad[col]);
    int h = nt >> 2;                 // head is uniform per nt
#pragma unroll
    for (int r = 0; r < 4; ++r){
      h1[(size_t)(r0 + r)*256 + col] = f2b(acc[r]);
      ssA[h][r] += acc[r]*asv;
      sdA[h][r] += acc[r]*adv;
    }
  }
  // reduce over the 16 col-lanes of each row group
#pragma unroll
  for (int m = 1; m < 16; m <<= 1){
#pragma unroll
    for (int h = 0; h < 4; ++h)
#pragma unroll
      for (int r = 0; r < 4; ++r){
        ssA[h][r] += __shfl_xor(ssA[h][r], m, 64);
        sdA[h][r] += __shfl_xor(sdA[h][r], m, 64);
      }
  }
  if ((l & 15) == 0){
#pragma unroll
    for (int r = 0; r < 4; ++r){
      f4v os, od;
      os[0]=ssA[0][r]; os[1]=ssA[1][r]; os[2]=ssA[2][r]; os[3]=ssA[3][r];
      od[0]=sdA[0][r]; od[1]=sdA[1][r]; od[2]=sdA[2][r]; od[3]=sdA[3][r];
      *(f4v*)(a1s + (size_t)(r0 + r)*4) = os;
      *(f4v*)(a1d + (size_t)(r0 + r)*4) = od;
    }
  }
}

// ---- fused alpha+gather layer 1: two-phase, clamped exp (no max / no rescale)
__global__ __launch_bounds__(256) void k_fagg1(const int* __restrict__ off, const int* __restrict__ csr,
                                               const short* __restrict__ h1, const float* __restrict__ a1s,
                                               const float* __restrict__ a1d, const short* __restrict__ b1,
                                               short* __restrict__ g1){
  __shared__ int   s_u[4][64];
  __shared__ float s_p[4][64][4];
  int v = blockIdx.x*4 + (threadIdx.x >> 6);
  if (v >= NN) return;
  int w = threadIdx.x >> 6;
  int l = threadIdx.x & 63;
  int hh = l >> 4;
  int c0 = l*4;
  const f4v ad4 = *(const f4v*)(a1d + v*4);
  int e0 = off[v], e1 = off[v+1];
  float s0=0.f,s1=0.f,s2=0.f,s3=0.f;
  f4v acc = {0.f,0.f,0.f,0.f};

  for (int base = e0; base < e1; base += 64){
    int nc = e1 - base; if (nc > 64) nc = 64;
    // Phase A: lane = edge
    int u = v;
    float p0=0.f,p1=0.f,p2=0.f,p3=0.f;
    if (l < nc){
      u = csr[base + l];
      f4v as4 = *(const f4v*)(a1s + u*4);
      float t0 = as4[0]+ad4[0]; t0 = (t0>=0.f)?t0:0.2f*t0; p0 = __expf(fminf(t0,30.f));
      float t1 = as4[1]+ad4[1]; t1 = (t1>=0.f)?t1:0.2f*t1; p1 = __expf(fminf(t1,30.f));
      float t2 = as4[2]+ad4[2]; t2 = (t2>=0.f)?t2:0.2f*t2; p2 = __expf(fminf(t2,30.f));
      float t3 = as4[3]+ad4[3]; t3 = (t3>=0.f)?t3:0.2f*t3; p3 = __expf(fminf(t3,30.f));
    }
    s_u[w][l] = u;
    f4v pv; pv[0]=p0; pv[1]=p1; pv[2]=p2; pv[3]=p3;
    *(f4v*)&s_p[w][l][0] = pv;
    float q0=p0,q1=p1,q2=p2,q3=p3;
#pragma unroll
    for (int st = 1; st < 64; st <<= 1){
      q0 += __shfl_xor(q0, st, 64);
      q1 += __shfl_xor(q1, st, 64);
      q2 += __shfl_xor(q2, st, 64);
      q3 += __shfl_xor(q3, st, 64);
    }
    s0 += q0; s1 += q1; s2 += q2; s3 += q3;
    asm volatile("s_waitcnt lgkmcnt(0)" ::: "memory");
    // Phase B: lane = 4 channels of full 256-ch row
#pragma unroll 8
    for (int i = 0; i < nc; ++i){
      int   ui = s_u[w][i];
      float pi = s_p[w][i][hh];
      short4v hv = *(const short4v*)(h1 + (size_t)ui*256 + c0);
      acc[0] += pi*b2f(hv[0]);
      acc[1] += pi*b2f(hv[1]);
      acc[2] += pi*b2f(hv[2]);
      acc[3] += pi*b2f(hv[3]);
    }
    asm volatile("s_waitcnt lgkmcnt(0)" ::: "memory");
  }
  float mys = (hh==0)?s0:((hh==1)?s1:((hh==2)?s2:s3));
  float inv = 1.f/mys;
  short4v o;
  o[0] = f2b(fmaxf(acc[0]*inv + b2f(b1[c0+0]), 0.f));
  o[1] = f2b(fmaxf(acc[1]*inv + b2f(b1[c0+1]), 0.f));
  o[2] = f2b(fmaxf(acc[2]*inv + b2f(b1[c0+2]), 0.f));
  o[3] = f2b(fmaxf(acc[3]*inv + b2f(b1[c0+3]), 0.f));
  *(short4v*)(g1 + (size_t)v*256 + c0) = o;
}

// ---------------- GAT layer 2 GEMM + fused scores ----------------
__global__ __launch_bounds__(256) void k_gemm2(const short* __restrict__ g1, const short* __restrict__ W,
                                               const short* __restrict__ as, const short* __restrict__ ad,
                                               short* __restrict__ h2, float* __restrict__ a2s, float* __restrict__ a2d){
  int wv = blockIdx.x*4 + (threadIdx.x >> 6);
  if (wv >= NN/16) return;
  int l = threadIdx.x & 63;
  int row = wv*16 + (l & 15);
  int koff = (l >> 4)*8;
  short8v a[8];
#pragma unroll
  for (int k = 0; k < 8; ++k) a[k] = *(const short8v*)(g1 + (size_t)row*256 + k*32 + koff);
  int r0 = wv*16 + (l >> 4)*4;
  float ss[4] = {0.f,0.f,0.f,0.f}, sd[4] = {0.f,0.f,0.f,0.f};
#pragma unroll
  for (int nt = 0; nt < 4; ++nt){
    f4v acc = {0.f,0.f,0.f,0.f};
#pragma unroll
    for (int k = 0; k < 8; ++k){
      short8v b = *(const short8v*)(W + (size_t)(nt*16 + (l & 15))*256 + k*32 + koff);
      acc = mfma16(a[k], b, acc);
    }
    int col = nt*16 + (l & 15);
    float asv = b2f(as[col]), adv = b2f(ad[col]);
#pragma unroll
    for (int r = 0; r < 4; ++r){
      h2[(size_t)(r0 + r)*64 + col] = f2b(acc[r]);
      ss[r] += acc[r]*asv;
      sd[r] += acc[r]*adv;
    }
  }
#pragma unroll
  for (int m = 1; m < 16; m <<= 1){
#pragma unroll
    for (int r = 0; r < 4; ++r){
      ss[r] += __shfl_xor(ss[r], m, 64);
      sd[r] += __shfl_xor(sd[r], m, 64);
    }
  }
  if ((l & 15) == 0){
#pragma unroll
    for (int r = 0; r < 4; ++r){
      a2s[r0 + r] = ss[r];
      a2d[r0 + r] = sd[r];
    }
  }
}

// ---- fused alpha+gather layer 2
__global__ __launch_bounds__(256) void k_fagg2(const int* __restrict__ off, const int* __restrict__ csr,
                                               const short* __restrict__ h2, const float* __restrict__ a2s,
                                               const float* __restrict__ a2d, const short* __restrict__ b2,
                                               short* __restrict__ g2){
  __shared__ int   s_u[4][64];
  __shared__ float s_p[4][64];
  int v = blockIdx.x*4 + (threadIdx.x >> 6);
  if (v >= NN) return;
  int w = threadIdx.x >> 6;
  int l = threadIdx.x & 63;
  float adst = a2d[v];
  int e0 = off[v], e1 = off[v+1];
  float s = 0.f, acc = 0.f;

  for (int base = e0; base < e1; base += 64){
    int nc = e1 - base; if (nc > 64) nc = 64;
    int u = v;
    float p = 0.f;
    if (l < nc){
      u = csr[base + l];
      float t = a2s[u] + adst;
      t = (t>=0.f)?t:0.2f*t;
      p = __expf(fminf(t,30.f));
    }
    s_u[w][l] = u;
    s_p[w][l] = p;
    float q = p;
#pragma unroll
    for (int st = 1; st < 64; st <<= 1) q += __shfl_xor(q, st, 64);
    s += q;
    asm volatile("s_waitcnt lgkmcnt(0)" ::: "memory");
#pragma unroll 8
    for (int i = 0; i < nc; ++i){
      int   ui = s_u[w][i];
      float pi = s_p[w][i];
      acc += pi*b2f(h2[(size_t)ui*64 + l]);
    }
    asm volatile("s_waitcnt lgkmcnt(0)" ::: "memory");
  }
  float val = fmaxf(acc*(1.f/s) + b2f(b2[l]), 0.f);
  g2[(size_t)v*64 + l] = f2b(val);
}

// ---- segment mean-pool over sorted batch: grid (8 splits, 64 segments)
__global__ __launch_bounds__(256) void k_pool(const short* __restrict__ g2, const int* __restrict__ batch,
                                              float* __restrict__ pool, float* __restrict__ cntf){
  int b = blockIdx.y;
  int split = blockIdx.x;       // 0..7
  __shared__ int seg[2];
  __shared__ float red[4][64];
  int tid = threadIdx.x;
  if (tid == 0){
    int lo = 0, hi = NN;
    while (lo < hi){ int mid = (lo+hi)>>1; if (batch[mid] < b) lo = mid+1; else hi = mid; }
    seg[0] = lo;
    lo = 0; hi = NN;
    while (lo < hi){ int mid = (lo+hi)>>1; if (batch[mid] < b+1) lo = mid+1; else hi = mid; }
    seg[1] = lo;
  }
  __syncthreads();
  int lo = seg[0], hi = seg[1];
  int c = tid & 63;
  int rg = tid >> 6;            // 0..3
  float acc = 0.f;
  for (int r = lo + split*4 + rg; r < hi; r += 32)
    acc += b2f(g2[(size_t)r*64 + c]);
  red[rg][c] = acc;
  __syncthreads();
  if (tid < 64){
    float sum = red[0][tid] + red[1][tid] + red[2][tid] + red[3][tid];
    atomicAdd(&pool[b*HD + tid], sum);
  }
  if (split == 0 && tid == 0) cntf[b] = (float)(hi - lo);
}

// ---------------- LSTM pre-GEMM: Xp stored in PERMUTED gate order ----------------
__global__ __launch_bounds__(256) void k_xp(const short* __restrict__ seq,
                                            const short* __restrict__ WihF, const short* __restrict__ bihF, const short* __restrict__ bhhF,
                                            const short* __restrict__ WihB, const short* __restrict__ bihB, const short* __restrict__ bhhB,
                                            float* __restrict__ Xp){
  int dir = blockIdx.y;
  const short* Wih = dir ? WihB : WihF;
  const short* bih = dir ? bihB : bihF;
  const short* bhh = dir ? bhhB : bhhF;
  int wv = blockIdx.x*4 + (threadIdx.x >> 6);   // 200 waves
  int l = threadIdx.x & 63;
  int row = wv*16 + (l & 15);
  int koff = (l >> 4)*8;
  short8v a[2];
#pragma unroll
  for (int k = 0; k < 2; ++k) a[k] = *(const short8v*)(seq + (size_t)row*64 + k*32 + koff);
  int r0 = wv*16 + (l >> 4)*4;
  float* Xpd = Xp + (size_t)dir*TT*BB*256;
#pragma unroll
  for (int nt = 0; nt < 16; ++nt){
    f4v acc = {0.f,0.f,0.f,0.f};
#pragma unroll
    for (int k = 0; k < 2; ++k){
      short8v b = *(const short8v*)(Wih + (size_t)(nt*16 + (l & 15))*64 + k*32 + koff);
      acc = mfma16(a[k], b, acc);
    }
    int col = nt*16 + (l & 15);
    float bias = b2f(bih[col]) + b2f(bhh[col]);
    int gate = col >> 6, ch = col & 63;
    int pcol = ((ch>>5)*8 + ((ch>>4)&1)*4 + gate)*16 + (ch & 15);
#pragma unroll
    for (int r = 0; r < 4; ++r){
      int rr = r0 + r;
      int bidx = rr / TT, t = rr % TT;
      Xpd[((size_t)t*BB + bidx)*256 + pcol] = acc[r] + bias;
    }
  }
}

// persistent LSTM: 8 blocks (2 dir x 4 batch-groups of 16 rows), 256 threads (4 waves).
__global__ __launch_bounds__(256) void k_lstm(const float* __restrict__ Xp,
                                              const short* __restrict__ WhhF, const short* __restrict__ WhhB,
                                              short* __restrict__ lout){
  int bg  = blockIdx.x;            // 0..3 batch-group
  int dir = blockIdx.y;
  const short* Whh = dir ? WhhB : WhhF;
  const float* Xpd = Xp + (size_t)dir*TT*BB*256 + (size_t)bg*16*256;
  __shared__ short hl[2][16][72];     // stride 36 words: 2-way banks (free)
  __shared__ short whl[256][72];
  int tid = threadIdx.x;
  {
    int p = tid;
    int nt = p >> 4, c16p = p & 15;
    int jj = nt & 7, half = nt >> 3;
    int gate = jj & 3, ch = half*32 + (jj>>2)*16 + c16p;
    int src = gate*64 + ch;
#pragma unroll
    for (int q = 0; q < 8; ++q){
      short8v vv = *(const short8v*)(Whh + (size_t)src*64 + q*8);
      *(short8v*)&whl[p][q*8] = vv;
    }
  }
  for (int i = tid; i < 16*64; i += 256) hl[0][i>>6][i&63] = 0;

  int l = tid & 63;
  int w = tid >> 6;                 // wave = gate-group
  int c16 = l & 15;
  int koff = (l >> 4)*8;
  int r0 = (l >> 4)*4;
  int ch = (w>>1)*32 + (w&1)*16 + c16;
  float creg[4] = {0.f,0.f,0.f,0.f};

  float xg[4][4];
  {
    int t0 = dir ? (TT-1) : 0;
    const float* xpb = Xpd + (size_t)t0*BB*256;
#pragma unroll
    for (int j = 0; j < 4; ++j){
      int p = (w*4 + j)*16 + c16;
#pragma unroll
      for (int r = 0; r < 4; ++r) xg[j][r] = xpb[(size_t)(r0 + r)*256 + p];
    }
  }

  int cur = 0;
  for (int s = 0; s < TT; ++s){
    int t = dir ? (TT - 1 - s) : s;
    __syncthreads();
    float xgn[4][4];
    if (s + 1 < TT){
      int tn = dir ? (TT - 2 - s) : (s + 1);
      const float* xpb = Xpd + (size_t)tn*BB*256;
#pragma unroll
      for (int j = 0; j < 4; ++j){
        int p = (w*4 + j)*16 + c16;
#pragma unroll
        for (int r = 0; r < 4; ++r) xgn[j][r] = xpb[(size_t)(r0 + r)*256 + p];
      }
    }
    short8v a0 = *(const short8v*)&hl[cur][c16][koff];
    short8v a1 = *(const short8v*)&hl[cur][c16][32 + koff];
    f4v acc[4];
#pragma unroll
    for (int j = 0; j < 4; ++j){
      int nt = w*4 + j;
      short8v b0 = *(const short8v*)&whl[nt*16 + c16][koff];
      short8v b1 = *(const short8v*)&whl[nt*16 + c16][32 + koff];
      f4v z = {0.f,0.f,0.f,0.f};
      z = mfma16(a0, b0, z);
      z = mfma16(a1, b1, z);
      acc[j] = z;
    }
    int nxt = cur ^ 1;
#pragma unroll
    for (int r = 0; r < 4; ++r){
      float gi = acc[0][r] + xg[0][r];
      float gf = acc[1][r] + xg[1][r];
      float gg = acc[2][r] + xg[2][r];
      float go = acc[3][r] + xg[3][r];
      float cn = fsig(gf)*creg[r] + fsig(gi)*ftanh(gg);
      creg[r] = cn;
      float hv = fsig(go)*ftanh(cn);
      short hb = f2b(hv);
      int row = r0 + r;
      hl[nxt][row][ch] = hb;
      lout[((size_t)(bg*16 + row)*TT + t)*128 + dir*64 + ch] = hb;
    }
#pragma unroll
    for (int j = 0; j < 4; ++j)
#pragma unroll
      for (int r = 0; r < 4; ++r) xg[j][r] = xgn[j][r];
    cur = nxt;
  }
}

// ---------------- attention: qkv = lstm_out @ Win^T + b ----------------
__global__ __launch_bounds__(256) void k_qkv(const short* __restrict__ lout, const short* __restrict__ W, const short* __restrict__ bias, short* __restrict__ qkv){
  int wv = blockIdx.x*4 + (threadIdx.x >> 6);   // 200 waves
  int l = threadIdx.x & 63;
  int row = wv*16 + (l & 15);
  int koff = (l >> 4)*8;
  short8v a[4];
#pragma unroll
  for (int k = 0; k < 4; ++k) a[k] = *(const short8v*)(lout + (size_t)row*128 + k*32 + koff);
  int r0 = wv*16 + (l >> 4)*4;
#pragma unroll
  for (int nt = 0; nt < 24; ++nt){
    f4v acc = {0.f,0.f,0.f,0.f};
#pragma unroll
    for (int k = 0; k < 4; ++k){
      short8v b = *(const short8v*)(W + (size_t)(nt*16 + (l & 15))*128 + k*32 + koff);
      acc = mfma16(a[k], b, acc);
    }
    int col = nt*16 + (l & 15);
    float bv = b2f(bias[col]);
#pragma unroll
    for (int r = 0; r < 4; ++r) qkv[(size_t)(r0 + r)*384 + col] = f2b(acc[r] + bv);
  }
}

// one wave per (batch, head); mean over T fused (output projection deferred)
__global__ __launch_bounds__(64) void k_attn(const short* __restrict__ qkv, float* __restrict__ omean){
  int b = blockIdx.x >> 2, h = blockIdx.x & 3;
  int l = threadIdx.x;
  __shared__ float kl[50][32], vl[50][32], ol[50][32];
  for (int i = l; i < 1600; i += 64){
    int t = i >> 5, c = i & 31;
    kl[t][c] = b2f(qkv[((size_t)b*TT + t)*384 + 128 + h*32 + c]);
    vl[t][c] = b2f(qkv[((size_t)b*TT + t)*384 + 256 + h*32 + c]);
  }
  __syncthreads();
  float o[32];
#pragma unroll
  for (int c = 0; c < 32; ++c) o[c] = 0.f;
  if (l < TT){
    float q[32];
#pragma unroll
    for (int qq = 0; qq < 4; ++qq){
      short8v vq = *(const short8v*)(qkv + ((size_t)b*TT + l)*384 + h*32 + qq*8);
#pragma unroll
      for (int j = 0; j < 8; ++j) q[qq*8 + j] = b2f(vq[j]);
    }
    float sc[50];
    float mx = -1e30f;
    const float scale = 0.17677669529663687f;  // 1/sqrt(32)
#pragma unroll
    for (int j = 0; j < 50; ++j){
      float d = 0.f;
#pragma unroll
      for (int c = 0; c < 32; ++c) d += q[c]*kl[j][c];
      d *= scale;
      sc[j] = d;
      mx = fmaxf(mx, d);
    }
    float sum = 0.f;
#pragma unroll
    for (int j = 0; j < 50; ++j){ float p = __expf(sc[j] - mx); sc[j] = p; sum += p; }
    float inv = 1.f/sum;
#pragma unroll
    for (int j = 0; j < 50; ++j){
      float p = sc[j]*inv;
#pragma unroll
      for (int c = 0; c < 32; ++c) o[c] += p*vl[j][c];
    }
#pragma unroll
    for (int c = 0; c < 32; ++c) ol[l][c] = o[c];
  }
  __syncthreads();
  if (l < 32){
    float s = 0.f;
#pragma unroll
    for (int t = 0; t < TT; ++t) s += ol[t][l];
    omean[(size_t)b*128 + h*32 + l] = s*0.02f;  // mean over T=50
  }
}

// final: combined = [pool/cnt (64), omean @ Wout^T + bout (128)]; out = combined @ fc^T + fcb
__global__ __launch_bounds__(192) void k_final(const float* __restrict__ pool, const float* __restrict__ cntf,
                                               const float* __restrict__ omean,
                                               const short* __restrict__ Woutw, const short* __restrict__ Woutb,
                                               const short* __restrict__ fcw, const short* __restrict__ fcb,
                                               const int* __restrict__ flag, void* __restrict__ outv){
  int b = blockIdx.x;
  int tid = threadIdx.x;
  __shared__ float comb[192];
  if (tid < 64){
    float cnt = cntf[b];
    comb[tid] = pool[b*HD + tid] / fmaxf(cnt, 1.f);
  } else {
    int e = tid - 64;
    float s = b2f(Woutb[e]);
    for (int j = 0; j < 128; ++j) s += omean[(size_t)b*128 + j]*b2f(Woutw[e*128 + j]);
    comb[tid] = s;
  }
  __syncthreads();
  if (tid < 2){
    float s = b2f(fcb[tid]);
    for (int j = 0; j < 192; ++j) s += comb[j]*b2f(fcw[tid*192 + j]);
    if (*flag) ((short*)outv)[b*2 + tid] = f2b(s);
    else       ((float*)outv)[b*2 + tid] = s;
  }
}

extern "C" void kernel_launch(void* const* d_in, const int* in_sizes, int n_in,
                              void* d_out, int out_size, void* d_ws, size_t ws_size,
                              hipStream_t stream){
  const int* ei    = (const int*)d_in[1];
  const int* batch = (const int*)d_in[2];

  char* ws = (char*)d_ws;
  size_t o = 0;
  auto alloc = [&](size_t bytes)->char*{
    char* r = ws + o;
    o = (o + bytes + 255) & ~(size_t)255;
    return r;
  };
  short* arena = (short*)alloc((size_t)6787912*2);
  int*   flag  = (int*)alloc(256);
  char*  bufA  = alloc((size_t)NN*256*2);   // h1, later h2+g2
  char*  bufB  = alloc((size_t)NN*256*2);   // g1, later Xp/lout/qkv/omean
  float* a1s  = (float*)alloc((size_t)NN*4*4);
  float* a1d  = (float*)alloc((size_t)NN*4*4);
  float* a2s  = (float*)alloc((size_t)NN*4);
  float* a2d  = (float*)alloc((size_t)NN*4);
  int*   deg  = (int*)alloc((size_t)NPAD*4);
  int*   offv = (int*)alloc((size_t)(NN+1)*4);
  int*   cur  = (int*)alloc((size_t)NN*4);
  int*   csr  = (int*)alloc((size_t)ETOT*4);
  float* pool = (float*)alloc((size_t)BB*HD*4);
  float* cntf = (float*)alloc((size_t)BB*4);

  short* h1 = (short*)bufA;                       // [NN][256]
  short* h2 = (short*)bufA;                       // [NN][64] overlay (h1 dead after k_fagg1)
  short* g2 = (short*)(bufA + 12800000);          // [NN][64] bf16
  short* g1 = (short*)bufB;
  float* Xp   = (float*)bufB;                     // overlay (g1 dead after k_gemm2)
  short* lout = (short*)(bufB + 6553600);
  short* qkv  = (short*)(bufB + 6553600 + 819200);
  float* omean= (float*)(bufB + 6553600 + 819200 + 2457600);

  // arena views
  const short* xb    = arena + 0;
  const short* seqb  = arena + 6400000;
  const short* w1b   = arena + 6604800;
  const short* as1b  = arena + 6637568;
  const short* ad1b  = arena + 6637824;
  const short* b1b   = arena + 6638080;
  const short* w2b   = arena + 6638336;
  const short* as2b  = arena + 6654720;
  const short* ad2b  = arena + 6654784;
  const short* b2b   = arena + 6654848;
  const short* wihFb = arena + 6654912;
  const short* whhFb = arena + 6671296;
  const short* bihFb = arena + 6687680;
  const short* bhhFb = arena + 6687936;
  const short* wihBb = arena + 6688192;
  const short* whhBb = arena + 6704576;
  const short* bihBb = arena + 6720960;
  const short* bhhBb = arena + 6721216;
  const short* winwb = arena + 6721472;
  const short* winbb = arena + 6770624;
  const short* woutwb= arena + 6771008;
  const short* woutbb= arena + 6787392;
  const short* fcwb  = arena + 6787520;
  const short* fcbb  = arena + 6787904;

  Ptrs P;
  P.p[0]=d_in[0];  P.p[1]=d_in[3];  P.p[2]=d_in[4];  P.p[3]=d_in[5];
  P.p[4]=d_in[6];  P.p[5]=d_in[7];  P.p[6]=d_in[8];  P.p[7]=d_in[9];
  P.p[8]=d_in[10]; P.p[9]=d_in[11]; P.p[10]=d_in[12];P.p[11]=d_in[13];
  P.p[12]=d_in[14];P.p[13]=d_in[15];P.p[14]=d_in[16];P.p[15]=d_in[17];
  P.p[16]=d_in[18];P.p[17]=d_in[19];P.p[18]=d_in[20];P.p[19]=d_in[21];
  P.p[20]=d_in[22];P.p[21]=d_in[23];P.p[22]=d_in[24];P.p[23]=d_in[25];

  // convert (dtype detect folded in)
  k_cvt<<<2048, 256, 0, stream>>>(P, arena, flag);

  // CSR build
  k_init<<<(NPAD+255)/256, 256, 0, stream>>>(deg, pool);
  k_count<<<(EE+255)/256, 256, 0, stream>>>(ei, deg);
  k_scan<<<1, 1024, 0, stream>>>(deg, offv);
  k_self<<<(NN+255)/256, 256, 0, stream>>>(offv, cur, csr);
  k_scatter<<<(EE+255)/256, 256, 0, stream>>>(ei, cur, csr);

  // GAT layer 1
  k_gemm1<<<(NN/16+3)/4, 256, 0, stream>>>(xb, w1b, as1b, ad1b, h1, a1s, a1d);
  k_fagg1<<<(NN+3)/4, 256, 0, stream>>>(offv, csr, h1, a1s, a1d, b1b, g1);

  // GAT layer 2 + pool
  k_gemm2<<<(NN/16+3)/4, 256, 0, stream>>>(g1, w2b, as2b, ad2b, h2, a2s, a2d);
  k_fagg2<<<(NN+3)/4, 256, 0, stream>>>(offv, csr, h2, a2s, a2d, b2b, g2);
  k_pool<<<dim3(8, BB), 256, 0, stream>>>(g2, batch, pool, cntf);

  // LSTM
  k_xp<<<dim3(50, 2), 256, 0, stream>>>(seqb, wihFb, bihFb, bhhFb, wihBb, bihBb, bhhBb, Xp);
  k_lstm<<<dim3(4, 2), 256, 0, stream>>>(Xp, whhFb, whhBb, lout);

  // attention
  k_qkv<<<50, 256, 0, stream>>>(lout, winwb, winbb, qkv);
  k_attn<<<BB*4, 64, 0, stream>>>(qkv, omean);

  // final
  k_final<<<BB, 192, 0, stream>>>(pool, cntf, omean, woutwb, woutbb, fcwb, fcbb, flag, d_out);
}

// Round 13
// 350.869 us; speedup vs baseline: 1.3838x; 1.0222x over previous
//
#include <hip/hip_runtime.h>

#define NN 50000
#define EE 500000
#define BB 64
#define TT 50
#define FN 128
#define FS 64
#define HD 64
#define ETOT (EE + NN)
#define NPAD 50176   // 1024*49, k_scan guard-free

typedef __attribute__((ext_vector_type(8))) short short8v;
typedef __attribute__((ext_vector_type(4))) short short4v;
typedef __attribute__((ext_vector_type(4))) float f4v;

__device__ __forceinline__ float b2f(short u){
  union { unsigned int i; float f; } v; v.i = ((unsigned int)(unsigned short)u) << 16; return v.f;
}
__device__ __forceinline__ short f2b(float f){
  union { float f; unsigned int i; } v; v.f = f;
  unsigned int x = v.i;
  return (short)((x + 0x7fffu + ((x >> 16) & 1u)) >> 16);
}
__device__ __forceinline__ f4v mfma16(short8v a, short8v b, f4v c){
  return __builtin_amdgcn_mfma_f32_16x16x32_bf16(a, b, c, 0, 0, 0);
}
__device__ __forceinline__ float frcp(float x){ return __builtin_amdgcn_rcpf(x); }
__device__ __forceinline__ float fsig(float x){ return frcp(1.f + __expf(-x)); }
__device__ __forceinline__ float ftanh(float x){ return 1.f - 2.f*frcp(1.f + __expf(2.f*x)); }

// ---------------- input convert to bf16 arena (dtype detect folded in) ----------------
constexpr int SEG_CUM[25] = {0, 6400000, 6604800, 6637568, 6637824, 6638080,
  6638336, 6654720, 6654784, 6654848, 6654912, 6671296, 6687680, 6687936,
  6688192, 6704576, 6720960, 6721216, 6721472, 6770624, 6771008, 6787392,
  6787520, 6787904, 6787906};
#define ARENA_VEC (6787904/8)

struct Ptrs { const void* p[24]; };

__global__ __launch_bounds__(256) void k_cvt(Ptrs P, short* arena, int* flag){
  __shared__ int cnt;
  if (threadIdx.x == 0) cnt = 0;
  __syncthreads();
  {
    const unsigned short* x16 = (const unsigned short*)P.p[0];
    int c = 0;
    for (int i = threadIdx.x; i < 2048; i += 256){
      unsigned short vv = x16[2*i];     // even shorts: f32 low-halves (random) vs bf16 values
      int e = (vv >> 7) & 0xFF;
      if (e >= 64 && e < 160) c++;
    }
    atomicAdd(&cnt, c);
  }
  __syncthreads();
  bool isb = (cnt >= 1536);             // 1 = inputs are bf16
  if (blockIdx.x == 0 && threadIdx.x == 0) *flag = isb ? 1 : 0;

  int idx = blockIdx.x*256 + threadIdx.x;
  for (int v = idx; v < ARENA_VEC; v += gridDim.x*256){
    int i = v*8;
    int s = 0;
#pragma unroll
    for (int k = 1; k < 24; ++k) if (i >= SEG_CUM[k]) s = k;
    int j = i - SEG_CUM[s];
    short8v o;
    if (isb){
      o = *(const short8v*)((const short*)P.p[s] + j);
    } else {
      const float* f = (const float*)P.p[s] + j;
      f4v lo = *(const f4v*)f;
      f4v hi = *(const f4v*)(f + 4);
#pragma unroll
      for (int q = 0; q < 4; ++q){ o[q] = f2b(lo[q]); o[4+q] = f2b(hi[q]); }
    }
    *(short8v*)(arena + i) = o;
  }
  if (blockIdx.x == 0 && threadIdx.x == 0){
    for (int j = 0; j < 2; ++j)
      arena[6787904 + j] = isb ? ((const short*)P.p[23])[j] : f2b(((const float*)P.p[23])[j]);
  }
}

// ---------------- CSR build ----------------
__global__ __launch_bounds__(256) void k_init(int* deg, float* pool){
  int i = blockIdx.x*256 + threadIdx.x;
  if (i < NN) deg[i] = 1;            // self loop
  else if (i < NPAD) deg[i] = 0;     // pad for guard-free scan
  if (i < BB*HD) pool[i] = 0.f;
}

__global__ __launch_bounds__(256) void k_count(const int* ei, int* deg){
  int e = blockIdx.x*256 + threadIdx.x;
  if (e < EE) atomicAdd(&deg[ei[EE + e]], 1);
}

// single-pass scan: 49 values/thread held in REGISTERS (guard-free, unrolled)
__global__ __launch_bounds__(1024) void k_scan(const int* __restrict__ deg, int* __restrict__ off){
  __shared__ int buf[1024];
  int tid = threadIdx.x;
  int start = tid*49;
  int v[49];
#pragma unroll
  for (int j = 0; j < 49; ++j) v[j] = deg[start + j];
  int s = 0;
#pragma unroll
  for (int j = 0; j < 49; ++j) s += v[j];
  buf[tid] = s;
  __syncthreads();
  for (int st = 1; st < 1024; st <<= 1){
    int t = (tid >= st) ? buf[tid - st] : 0;
    __syncthreads();
    buf[tid] += t;
    __syncthreads();
  }
  int run = buf[tid] - s;            // exclusive base for this chunk
#pragma unroll
  for (int j = 0; j < 49; ++j){
    int i = start + j;
    if (i < NN) off[i] = run;
    run += v[j];
  }
  if (tid == 1023) off[NN] = run;
}

__global__ __launch_bounds__(256) void k_self(const int* off, int* cur, int* csr){
  int v = blockIdx.x*256 + threadIdx.x;
  if (v < NN){ int o = off[v]; csr[o] = v; cur[v] = o + 1; }
}

__global__ __launch_bounds__(256) void k_scatter(const int* ei, int* cur, int* csr){
  int e = blockIdx.x*256 + threadIdx.x;
  if (e < EE){
    int d = ei[EE + e];
    int pos = atomicAdd(&cur[d], 1);
    csr[pos] = ei[e];
  }
}

// ---------------- GAT layer 1 GEMM + fused scores: h1 = x @ W1^T; a1s/a1d from f32 acc ----------------
__global__ __launch_bounds__(256) void k_gemm1(const short* __restrict__ x, const short* __restrict__ W,
                                               const short* __restrict__ as, const short* __restrict__ ad,
                                               short* __restrict__ h1, float* __restrict__ a1s, float* __restrict__ a1d){
  int wv = blockIdx.x*4 + (threadIdx.x >> 6);
  if (wv >= NN/16) return;
  int l = threadIdx.x & 63;
  int row = wv*16 + (l & 15);
  int koff = (l >> 4)*8;
  short8v a[4];
#pragma unroll
  for (int k = 0; k < 4; ++k) a[k] = *(const short8v*)(x + (size_t)row*128 + k*32 + koff);
  int r0 = wv*16 + (l >> 4)*4;
  float ssA[4][4], sdA[4][4];      // [head][r]
#pragma unroll
  for (int h = 0; h < 4; ++h)
#pragma unroll
    for (int r = 0; r < 4; ++r){ ssA[h][r] = 0.f; sdA[h][r] = 0.f; }
#pragma unroll
  for (int nt = 0; nt < 16; ++nt){
    f4v acc = {0.f,0.f,0.f,0.f};
#pragma unroll
    for (int k = 0; k < 4; ++k){
      short8v b = *(const short8v*)(W + (size_t)(nt*16 + (l & 15))*128 + k*32 + koff);
      acc = mfma16(a[k], b, acc);
    }
    int col = nt*16 + (l & 15);
    float asv = b2f(as[col]), adv = b2f(ad[col]);
    int h = nt >> 2;                 // head is uniform per nt
#pragma unroll
    for (int r = 0; r < 4; ++r){
      h1[(size_t)(r0 + r)*256 + col] = f2b(acc[r]);
      ssA[h][r] += acc[r]*asv;
      sdA[h][r] += acc[r]*adv;
    }
  }
#pragma unroll
  for (int m = 1; m < 16; m <<= 1){
#pragma unroll
    for (int h = 0; h < 4; ++h)
#pragma unroll
      for (int r = 0; r < 4; ++r){
        ssA[h][r] += __shfl_xor(ssA[h][r], m, 64);
        sdA[h][r] += __shfl_xor(sdA[h][r], m, 64);
      }
  }
  if ((l & 15) == 0){
#pragma unroll
    for (int r = 0; r < 4; ++r){
      f4v os, od;
      os[0]=ssA[0][r]; os[1]=ssA[1][r]; os[2]=ssA[2][r]; os[3]=ssA[3][r];
      od[0]=sdA[0][r]; od[1]=sdA[1][r]; od[2]=sdA[2][r]; od[3]=sdA[3][r];
      *(f4v*)(a1s + (size_t)(r0 + r)*4) = os;
      *(f4v*)(a1d + (size_t)(r0 + r)*4) = od;
    }
  }
}

// ---- fused alpha+gather layer 1: PhaseA lane=edge; PhaseB 2 rows/iter, 16B/lane
__global__ __launch_bounds__(256) void k_fagg1(const int* __restrict__ off, const int* __restrict__ csr,
                                               const short* __restrict__ h1, const float* __restrict__ a1s,
                                               const float* __restrict__ a1d, const short* __restrict__ b1,
                                               short* __restrict__ g1){
  __shared__ int   s_u[4][64];
  __shared__ float s_p[4][64][4];
  int v = blockIdx.x*4 + (threadIdx.x >> 6);
  if (v >= NN) return;
  int w = threadIdx.x >> 6;
  int l = threadIdx.x & 63;
  int rp  = l >> 5;              // row of pair
  int ch8 = (l & 31)*8;          // 8 channels
  int hh  = (l & 31) >> 3;       // head owning those channels
  const f4v ad4 = *(const f4v*)(a1d + v*4);
  int e0 = off[v], e1 = off[v+1];
  float s0=0.f,s1=0.f,s2=0.f,s3=0.f;
  float acc[8] = {0.f,0.f,0.f,0.f,0.f,0.f,0.f,0.f};

  for (int base = e0; base < e1; base += 64){
    int nc = e1 - base; if (nc > 64) nc = 64;
    // Phase A: lane = edge (padded lanes: u=v, p=0)
    int u = v;
    float p0=0.f,p1=0.f,p2=0.f,p3=0.f;
    if (l < nc){
      u = csr[base + l];
      f4v as4 = *(const f4v*)(a1s + u*4);
      float t0 = as4[0]+ad4[0]; t0 = (t0>=0.f)?t0:0.2f*t0; p0 = __expf(fminf(t0,30.f));
      float t1 = as4[1]+ad4[1]; t1 = (t1>=0.f)?t1:0.2f*t1; p1 = __expf(fminf(t1,30.f));
      float t2 = as4[2]+ad4[2]; t2 = (t2>=0.f)?t2:0.2f*t2; p2 = __expf(fminf(t2,30.f));
      float t3 = as4[3]+ad4[3]; t3 = (t3>=0.f)?t3:0.2f*t3; p3 = __expf(fminf(t3,30.f));
    }
    s_u[w][l] = u;
    f4v pv; pv[0]=p0; pv[1]=p1; pv[2]=p2; pv[3]=p3;
    *(f4v*)&s_p[w][l][0] = pv;
    float q0=p0,q1=p1,q2=p2,q3=p3;
#pragma unroll
    for (int st = 1; st < 64; st <<= 1){
      q0 += __shfl_xor(q0, st, 64);
      q1 += __shfl_xor(q1, st, 64);
      q2 += __shfl_xor(q2, st, 64);
      q3 += __shfl_xor(q3, st, 64);
    }
    s0 += q0; s1 += q1; s2 += q2; s3 += q3;
    asm volatile("s_waitcnt lgkmcnt(0)" ::: "memory");
    // Phase B: 2 rows per iteration, 16B/lane
    int nit = (nc + 1) >> 1;
#pragma unroll 4
    for (int i = 0; i < nit; ++i){
      int idx = i*2 + rp;
      int   ui = s_u[w][idx];
      float pi = s_p[w][idx][hh];
      short8v hv = *(const short8v*)(h1 + (size_t)ui*256 + ch8);
#pragma unroll
      for (int j = 0; j < 8; ++j) acc[j] += pi*b2f(hv[j]);
    }
    asm volatile("s_waitcnt lgkmcnt(0)" ::: "memory");
  }
#pragma unroll
  for (int j = 0; j < 8; ++j) acc[j] += __shfl_xor(acc[j], 32, 64);
  if (l < 32){
    float mys = (hh==0)?s0:((hh==1)?s1:((hh==2)?s2:s3));
    float inv = 1.f/mys;
    short8v bb = *(const short8v*)(b1 + ch8);
    short8v o;
#pragma unroll
    for (int j = 0; j < 8; ++j) o[j] = f2b(fmaxf(acc[j]*inv + b2f(bb[j]), 0.f));
    *(short8v*)(g1 + (size_t)v*256 + ch8) = o;
  }
}

// ---------------- GAT layer 2 GEMM + fused scores ----------------
__global__ __launch_bounds__(256) void k_gemm2(const short* __restrict__ g1, const short* __restrict__ W,
                                               const short* __restrict__ as, const short* __restrict__ ad,
                                               short* __restrict__ h2, float* __restrict__ a2s, float* __restrict__ a2d){
  int wv = blockIdx.x*4 + (threadIdx.x >> 6);
  if (wv >= NN/16) return;
  int l = threadIdx.x & 63;
  int row = wv*16 + (l & 15);
  int koff = (l >> 4)*8;
  short8v a[8];
#pragma unroll
  for (int k = 0; k < 8; ++k) a[k] = *(const short8v*)(g1 + (size_t)row*256 + k*32 + koff);
  int r0 = wv*16 + (l >> 4)*4;
  float ss[4] = {0.f,0.f,0.f,0.f}, sd[4] = {0.f,0.f,0.f,0.f};
#pragma unroll
  for (int nt = 0; nt < 4; ++nt){
    f4v acc = {0.f,0.f,0.f,0.f};
#pragma unroll
    for (int k = 0; k < 8; ++k){
      short8v b = *(const short8v*)(W + (size_t)(nt*16 + (l & 15))*256 + k*32 + koff);
      acc = mfma16(a[k], b, acc);
    }
    int col = nt*16 + (l & 15);
    float asv = b2f(as[col]), adv = b2f(ad[col]);
#pragma unroll
    for (int r = 0; r < 4; ++r){
      h2[(size_t)(r0 + r)*64 + col] = f2b(acc[r]);
      ss[r] += acc[r]*asv;
      sd[r] += acc[r]*adv;
    }
  }
#pragma unroll
  for (int m = 1; m < 16; m <<= 1){
#pragma unroll
    for (int r = 0; r < 4; ++r){
      ss[r] += __shfl_xor(ss[r], m, 64);
      sd[r] += __shfl_xor(sd[r], m, 64);
    }
  }
  if ((l & 15) == 0){
#pragma unroll
    for (int r = 0; r < 4; ++r){
      a2s[r0 + r] = ss[r];
      a2d[r0 + r] = sd[r];
    }
  }
}

// ---- fused alpha+gather layer 2: PhaseB 8 rows/iter, 16B/lane
__global__ __launch_bounds__(256) void k_fagg2(const int* __restrict__ off, const int* __restrict__ csr,
                                               const short* __restrict__ h2, const float* __restrict__ a2s,
                                               const float* __restrict__ a2d, const short* __restrict__ b2,
                                               short* __restrict__ g2){
  __shared__ int   s_u[4][64];
  __shared__ float s_p[4][64];
  int v = blockIdx.x*4 + (threadIdx.x >> 6);
  if (v >= NN) return;
  int w = threadIdx.x >> 6;
  int l = threadIdx.x & 63;
  int rp  = l >> 3;              // 0..7: row within group of 8
  int ch8 = (l & 7)*8;           // 8 channels of the 64
  float adst = a2d[v];
  int e0 = off[v], e1 = off[v+1];
  float s = 0.f;
  float acc[8] = {0.f,0.f,0.f,0.f,0.f,0.f,0.f,0.f};

  for (int base = e0; base < e1; base += 64){
    int nc = e1 - base; if (nc > 64) nc = 64;
    int u = v;
    float p = 0.f;
    if (l < nc){
      u = csr[base + l];
      float t = a2s[u] + adst;
      t = (t>=0.f)?t:0.2f*t;
      p = __expf(fminf(t,30.f));
    }
    s_u[w][l] = u;
    s_p[w][l] = p;
    float q = p;
#pragma unroll
    for (int st = 1; st < 64; st <<= 1) q += __shfl_xor(q, st, 64);
    s += q;
    asm volatile("s_waitcnt lgkmcnt(0)" ::: "memory");
    int nit = (nc + 7) >> 3;
#pragma unroll 2
    for (int i = 0; i < nit; ++i){
      int idx = i*8 + rp;
      int   ui = s_u[w][idx];
      float pi = s_p[w][idx];
      short8v hv = *(const short8v*)(h2 + (size_t)ui*64 + ch8);
#pragma unroll
      for (int j = 0; j < 8; ++j) acc[j] += pi*b2f(hv[j]);
    }
    asm volatile("s_waitcnt lgkmcnt(0)" ::: "memory");
  }
#pragma unroll
  for (int m = 8; m < 64; m <<= 1)
#pragma unroll
    for (int j = 0; j < 8; ++j) acc[j] += __shfl_xor(acc[j], m, 64);
  if (l < 8){
    float inv = 1.f/s;
    short8v bb = *(const short8v*)(b2 + ch8);
    short8v o;
#pragma unroll
    for (int j = 0; j < 8; ++j) o[j] = f2b(fmaxf(acc[j]*inv + b2f(bb[j]), 0.f));
    *(short8v*)(g2 + (size_t)v*64 + ch8) = o;
  }
}

// ---- segment mean-pool over sorted batch: grid (8 splits, 64 segments)
__global__ __launch_bounds__(256) void k_pool(const short* __restrict__ g2, const int* __restrict__ batch,
                                              float* __restrict__ pool, float* __restrict__ cntf){
  int b = blockIdx.y;
  int split = blockIdx.x;       // 0..7
  __shared__ int seg[2];
  __shared__ float red[4][64];
  int tid = threadIdx.x;
  if (tid == 0){
    int lo = 0, hi = NN;
    while (lo < hi){ int mid = (lo+hi)>>1; if (batch[mid] < b) lo = mid+1; else hi = mid; }
    seg[0] = lo;
    lo = 0; hi = NN;
    while (lo < hi){ int mid = (lo+hi)>>1; if (batch[mid] < b+1) lo = mid+1; else hi = mid; }
    seg[1] = lo;
  }
  __syncthreads();
  int lo = seg[0], hi = seg[1];
  int c = tid & 63;
  int rg = tid >> 6;            // 0..3
  float acc = 0.f;
  for (int r = lo + split*4 + rg; r < hi; r += 32)
    acc += b2f(g2[(size_t)r*64 + c]);
  red[rg][c] = acc;
  __syncthreads();
  if (tid < 64){
    float sum = red[0][tid] + red[1][tid] + red[2][tid] + red[3][tid];
    atomicAdd(&pool[b*HD + tid], sum);
  }
  if (split == 0 && tid == 0) cntf[b] = (float)(hi - lo);
}

// ---------------- LSTM pre-GEMM: Xp stored in PERMUTED gate order ----------------
__global__ __launch_bounds__(256) void k_xp(const short* __restrict__ seq,
                                            const short* __restrict__ WihF, const short* __restrict__ bihF, const short* __restrict__ bhhF,
                                            const short* __restrict__ WihB, const short* __restrict__ bihB, const short* __restrict__ bhhB,
                                            float* __restrict__ Xp){
  int dir = blockIdx.y;
  const short* Wih = dir ? WihB : WihF;
  const short* bih = dir ? bihB : bihF;
  const short* bhh = dir ? bhhB : bhhF;
  int wv = blockIdx.x*4 + (threadIdx.x >> 6);   // 200 waves
  int l = threadIdx.x & 63;
  int row = wv*16 + (l & 15);
  int koff = (l >> 4)*8;
  short8v a[2];
#pragma unroll
  for (int k = 0; k < 2; ++k) a[k] = *(const short8v*)(seq + (size_t)row*64 + k*32 + koff);
  int r0 = wv*16 + (l >> 4)*4;
  float* Xpd = Xp + (size_t)dir*TT*BB*256;
#pragma unroll
  for (int nt = 0; nt < 16; ++nt){
    f4v acc = {0.f,0.f,0.f,0.f};
#pragma unroll
    for (int k = 0; k < 2; ++k){
      short8v b = *(const short8v*)(Wih + (size_t)(nt*16 + (l & 15))*64 + k*32 + koff);
      acc = mfma16(a[k], b, acc);
    }
    int col = nt*16 + (l & 15);
    float bias = b2f(bih[col]) + b2f(bhh[col]);
    int gate = col >> 6, ch = col & 63;
    int pcol = ((ch>>5)*8 + ((ch>>4)&1)*4 + gate)*16 + (ch & 15);
#pragma unroll
    for (int r = 0; r < 4; ++r){
      int rr = r0 + r;
      int bidx = rr / TT, t = rr % TT;
      Xpd[((size_t)t*BB + bidx)*256 + pcol] = acc[r] + bias;
    }
  }
}

// persistent LSTM: 8 blocks (2 dir x 4 batch-groups of 16 rows), 256 threads (4 waves).
__global__ __launch_bounds__(256) void k_lstm(const float* __restrict__ Xp,
                                              const short* __restrict__ WhhF, const short* __restrict__ WhhB,
                                              short* __restrict__ lout){
  int bg  = blockIdx.x;            // 0..3 batch-group
  int dir = blockIdx.y;
  const short* Whh = dir ? WhhB : WhhF;
  const float* Xpd = Xp + (size_t)dir*TT*BB*256 + (size_t)bg*16*256;
  __shared__ short hl[2][16][72];     // stride 36 words: 2-way banks (free)
  __shared__ short whl[256][72];
  int tid = threadIdx.x;
  {
    int p = tid;
    int nt = p >> 4, c16p = p & 15;
    int jj = nt & 7, half = nt >> 3;
    int gate = jj & 3, ch = half*32 + (jj>>2)*16 + c16p;
    int src = gate*64 + ch;
#pragma unroll
    for (int q = 0; q < 8; ++q){
      short8v vv = *(const short8v*)(Whh + (size_t)src*64 + q*8);
      *(short8v*)&whl[p][q*8] = vv;
    }
  }
  for (int i = tid; i < 16*64; i += 256) hl[0][i>>6][i&63] = 0;

  int l = tid & 63;
  int w = tid >> 6;                 // wave = gate-group
  int c16 = l & 15;
  int koff = (l >> 4)*8;
  int r0 = (l >> 4)*4;
  int ch = (w>>1)*32 + (w&1)*16 + c16;
  float creg[4] = {0.f,0.f,0.f,0.f};

  float xg[4][4];
  {
    int t0 = dir ? (TT-1) : 0;
    const float* xpb = Xpd + (size_t)t0*BB*256;
#pragma unroll
    for (int j = 0; j < 4; ++j){
      int p = (w*4 + j)*16 + c16;
#pragma unroll
      for (int r = 0; r < 4; ++r) xg[j][r] = xpb[(size_t)(r0 + r)*256 + p];
    }
  }

  int cur = 0;
  for (int s = 0; s < TT; ++s){
    int t = dir ? (TT - 1 - s) : s;
    __syncthreads();
    float xgn[4][4];
    if (s + 1 < TT){
      int tn = dir ? (TT - 2 - s) : (s + 1);
      const float* xpb = Xpd + (size_t)tn*BB*256;
#pragma unroll
      for (int j = 0; j < 4; ++j){
        int p = (w*4 + j)*16 + c16;
#pragma unroll
        for (int r = 0; r < 4; ++r) xgn[j][r] = xpb[(size_t)(r0 + r)*256 + p];
      }
    }
    short8v a0 = *(const short8v*)&hl[cur][c16][koff];
    short8v a1 = *(const short8v*)&hl[cur][c16][32 + koff];
    f4v acc[4];
#pragma unroll
    for (int j = 0; j < 4; ++j){
      int nt = w*4 + j;
      short8v b0 = *(const short8v*)&whl[nt*16 + c16][koff];
      short8v b1 = *(const short8v*)&whl[nt*16 + c16][32 + koff];
      f4v z = {0.f,0.f,0.f,0.f};
      z = mfma16(a0, b0, z);
      z = mfma16(a1, b1, z);
      acc[j] = z;
    }
    int nxt = cur ^ 1;
#pragma unroll
    for (int r = 0; r < 4; ++r){
      float gi = acc[0][r] + xg[0][r];
      float gf = acc[1][r] + xg[1][r];
      float gg = acc[2][r] + xg[2][r];
      float go = acc[3][r] + xg[3][r];
      float cn = fsig(gf)*creg[r] + fsig(gi)*ftanh(gg);
      creg[r] = cn;
      float hv = fsig(go)*ftanh(cn);
      short hb = f2b(hv);
      int row = r0 + r;
      hl[nxt][row][ch] = hb;
      lout[((size_t)(bg*16 + row)*TT + t)*128 + dir*64 + ch] = hb;
    }
#pragma unroll
    for (int j = 0; j < 4; ++j)
#pragma unroll
      for (int r = 0; r < 4; ++r) xg[j][r] = xgn[j][r];
    cur = nxt;
  }
}

// ---------------- attention: qkv = lstm_out @ Win^T + b ----------------
__global__ __launch_bounds__(256) void k_qkv(const short* __restrict__ lout, const short* __restrict__ W, const short* __restrict__ bias, short* __restrict__ qkv){
  int wv = blockIdx.x*4 + (threadIdx.x >> 6);   // 200 waves
  int l = threadIdx.x & 63;
  int row = wv*16 + (l & 15);
  int koff = (l >> 4)*8;
  short8v a[4];
#pragma unroll
  for (int k = 0; k < 4; ++k) a[k] = *(const short8v*)(lout + (size_t)row*128 + k*32 + koff);
  int r0 = wv*16 + (l >> 4)*4;
#pragma unroll
  for (int nt = 0; nt < 24; ++nt){
    f4v acc = {0.f,0.f,0.f,0.f};
#pragma unroll
    for (int k = 0; k < 4; ++k){
      short8v b = *(const short8v*)(W + (size_t)(nt*16 + (l & 15))*128 + k*32 + koff);
      acc = mfma16(a[k], b, acc);
    }
    int col = nt*16 + (l & 15);
    float bv = b2f(bias[col]);
#pragma unroll
    for (int r = 0; r < 4; ++r) qkv[(size_t)(r0 + r)*384 + col] = f2b(acc[r] + bv);
  }
}

// one wave per (batch, head); mean over T fused (output projection deferred)
__global__ __launch_bounds__(64) void k_attn(const short* __restrict__ qkv, float* __restrict__ omean){
  int b = blockIdx.x >> 2, h = blockIdx.x & 3;
  int l = threadIdx.x;
  __shared__ float kl[50][32], vl[50][32], ol[50][32];
  for (int i = l; i < 1600; i += 64){
    int t = i >> 5, c = i & 31;
    kl[t][c] = b2f(qkv[((size_t)b*TT + t)*384 + 128 + h*32 + c]);
    vl[t][c] = b2f(qkv[((size_t)b*TT + t)*384 + 256 + h*32 + c]);
  }
  __syncthreads();
  float o[32];
#pragma unroll
  for (int c = 0; c < 32; ++c) o[c] = 0.f;
  if (l < TT){
    float q[32];
#pragma unroll
    for (int qq = 0; qq < 4; ++qq){
      short8v vq = *(const short8v*)(qkv + ((size_t)b*TT + l)*384 + h*32 + qq*8);
#pragma unroll
      for (int j = 0; j < 8; ++j) q[qq*8 + j] = b2f(vq[j]);
    }
    float sc[50];
    float mx = -1e30f;
    const float scale = 0.17677669529663687f;  // 1/sqrt(32)
#pragma unroll
    for (int j = 0; j < 50; ++j){
      float d = 0.f;
#pragma unroll
      for (int c = 0; c < 32; ++c) d += q[c]*kl[j][c];
      d *= scale;
      sc[j] = d;
      mx = fmaxf(mx, d);
    }
    float sum = 0.f;
#pragma unroll
    for (int j = 0; j < 50; ++j){ float p = __expf(sc[j] - mx); sc[j] = p; sum += p; }
    float inv = 1.f/sum;
#pragma unroll
    for (int j = 0; j < 50; ++j){
      float p = sc[j]*inv;
#pragma unroll
      for (int c = 0; c < 32; ++c) o[c] += p*vl[j][c];
    }
#pragma unroll
    for (int c = 0; c < 32; ++c) ol[l][c] = o[c];
  }
  __syncthreads();
  if (l < 32){
    float s = 0.f;
#pragma unroll
    for (int t = 0; t < TT; ++t) s += ol[t][l];
    omean[(size_t)b*128 + h*32 + l] = s*0.02f;  // mean over T=50
  }
}

// final: combined = [pool/cnt (64), omean @ Wout^T + bout (128)]; out = combined @ fc^T + fcb
__global__ __launch_bounds__(192) void k_final(const float* __restrict__ pool, const float* __restrict__ cntf,
                                               const float* __restrict__ omean,
                                               const short* __restrict__ Woutw, const short* __restrict__ Woutb,
                                               const short* __restrict__ fcw, const short* __restrict__ fcb,
                                               const int* __restrict__ flag, void* __restrict__ outv){
  int b = blockIdx.x;
  int tid = threadIdx.x;
  __shared__ float comb[192];
  if (tid < 64){
    float cnt = cntf[b];
    comb[tid] = pool[b*HD + tid] / fmaxf(cnt, 1.f);
  } else {
    int e = tid - 64;
    float s = b2f(Woutb[e]);
    for (int j = 0; j < 128; ++j) s += omean[(size_t)b*128 + j]*b2f(Woutw[e*128 + j]);
    comb[tid] = s;
  }
  __syncthreads();
  if (tid < 2){
    float s = b2f(fcb[tid]);
    for (int j = 0; j < 192; ++j) s += comb[j]*b2f(fcw[tid*192 + j]);
    if (*flag) ((short*)outv)[b*2 + tid] = f2b(s);
    else       ((float*)outv)[b*2 + tid] = s;
  }
}

extern "C" void kernel_launch(void* const* d_in, const int* in_sizes, int n_in,
                              void* d_out, int out_size, void* d_ws, size_t ws_size,
                              hipStream_t stream){
  const int* ei    = (const int*)d_in[1];
  const int* batch = (const int*)d_in[2];

  char* ws = (char*)d_ws;
  size_t o = 0;
  auto alloc = [&](size_t bytes)->char*{
    char* r = ws + o;
    o = (o + bytes + 255) & ~(size_t)255;
    return r;
  };
  short* arena = (short*)alloc((size_t)6787912*2);
  int*   flag  = (int*)alloc(256);
  char*  bufA  = alloc((size_t)NN*256*2);   // h1, later h2+g2
  char*  bufB  = alloc((size_t)NN*256*2);   // g1, later Xp/lout/qkv/omean
  float* a1s  = (float*)alloc((size_t)NN*4*4);
  float* a1d  = (float*)alloc((size_t)NN*4*4);
  float* a2s  = (float*)alloc((size_t)NN*4);
  float* a2d  = (float*)alloc((size_t)NN*4);
  int*   deg  = (int*)alloc((size_t)NPAD*4);
  int*   offv = (int*)alloc((size_t)(NN+1)*4);
  int*   cur  = (int*)alloc((size_t)NN*4);
  int*   csr  = (int*)alloc((size_t)ETOT*4);
  float* pool = (float*)alloc((size_t)BB*HD*4);
  float* cntf = (float*)alloc((size_t)BB*4);

  short* h1 = (short*)bufA;                       // [NN][256]
  short* h2 = (short*)bufA;                       // [NN][64] overlay (h1 dead after k_fagg1)
  short* g2 = (short*)(bufA + 12800000);          // [NN][64] bf16
  short* g1 = (short*)bufB;
  float* Xp   = (float*)bufB;                     // overlay (g1 dead after k_gemm2)
  short* lout = (short*)(bufB + 6553600);
  short* qkv  = (short*)(bufB + 6553600 + 819200);
  float* omean= (float*)(bufB + 6553600 + 819200 + 2457600);

  // arena views
  const short* xb    = arena + 0;
  const short* seqb  = arena + 6400000;
  const short* w1b   = arena + 6604800;
  const short* as1b  = arena + 6637568;
  const short* ad1b  = arena + 6637824;
  const short* b1b   = arena + 6638080;
  const short* w2b   = arena + 6638336;
  const short* as2b  = arena + 6654720;
  const short* ad2b  = arena + 6654784;
  const short* b2b   = arena + 6654848;
  const short* wihFb = arena + 6654912;
  const short* whhFb = arena + 6671296;
  const short* bihFb = arena + 6687680;
  const short* bhhFb = arena + 6687936;
  const short* wihBb = arena + 6688192;
  const short* whhBb = arena + 6704576;
  const short* bihBb = arena + 6720960;
  const short* bhhBb = arena + 6721216;
  const short* winwb = arena + 6721472;
  const short* winbb = arena + 6770624;
  const short* woutwb= arena + 6771008;
  const short* woutbb= arena + 6787392;
  const short* fcwb  = arena + 6787520;
  const short* fcbb  = arena + 6787904;

  Ptrs P;
  P.p[0]=d_in[0];  P.p[1]=d_in[3];  P.p[2]=d_in[4];  P.p[3]=d_in[5];
  P.p[4]=d_in[6];  P.p[5]=d_in[7];  P.p[6]=d_in[8];  P.p[7]=d_in[9];
  P.p[8]=d_in[10]; P.p[9]=d_in[11]; P.p[10]=d_in[12];P.p[11]=d_in[13];
  P.p[12]=d_in[14];P.p[13]=d_in[15];P.p[14]=d_in[16];P.p[15]=d_in[17];
  P.p[16]=d_in[18];P.p[17]=d_in[19];P.p[18]=d_in[20];P.p[19]=d_in[21];
  P.p[20]=d_in[22];P.p[21]=d_in[23];P.p[22]=d_in[24];P.p[23]=d_in[25];

  // convert (dtype detect folded in)
  k_cvt<<<2048, 256, 0, stream>>>(P, arena, flag);

  // CSR build
  k_init<<<(NPAD+255)/256, 256, 0, stream>>>(deg, pool);
  k_count<<<(EE+255)/256, 256, 0, stream>>>(ei, deg);
  k_scan<<<1, 1024, 0, stream>>>(deg, offv);
  k_self<<<(NN+255)/256, 256, 0, stream>>>(offv, cur, csr);
  k_scatter<<<(EE+255)/256, 256, 0, stream>>>(ei, cur, csr);

  // GAT layer 1
  k_gemm1<<<(NN/16+3)/4, 256, 0, stream>>>(xb, w1b, as1b, ad1b, h1, a1s, a1d);
  k_fagg1<<<(NN+3)/4, 256, 0, stream>>>(offv, csr, h1, a1s, a1d, b1b, g1);

  // GAT layer 2 + pool
  k_gemm2<<<(NN/16+3)/4, 256, 0, stream>>>(g1, w2b, as2b, ad2b, h2, a2s, a2d);
  k_fagg2<<<(NN+3)/4, 256, 0, stream>>>(offv, csr, h2, a2s, a2d, b2b, g2);
  k_pool<<<dim3(8, BB), 256, 0, stream>>>(g2, batch, pool, cntf);

  // LSTM
  k_xp<<<dim3(50, 2), 256, 0, stream>>>(seqb, wihFb, bihFb, bhhFb, wihBb, bihBb, bhhBb, Xp);
  k_lstm<<<dim3(4, 2), 256, 0, stream>>>(Xp, whhFb, whhBb, lout);

  // attention
  k_qkv<<<50, 256, 0, stream>>>(lout, winwb, winbb, qkv);
  k_attn<<<BB*4, 64, 0, stream>>>(qkv, omean);

  // final
  k_final<<<BB, 192, 0, stream>>>(pool, cntf, omean, woutwb, woutbb, fcwb, fcbb, flag, d_out);
}

// Round 14
// 315.312 us; speedup vs baseline: 1.5398x; 1.1128x over previous
//
#include <hip/hip_runtime.h>

#define NN 50000
#define EE 500000
#define BB 64
#define TT 50
#define FN 128
#define FS 64
#define HD 64
#define ETOT (EE + NN)
#define NPAD 50176   // 1024*49, k_scan guard-free

typedef __attribute__((ext_vector_type(8))) short short8v;
typedef __attribute__((ext_vector_type(4))) short short4v;
typedef __attribute__((ext_vector_type(4))) float f4v;

__device__ __forceinline__ float b2f(short u){
  union { unsigned int i; float f; } v; v.i = ((unsigned int)(unsigned short)u) << 16; return v.f;
}
__device__ __forceinline__ short f2b(float f){
  union { float f; unsigned int i; } v; v.f = f;
  unsigned int x = v.i;
  return (short)((x + 0x7fffu + ((x >> 16) & 1u)) >> 16);
}
__device__ __forceinline__ f4v mfma16(short8v a, short8v b, f4v c){
  return __builtin_amdgcn_mfma_f32_16x16x32_bf16(a, b, c, 0, 0, 0);
}
__device__ __forceinline__ float frcp(float x){ return __builtin_amdgcn_rcpf(x); }
__device__ __forceinline__ float fsig(float x){ return frcp(1.f + __expf(-x)); }
__device__ __forceinline__ float ftanh(float x){ return 1.f - 2.f*frcp(1.f + __expf(2.f*x)); }

// ---------------- input convert to bf16 arena (dtype detect + deg/pool init folded in) ----------------
constexpr int SEG_CUM[25] = {0, 6400000, 6604800, 6637568, 6637824, 6638080,
  6638336, 6654720, 6654784, 6654848, 6654912, 6671296, 6687680, 6687936,
  6688192, 6704576, 6720960, 6721216, 6721472, 6770624, 6771008, 6787392,
  6787520, 6787904, 6787906};
#define ARENA_VEC (6787904/8)

struct Ptrs { const void* p[24]; };

__global__ __launch_bounds__(256) void k_cvt(Ptrs P, short* arena, int* flag, int* deg, float* pool){
  // init (independent of conversion)
  int gi = blockIdx.x*256 + threadIdx.x;
  if (gi < NPAD) deg[gi] = (gi < NN) ? 1 : 0;     // self loop; pad zeros
  if (gi < BB*HD) pool[gi] = 0.f;

  __shared__ int cnt;
  if (threadIdx.x == 0) cnt = 0;
  __syncthreads();
  {
    const unsigned short* x16 = (const unsigned short*)P.p[0];
    int c = 0;
    for (int i = threadIdx.x; i < 2048; i += 256){
      unsigned short vv = x16[2*i];     // even shorts: f32 low-halves (random) vs bf16 values
      int e = (vv >> 7) & 0xFF;
      if (e >= 64 && e < 160) c++;
    }
    atomicAdd(&cnt, c);
  }
  __syncthreads();
  bool isb = (cnt >= 1536);             // 1 = inputs are bf16
  if (blockIdx.x == 0 && threadIdx.x == 0) *flag = isb ? 1 : 0;

  int idx = blockIdx.x*256 + threadIdx.x;
  for (int v = idx; v < ARENA_VEC; v += gridDim.x*256){
    int i = v*8;
    int s = 0;
#pragma unroll
    for (int k = 1; k < 24; ++k) if (i >= SEG_CUM[k]) s = k;
    int j = i - SEG_CUM[s];
    short8v o;
    if (isb){
      o = *(const short8v*)((const short*)P.p[s] + j);
    } else {
      const float* f = (const float*)P.p[s] + j;
      f4v lo = *(const f4v*)f;
      f4v hi = *(const f4v*)(f + 4);
#pragma unroll
      for (int q = 0; q < 4; ++q){ o[q] = f2b(lo[q]); o[4+q] = f2b(hi[q]); }
    }
    *(short8v*)(arena + i) = o;
  }
  if (blockIdx.x == 0 && threadIdx.x == 0){
    for (int j = 0; j < 2; ++j)
      arena[6787904 + j] = isb ? ((const short*)P.p[23])[j] : f2b(((const float*)P.p[23])[j]);
  }
}

// ---------------- CSR build ----------------
__global__ __launch_bounds__(256) void k_count(const int* ei, int* deg){
  int e = blockIdx.x*256 + threadIdx.x;
  if (e < EE) atomicAdd(&deg[ei[EE + e]], 1);
}

__global__ __launch_bounds__(1024) void k_scan(const int* __restrict__ deg, int* __restrict__ off){
  __shared__ int buf[1024];
  int tid = threadIdx.x;
  int start = tid*49;
  int v[49];
#pragma unroll
  for (int j = 0; j < 49; ++j) v[j] = deg[start + j];
  int s = 0;
#pragma unroll
  for (int j = 0; j < 49; ++j) s += v[j];
  buf[tid] = s;
  __syncthreads();
  for (int st = 1; st < 1024; st <<= 1){
    int t = (tid >= st) ? buf[tid - st] : 0;
    __syncthreads();
    buf[tid] += t;
    __syncthreads();
  }
  int run = buf[tid] - s;
#pragma unroll
  for (int j = 0; j < 49; ++j){
    int i = start + j;
    if (i < NN) off[i] = run;
    run += v[j];
  }
  if (tid == 1023) off[NN] = run;
}

__global__ __launch_bounds__(256) void k_self(const int* off, int* cur, int* csr){
  int v = blockIdx.x*256 + threadIdx.x;
  if (v < NN){ int o = off[v]; csr[o] = v; cur[v] = o + 1; }
}

__global__ __launch_bounds__(256) void k_scatter(const int* ei, int* cur, int* csr){
  int e = blockIdx.x*256 + threadIdx.x;
  if (e < EE){
    int d = ei[EE + e];
    int pos = atomicAdd(&cur[d], 1);
    csr[pos] = ei[e];
  }
}

// ---------------- F3: gemm1 (blocks 0..781) || xp (blocks 782..881) ----------------
__global__ __launch_bounds__(256) void k_g1xp(const short* __restrict__ x, const short* __restrict__ W1,
                                              const short* __restrict__ as1, const short* __restrict__ ad1,
                                              short* __restrict__ h1, float* __restrict__ a1s, float* __restrict__ a1d,
                                              const short* __restrict__ seq,
                                              const short* __restrict__ WihF, const short* __restrict__ bihF, const short* __restrict__ bhhF,
                                              const short* __restrict__ WihB, const short* __restrict__ bihB, const short* __restrict__ bhhB,
                                              float* __restrict__ Xp){
  int bid = blockIdx.x;
  int l = threadIdx.x & 63;
  if (bid < 782){
    // ---- gemm1 + fused scores
    int wv = bid*4 + (threadIdx.x >> 6);
    if (wv >= NN/16) return;
    int row = wv*16 + (l & 15);
    int koff = (l >> 4)*8;
    short8v a[4];
#pragma unroll
    for (int k = 0; k < 4; ++k) a[k] = *(const short8v*)(x + (size_t)row*128 + k*32 + koff);
    int r0 = wv*16 + (l >> 4)*4;
    float ssA[4][4], sdA[4][4];
#pragma unroll
    for (int h = 0; h < 4; ++h)
#pragma unroll
      for (int r = 0; r < 4; ++r){ ssA[h][r] = 0.f; sdA[h][r] = 0.f; }
#pragma unroll
    for (int nt = 0; nt < 16; ++nt){
      f4v acc = {0.f,0.f,0.f,0.f};
#pragma unroll
      for (int k = 0; k < 4; ++k){
        short8v b = *(const short8v*)(W1 + (size_t)(nt*16 + (l & 15))*128 + k*32 + koff);
        acc = mfma16(a[k], b, acc);
      }
      int col = nt*16 + (l & 15);
      float asv = b2f(as1[col]), adv = b2f(ad1[col]);
      int h = nt >> 2;
#pragma unroll
      for (int r = 0; r < 4; ++r){
        h1[(size_t)(r0 + r)*256 + col] = f2b(acc[r]);
        ssA[h][r] += acc[r]*asv;
        sdA[h][r] += acc[r]*adv;
      }
    }
#pragma unroll
    for (int m = 1; m < 16; m <<= 1){
#pragma unroll
      for (int h = 0; h < 4; ++h)
#pragma unroll
        for (int r = 0; r < 4; ++r){
          ssA[h][r] += __shfl_xor(ssA[h][r], m, 64);
          sdA[h][r] += __shfl_xor(sdA[h][r], m, 64);
        }
    }
    if ((l & 15) == 0){
#pragma unroll
      for (int r = 0; r < 4; ++r){
        f4v os, od;
        os[0]=ssA[0][r]; os[1]=ssA[1][r]; os[2]=ssA[2][r]; os[3]=ssA[3][r];
        od[0]=sdA[0][r]; od[1]=sdA[1][r]; od[2]=sdA[2][r]; od[3]=sdA[3][r];
        *(f4v*)(a1s + (size_t)(r0 + r)*4) = os;
        *(f4v*)(a1d + (size_t)(r0 + r)*4) = od;
      }
    }
  } else {
    // ---- xp: Xp in permuted gate order
    int bb = bid - 782;
    int dir = bb / 50;
    int bx  = bb % 50;
    const short* Wih = dir ? WihB : WihF;
    const short* bih = dir ? bihB : bihF;
    const short* bhh = dir ? bhhB : bhhF;
    int wv = bx*4 + (threadIdx.x >> 6);
    int row = wv*16 + (l & 15);
    int koff = (l >> 4)*8;
    short8v a[2];
#pragma unroll
    for (int k = 0; k < 2; ++k) a[k] = *(const short8v*)(seq + (size_t)row*64 + k*32 + koff);
    int r0 = wv*16 + (l >> 4)*4;
    float* Xpd = Xp + (size_t)dir*TT*BB*256;
#pragma unroll
    for (int nt = 0; nt < 16; ++nt){
      f4v acc = {0.f,0.f,0.f,0.f};
#pragma unroll
      for (int k = 0; k < 2; ++k){
        short8v b = *(const short8v*)(Wih + (size_t)(nt*16 + (l & 15))*64 + k*32 + koff);
        acc = mfma16(a[k], b, acc);
      }
      int col = nt*16 + (l & 15);
      float bias = b2f(bih[col]) + b2f(bhh[col]);
      int gate = col >> 6, ch = col & 63;
      int pcol = ((ch>>5)*8 + ((ch>>4)&1)*4 + gate)*16 + (ch & 15);
#pragma unroll
      for (int r = 0; r < 4; ++r){
        int rr = r0 + r;
        int bidx = rr / TT, t = rr % TT;
        Xpd[((size_t)t*BB + bidx)*256 + pcol] = acc[r] + bias;
      }
    }
  }
}

// ---------------- F4: fagg1 (blocks 0..12499) || lstm (blocks 12500..12507) ----------------
union ShF4 {
  struct { int s_u[4][64]; float s_p[4][64][4]; } agg;   // 5.1 KB
  struct { short hl[2][16][72]; } rec;                   // 4.6 KB
};

__global__ __launch_bounds__(256) void k_f1ls(const int* __restrict__ off, const int* __restrict__ csr,
                                              const short* __restrict__ h1, const float* __restrict__ a1s,
                                              const float* __restrict__ a1d, const short* __restrict__ b1,
                                              short* __restrict__ g1,
                                              const float* __restrict__ Xp,
                                              const short* __restrict__ WhhF, const short* __restrict__ WhhB,
                                              short* __restrict__ lout){
  __shared__ ShF4 sh;
  int bid = blockIdx.x;
  int tid = threadIdx.x;
  int l = tid & 63;
  if (bid < 12500){
    // ---- fagg1: PhaseA lane=edge; PhaseB 2 rows/iter 16B/lane
    int v = bid*4 + (tid >> 6);
    if (v >= NN) return;
    int w = tid >> 6;
    int rp  = l >> 5;
    int ch8 = (l & 31)*8;
    int hh  = (l & 31) >> 3;
    const f4v ad4 = *(const f4v*)(a1d + v*4);
    int e0 = off[v], e1 = off[v+1];
    float s0=0.f,s1=0.f,s2=0.f,s3=0.f;
    float acc[8] = {0.f,0.f,0.f,0.f,0.f,0.f,0.f,0.f};

    for (int base = e0; base < e1; base += 64){
      int nc = e1 - base; if (nc > 64) nc = 64;
      int u = v;
      float p0=0.f,p1=0.f,p2=0.f,p3=0.f;
      if (l < nc){
        u = csr[base + l];
        f4v as4 = *(const f4v*)(a1s + u*4);
        float t0 = as4[0]+ad4[0]; t0 = (t0>=0.f)?t0:0.2f*t0; p0 = __expf(fminf(t0,30.f));
        float t1 = as4[1]+ad4[1]; t1 = (t1>=0.f)?t1:0.2f*t1; p1 = __expf(fminf(t1,30.f));
        float t2 = as4[2]+ad4[2]; t2 = (t2>=0.f)?t2:0.2f*t2; p2 = __expf(fminf(t2,30.f));
        float t3 = as4[3]+ad4[3]; t3 = (t3>=0.f)?t3:0.2f*t3; p3 = __expf(fminf(t3,30.f));
      }
      sh.agg.s_u[w][l] = u;
      f4v pv; pv[0]=p0; pv[1]=p1; pv[2]=p2; pv[3]=p3;
      *(f4v*)&sh.agg.s_p[w][l][0] = pv;
      float q0=p0,q1=p1,q2=p2,q3=p3;
#pragma unroll
      for (int st = 1; st < 64; st <<= 1){
        q0 += __shfl_xor(q0, st, 64);
        q1 += __shfl_xor(q1, st, 64);
        q2 += __shfl_xor(q2, st, 64);
        q3 += __shfl_xor(q3, st, 64);
      }
      s0 += q0; s1 += q1; s2 += q2; s3 += q3;
      asm volatile("s_waitcnt lgkmcnt(0)" ::: "memory");
      int nit = (nc + 1) >> 1;
#pragma unroll 4
      for (int i = 0; i < nit; ++i){
        int idx = i*2 + rp;
        int   ui = sh.agg.s_u[w][idx];
        float pi = sh.agg.s_p[w][idx][hh];
        short8v hv = *(const short8v*)(h1 + (size_t)ui*256 + ch8);
#pragma unroll
        for (int j = 0; j < 8; ++j) acc[j] += pi*b2f(hv[j]);
      }
      asm volatile("s_waitcnt lgkmcnt(0)" ::: "memory");
    }
#pragma unroll
    for (int j = 0; j < 8; ++j) acc[j] += __shfl_xor(acc[j], 32, 64);
    if (l < 32){
      float mys = (hh==0)?s0:((hh==1)?s1:((hh==2)?s2:s3));
      float inv = 1.f/mys;
      short8v bb = *(const short8v*)(b1 + ch8);
      short8v o;
#pragma unroll
      for (int j = 0; j < 8; ++j) o[j] = f2b(fmaxf(acc[j]*inv + b2f(bb[j]), 0.f));
      *(short8v*)(g1 + (size_t)v*256 + ch8) = o;
    }
  } else {
    // ---- lstm: 2 dir x 4 batch-groups; Whh fragments in REGISTERS
    int bb = bid - 12500;
    int bg = bb & 3, dir = bb >> 2;
    const short* Whh = dir ? WhhB : WhhF;
    const float* Xpd = Xp + (size_t)dir*TT*BB*256 + (size_t)bg*16*256;
    for (int i = tid; i < 16*64; i += 256) sh.rec.hl[0][i>>6][i&63] = 0;

    int w = tid >> 6;
    int c16 = l & 15;
    int koff = (l >> 4)*8;
    int r0 = (l >> 4)*4;
    int ch = (w>>1)*32 + (w&1)*16 + c16;
    // loop-invariant Whh fragments -> registers
    short8v wb0[4], wb1[4];
#pragma unroll
    for (int j = 0; j < 4; ++j){
      int nt = w*4 + j;
      int jj = nt & 7, half = nt >> 3;
      int gate = jj & 3, chx = half*32 + (jj>>2)*16 + c16;
      int src = gate*64 + chx;
      wb0[j] = *(const short8v*)(Whh + (size_t)src*64 + koff);
      wb1[j] = *(const short8v*)(Whh + (size_t)src*64 + 32 + koff);
    }
    float creg[4] = {0.f,0.f,0.f,0.f};

    float xg[4][4];
    {
      int t0 = dir ? (TT-1) : 0;
      const float* xpb = Xpd + (size_t)t0*BB*256;
#pragma unroll
      for (int j = 0; j < 4; ++j){
        int p = (w*4 + j)*16 + c16;
#pragma unroll
        for (int r = 0; r < 4; ++r) xg[j][r] = xpb[(size_t)(r0 + r)*256 + p];
      }
    }

    int cur = 0;
    for (int s = 0; s < TT; ++s){
      int t = dir ? (TT - 1 - s) : s;
      __syncthreads();
      float xgn[4][4];
      if (s + 1 < TT){
        int tn = dir ? (TT - 2 - s) : (s + 1);
        const float* xpb = Xpd + (size_t)tn*BB*256;
#pragma unroll
        for (int j = 0; j < 4; ++j){
          int p = (w*4 + j)*16 + c16;
#pragma unroll
          for (int r = 0; r < 4; ++r) xgn[j][r] = xpb[(size_t)(r0 + r)*256 + p];
        }
      }
      short8v a0 = *(const short8v*)&sh.rec.hl[cur][c16][koff];
      short8v a1 = *(const short8v*)&sh.rec.hl[cur][c16][32 + koff];
      f4v acc[4];
#pragma unroll
      for (int j = 0; j < 4; ++j){
        f4v z = {0.f,0.f,0.f,0.f};
        z = mfma16(a0, wb0[j], z);
        z = mfma16(a1, wb1[j], z);
        acc[j] = z;
      }
      int nxt = cur ^ 1;
#pragma unroll
      for (int r = 0; r < 4; ++r){
        float gi = acc[0][r] + xg[0][r];
        float gf = acc[1][r] + xg[1][r];
        float gg = acc[2][r] + xg[2][r];
        float go = acc[3][r] + xg[3][r];
        float cn = fsig(gf)*creg[r] + fsig(gi)*ftanh(gg);
        creg[r] = cn;
        float hv = fsig(go)*ftanh(cn);
        short hb = f2b(hv);
        int row = r0 + r;
        sh.rec.hl[nxt][row][ch] = hb;
        lout[((size_t)(bg*16 + row)*TT + t)*128 + dir*64 + ch] = hb;
      }
#pragma unroll
      for (int j = 0; j < 4; ++j)
#pragma unroll
        for (int r = 0; r < 4; ++r) xg[j][r] = xgn[j][r];
      cur = nxt;
    }
  }
}

// ---------------- F5: gemm2 (blocks 0..781) || qkv (blocks 782..831) ----------------
__global__ __launch_bounds__(256) void k_g2qk(const short* __restrict__ g1, const short* __restrict__ W2,
                                              const short* __restrict__ as2, const short* __restrict__ ad2,
                                              short* __restrict__ h2, float* __restrict__ a2s, float* __restrict__ a2d,
                                              const short* __restrict__ lout, const short* __restrict__ Winw,
                                              const short* __restrict__ Winb, short* __restrict__ qkv){
  int bid = blockIdx.x;
  int l = threadIdx.x & 63;
  if (bid < 782){
    int wv = bid*4 + (threadIdx.x >> 6);
    if (wv >= NN/16) return;
    int row = wv*16 + (l & 15);
    int koff = (l >> 4)*8;
    short8v a[8];
#pragma unroll
    for (int k = 0; k < 8; ++k) a[k] = *(const short8v*)(g1 + (size_t)row*256 + k*32 + koff);
    int r0 = wv*16 + (l >> 4)*4;
    float ss[4] = {0.f,0.f,0.f,0.f}, sd[4] = {0.f,0.f,0.f,0.f};
#pragma unroll
    for (int nt = 0; nt < 4; ++nt){
      f4v acc = {0.f,0.f,0.f,0.f};
#pragma unroll
      for (int k = 0; k < 8; ++k){
        short8v b = *(const short8v*)(W2 + (size_t)(nt*16 + (l & 15))*256 + k*32 + koff);
        acc = mfma16(a[k], b, acc);
      }
      int col = nt*16 + (l & 15);
      float asv = b2f(as2[col]), adv = b2f(ad2[col]);
#pragma unroll
      for (int r = 0; r < 4; ++r){
        h2[(size_t)(r0 + r)*64 + col] = f2b(acc[r]);
        ss[r] += acc[r]*asv;
        sd[r] += acc[r]*adv;
      }
    }
#pragma unroll
    for (int m = 1; m < 16; m <<= 1){
#pragma unroll
      for (int r = 0; r < 4; ++r){
        ss[r] += __shfl_xor(ss[r], m, 64);
        sd[r] += __shfl_xor(sd[r], m, 64);
      }
    }
    if ((l & 15) == 0){
#pragma unroll
      for (int r = 0; r < 4; ++r){
        a2s[r0 + r] = ss[r];
        a2d[r0 + r] = sd[r];
      }
    }
  } else {
    int wv = (bid - 782)*4 + (threadIdx.x >> 6);
    int row = wv*16 + (l & 15);
    int koff = (l >> 4)*8;
    short8v a[4];
#pragma unroll
    for (int k = 0; k < 4; ++k) a[k] = *(const short8v*)(lout + (size_t)row*128 + k*32 + koff);
    int r0 = wv*16 + (l >> 4)*4;
#pragma unroll
    for (int nt = 0; nt < 24; ++nt){
      f4v acc = {0.f,0.f,0.f,0.f};
#pragma unroll
      for (int k = 0; k < 4; ++k){
        short8v b = *(const short8v*)(Winw + (size_t)(nt*16 + (l & 15))*128 + k*32 + koff);
        acc = mfma16(a[k], b, acc);
      }
      int col = nt*16 + (l & 15);
      float bv = b2f(Winb[col]);
#pragma unroll
      for (int r = 0; r < 4; ++r) qkv[(size_t)(r0 + r)*384 + col] = f2b(acc[r] + bv);
    }
  }
}

// ---- fused alpha+gather layer 2: PhaseB 8 rows/iter, 16B/lane
__global__ __launch_bounds__(256) void k_fagg2(const int* __restrict__ off, const int* __restrict__ csr,
                                               const short* __restrict__ h2, const float* __restrict__ a2s,
                                               const float* __restrict__ a2d, const short* __restrict__ b2,
                                               short* __restrict__ g2){
  __shared__ int   s_u[4][64];
  __shared__ float s_p[4][64];
  int v = blockIdx.x*4 + (threadIdx.x >> 6);
  if (v >= NN) return;
  int w = threadIdx.x >> 6;
  int l = threadIdx.x & 63;
  int rp  = l >> 3;
  int ch8 = (l & 7)*8;
  float adst = a2d[v];
  int e0 = off[v], e1 = off[v+1];
  float s = 0.f;
  float acc[8] = {0.f,0.f,0.f,0.f,0.f,0.f,0.f,0.f};

  for (int base = e0; base < e1; base += 64){
    int nc = e1 - base; if (nc > 64) nc = 64;
    int u = v;
    float p = 0.f;
    if (l < nc){
      u = csr[base + l];
      float t = a2s[u] + adst;
      t = (t>=0.f)?t:0.2f*t;
      p = __expf(fminf(t,30.f));
    }
    s_u[w][l] = u;
    s_p[w][l] = p;
    float q = p;
#pragma unroll
    for (int st = 1; st < 64; st <<= 1) q += __shfl_xor(q, st, 64);
    s += q;
    asm volatile("s_waitcnt lgkmcnt(0)" ::: "memory");
    int nit = (nc + 7) >> 3;
#pragma unroll 2
    for (int i = 0; i < nit; ++i){
      int idx = i*8 + rp;
      int   ui = s_u[w][idx];
      float pi = s_p[w][idx];
      short8v hv = *(const short8v*)(h2 + (size_t)ui*64 + ch8);
#pragma unroll
      for (int j = 0; j < 8; ++j) acc[j] += pi*b2f(hv[j]);
    }
    asm volatile("s_waitcnt lgkmcnt(0)" ::: "memory");
  }
#pragma unroll
  for (int m = 8; m < 64; m <<= 1)
#pragma unroll
    for (int j = 0; j < 8; ++j) acc[j] += __shfl_xor(acc[j], m, 64);
  if (l < 8){
    float inv = 1.f/s;
    short8v bb = *(const short8v*)(b2 + ch8);
    short8v o;
#pragma unroll
    for (int j = 0; j < 8; ++j) o[j] = f2b(fmaxf(acc[j]*inv + b2f(bb[j]), 0.f));
    *(short8v*)(g2 + (size_t)v*64 + ch8) = o;
  }
}

// ---------------- F6: pool (blocks 0..511) || attn (blocks 512..767, 256-thread) ----------------
union ShF6 {
  struct { int seg[2]; float red[4][64]; } pl;
  struct { float kl[50][32]; float vl[50][32]; float ol[50][32]; } at;
};

__global__ __launch_bounds__(256) void k_plat(const short* __restrict__ g2, const int* __restrict__ batch,
                                              float* __restrict__ pool, float* __restrict__ cntf,
                                              const short* __restrict__ qkv, float* __restrict__ omean){
  __shared__ ShF6 sh;
  int bid = blockIdx.x;
  int tid = threadIdx.x;
  if (bid < 512){
    int split = bid & 7;
    int b = bid >> 3;
    if (tid == 0){
      int lo = 0, hi = NN;
      while (lo < hi){ int mid = (lo+hi)>>1; if (batch[mid] < b) lo = mid+1; else hi = mid; }
      sh.pl.seg[0] = lo;
      lo = 0; hi = NN;
      while (lo < hi){ int mid = (lo+hi)>>1; if (batch[mid] < b+1) lo = mid+1; else hi = mid; }
      sh.pl.seg[1] = lo;
    }
    __syncthreads();
    int lo = sh.pl.seg[0], hi = sh.pl.seg[1];
    int c = tid & 63;
    int rg = tid >> 6;
    float acc = 0.f;
    for (int r = lo + split*4 + rg; r < hi; r += 32)
      acc += b2f(g2[(size_t)r*64 + c]);
    sh.pl.red[rg][c] = acc;
    __syncthreads();
    if (tid < 64){
      float sum = sh.pl.red[0][tid] + sh.pl.red[1][tid] + sh.pl.red[2][tid] + sh.pl.red[3][tid];
      atomicAdd(&pool[b*HD + tid], sum);
    }
    if (split == 0 && tid == 0) cntf[b] = (float)(hi - lo);
  } else {
    int bb = bid - 512;
    int b = bb >> 2, h = bb & 3;
    for (int i = tid; i < 1600; i += 256){
      int t = i >> 5, c = i & 31;
      sh.at.kl[t][c] = b2f(qkv[((size_t)b*TT + t)*384 + 128 + h*32 + c]);
      sh.at.vl[t][c] = b2f(qkv[((size_t)b*TT + t)*384 + 256 + h*32 + c]);
    }
    __syncthreads();
    if (tid < TT){
      float q[32];
#pragma unroll
      for (int qq = 0; qq < 4; ++qq){
        short8v vq = *(const short8v*)(qkv + ((size_t)b*TT + tid)*384 + h*32 + qq*8);
#pragma unroll
        for (int j = 0; j < 8; ++j) q[qq*8 + j] = b2f(vq[j]);
      }
      float sc[50];
      float mx = -1e30f;
      const float scale = 0.17677669529663687f;
#pragma unroll
      for (int j = 0; j < 50; ++j){
        float d = 0.f;
#pragma unroll
        for (int c = 0; c < 32; ++c) d += q[c]*sh.at.kl[j][c];
        d *= scale;
        sc[j] = d;
        mx = fmaxf(mx, d);
      }
      float sum = 0.f;
#pragma unroll
      for (int j = 0; j < 50; ++j){ float p = __expf(sc[j] - mx); sc[j] = p; sum += p; }
      float inv = 1.f/sum;
      float o[32];
#pragma unroll
      for (int c = 0; c < 32; ++c) o[c] = 0.f;
#pragma unroll
      for (int j = 0; j < 50; ++j){
        float p = sc[j]*inv;
#pragma unroll
        for (int c = 0; c < 32; ++c) o[c] += p*sh.at.vl[j][c];
      }
#pragma unroll
      for (int c = 0; c < 32; ++c) sh.at.ol[tid][c] = o[c];
    }
    __syncthreads();
    if (tid < 32){
      float s = 0.f;
#pragma unroll
      for (int t = 0; t < TT; ++t) s += sh.at.ol[t][tid];
      omean[(size_t)b*128 + h*32 + tid] = s*0.02f;
    }
  }
}

// final: combined = [pool/cnt (64), omean @ Wout^T + bout (128)]; out = combined @ fc^T + fcb
__global__ __launch_bounds__(192) void k_final(const float* __restrict__ pool, const float* __restrict__ cntf,
                                               const float* __restrict__ omean,
                                               const short* __restrict__ Woutw, const short* __restrict__ Woutb,
                                               const short* __restrict__ fcw, const short* __restrict__ fcb,
                                               const int* __restrict__ flag, void* __restrict__ outv){
  int b = blockIdx.x;
  int tid = threadIdx.x;
  __shared__ float comb[192];
  if (tid < 64){
    float cnt = cntf[b];
    comb[tid] = pool[b*HD + tid] / fmaxf(cnt, 1.f);
  } else {
    int e = tid - 64;
    float s = b2f(Woutb[e]);
    for (int j = 0; j < 128; ++j) s += omean[(size_t)b*128 + j]*b2f(Woutw[e*128 + j]);
    comb[tid] = s;
  }
  __syncthreads();
  if (tid < 2){
    float s = b2f(fcb[tid]);
    for (int j = 0; j < 192; ++j) s += comb[j]*b2f(fcw[tid*192 + j]);
    if (*flag) ((short*)outv)[b*2 + tid] = f2b(s);
    else       ((float*)outv)[b*2 + tid] = s;
  }
}

extern "C" void kernel_launch(void* const* d_in, const int* in_sizes, int n_in,
                              void* d_out, int out_size, void* d_ws, size_t ws_size,
                              hipStream_t stream){
  const int* ei    = (const int*)d_in[1];
  const int* batch = (const int*)d_in[2];

  char* ws = (char*)d_ws;
  size_t o = 0;
  auto alloc = [&](size_t bytes)->char*{
    char* r = ws + o;
    o = (o + bytes + 255) & ~(size_t)255;
    return r;
  };
  short* arena = (short*)alloc((size_t)6787912*2);
  int*   flag  = (int*)alloc(256);
  char*  bufA  = alloc((size_t)NN*256*2);   // h1, later h2+g2
  char*  bufB  = alloc((size_t)NN*256*2);   // g1, later Xp/lout/qkv/omean
  float* a1s  = (float*)alloc((size_t)NN*4*4);
  float* a1d  = (float*)alloc((size_t)NN*4*4);
  float* a2s  = (float*)alloc((size_t)NN*4);
  float* a2d  = (float*)alloc((size_t)NN*4);
  int*   deg  = (int*)alloc((size_t)NPAD*4);
  int*   offv = (int*)alloc((size_t)(NN+1)*4);
  int*   cur  = (int*)alloc((size_t)NN*4);
  int*   csr  = (int*)alloc((size_t)ETOT*4);
  float* pool = (float*)alloc((size_t)BB*HD*4);
  float* cntf = (float*)alloc((size_t)BB*4);

  short* h1 = (short*)bufA;                       // [NN][256]
  short* h2 = (short*)bufA;                       // [NN][64] overlay (h1 dead after k_f1ls)
  short* g2 = (short*)(bufA + 12800000);          // [NN][64] bf16
  short* g1 = (short*)bufB;
  float* Xp   = (float*)(bufB + 12800000);        // [2][TT][BB][256] f32 = 6.55MB... placed after g1? see note
  // NOTE: g1 is [NN][256] bf16 = 25.6MB (all of bufB). Xp must NOT overlay g1 while both live.
  // Xp lives from k_g1xp until k_f1ls; g1 lives from k_f1ls until k_g2qk. Both alive during k_f1ls!
  // -> allocate Xp separately.
  Xp = (float*)alloc((size_t)2*TT*BB*256*4);
  short* lout = (short*)alloc((size_t)BB*TT*128*2);
  short* qkv  = (short*)alloc((size_t)BB*TT*384*2);
  float* omean= (float*)alloc((size_t)BB*128*4);

  // arena views
  const short* xb    = arena + 0;
  const short* seqb  = arena + 6400000;
  const short* w1b   = arena + 6604800;
  const short* as1b  = arena + 6637568;
  const short* ad1b  = arena + 6637824;
  const short* b1b   = arena + 6638080;
  const short* w2b   = arena + 6638336;
  const short* as2b  = arena + 6654720;
  const short* ad2b  = arena + 6654784;
  const short* b2b   = arena + 6654848;
  const short* wihFb = arena + 6654912;
  const short* whhFb = arena + 6671296;
  const short* bihFb = arena + 6687680;
  const short* bhhFb = arena + 6687936;
  const short* wihBb = arena + 6688192;
  const short* whhBb = arena + 6704576;
  const short* bihBb = arena + 6720960;
  const short* bhhBb = arena + 6721216;
  const short* winwb = arena + 6721472;
  const short* winbb = arena + 6770624;
  const short* woutwb= arena + 6771008;
  const short* woutbb= arena + 6787392;
  const short* fcwb  = arena + 6787520;
  const short* fcbb  = arena + 6787904;

  Ptrs P;
  P.p[0]=d_in[0];  P.p[1]=d_in[3];  P.p[2]=d_in[4];  P.p[3]=d_in[5];
  P.p[4]=d_in[6];  P.p[5]=d_in[7];  P.p[6]=d_in[8];  P.p[7]=d_in[9];
  P.p[8]=d_in[10]; P.p[9]=d_in[11]; P.p[10]=d_in[12];P.p[11]=d_in[13];
  P.p[12]=d_in[14];P.p[13]=d_in[15];P.p[14]=d_in[16];P.p[15]=d_in[17];
  P.p[16]=d_in[18];P.p[17]=d_in[19];P.p[18]=d_in[20];P.p[19]=d_in[21];
  P.p[20]=d_in[22];P.p[21]=d_in[23];P.p[22]=d_in[24];P.p[23]=d_in[25];

  // convert (+deg/pool init, dtype detect)
  k_cvt<<<2048, 256, 0, stream>>>(P, arena, flag, deg, pool);

  // CSR build
  k_count<<<(EE+255)/256, 256, 0, stream>>>(ei, deg);
  k_scan<<<1, 1024, 0, stream>>>(deg, offv);
  k_self<<<(NN+255)/256, 256, 0, stream>>>(offv, cur, csr);
  k_scatter<<<(EE+255)/256, 256, 0, stream>>>(ei, cur, csr);

  // F3: GAT1 GEMM || LSTM pre-GEMM
  k_g1xp<<<882, 256, 0, stream>>>(xb, w1b, as1b, ad1b, h1, a1s, a1d,
                                  seqb, wihFb, bihFb, bhhFb, wihBb, bihBb, bhhBb, Xp);
  // F4: GAT1 aggregate || LSTM recurrence
  k_f1ls<<<12508, 256, 0, stream>>>(offv, csr, h1, a1s, a1d, b1b, g1,
                                    Xp, whhFb, whhBb, lout);
  // F5: GAT2 GEMM || attention QKV
  k_g2qk<<<832, 256, 0, stream>>>(g1, w2b, as2b, ad2b, h2, a2s, a2d,
                                  lout, winwb, winbb, qkv);
  // GAT2 aggregate
  k_fagg2<<<(NN+3)/4, 256, 0, stream>>>(offv, csr, h2, a2s, a2d, b2b, g2);
  // F6: pool || attention softmax+mean
  k_plat<<<768, 256, 0, stream>>>(g2, batch, pool, cntf, qkv, omean);

  // final
  k_final<<<BB, 192, 0, stream>>>(pool, cntf, omean, woutwb, woutbb, fcwb, fcbb, flag, d_out);
}

// Round 15
// 279.748 us; speedup vs baseline: 1.7356x; 1.1271x over previous
//
#include <hip/hip_runtime.h>

#define NN 50000
#define EE 500000
#define BB 64
#define TT 50
#define FN 128
#define FS 64
#define HD 64
#define ETOT (EE + NN)
#define NPAD 50176   // 1024*49, k_scan guard-free

typedef __attribute__((ext_vector_type(8))) short short8v;
typedef __attribute__((ext_vector_type(4))) short short4v;
typedef __attribute__((ext_vector_type(4))) float f4v;

__device__ __forceinline__ float b2f(short u){
  union { unsigned int i; float f; } v; v.i = ((unsigned int)(unsigned short)u) << 16; return v.f;
}
__device__ __forceinline__ short f2b(float f){
  union { float f; unsigned int i; } v; v.f = f;
  unsigned int x = v.i;
  return (short)((x + 0x7fffu + ((x >> 16) & 1u)) >> 16);
}
__device__ __forceinline__ f4v mfma16(short8v a, short8v b, f4v c){
  return __builtin_amdgcn_mfma_f32_16x16x32_bf16(a, b, c, 0, 0, 0);
}
__device__ __forceinline__ float frcp(float x){ return __builtin_amdgcn_rcpf(x); }
__device__ __forceinline__ float fsig(float x){ return frcp(1.f + __expf(-x)); }
__device__ __forceinline__ float ftanh(float x){ return 1.f - 2.f*frcp(1.f + __expf(2.f*x)); }

// ---------------- input convert to bf16 arena (dtype detect + deg/pool init folded in) ----------------
constexpr int SEG_CUM[25] = {0, 6400000, 6604800, 6637568, 6637824, 6638080,
  6638336, 6654720, 6654784, 6654848, 6654912, 6671296, 6687680, 6687936,
  6688192, 6704576, 6720960, 6721216, 6721472, 6770624, 6771008, 6787392,
  6787520, 6787904, 6787906};
#define ARENA_VEC (6787904/8)

struct Ptrs { const void* p[24]; };

__global__ __launch_bounds__(256) void k_cvt(Ptrs P, short* arena, int* flag, int* deg, float* pool){
  int gi = blockIdx.x*256 + threadIdx.x;
  if (gi < NPAD) deg[gi] = (gi < NN) ? 1 : 0;     // self loop; pad zeros
  if (gi < BB*HD) pool[gi] = 0.f;

  __shared__ int cnt;
  if (threadIdx.x == 0) cnt = 0;
  __syncthreads();
  {
    const unsigned short* x16 = (const unsigned short*)P.p[0];
    int c = 0;
    for (int i = threadIdx.x; i < 2048; i += 256){
      unsigned short vv = x16[2*i];     // even shorts: f32 low-halves (random) vs bf16 values
      int e = (vv >> 7) & 0xFF;
      if (e >= 64 && e < 160) c++;
    }
    atomicAdd(&cnt, c);
  }
  __syncthreads();
  bool isb = (cnt >= 1536);             // 1 = inputs are bf16
  if (blockIdx.x == 0 && threadIdx.x == 0) *flag = isb ? 1 : 0;

  int idx = blockIdx.x*256 + threadIdx.x;
  for (int v = idx; v < ARENA_VEC; v += gridDim.x*256){
    int i = v*8;
    int s = 0;
#pragma unroll
    for (int k = 1; k < 24; ++k) if (i >= SEG_CUM[k]) s = k;
    int j = i - SEG_CUM[s];
    short8v o;
    if (isb){
      o = *(const short8v*)((const short*)P.p[s] + j);
    } else {
      const float* f = (const float*)P.p[s] + j;
      f4v lo = *(const f4v*)f;
      f4v hi = *(const f4v*)(f + 4);
#pragma unroll
      for (int q = 0; q < 4; ++q){ o[q] = f2b(lo[q]); o[4+q] = f2b(hi[q]); }
    }
    *(short8v*)(arena + i) = o;
  }
  if (blockIdx.x == 0 && threadIdx.x == 0){
    for (int j = 0; j < 2; ++j)
      arena[6787904 + j] = isb ? ((const short*)P.p[23])[j] : f2b(((const float*)P.p[23])[j]);
  }
}

// ---------------- CSR build ----------------
__global__ __launch_bounds__(256) void k_count(const int* ei, int* deg){
  int e = blockIdx.x*256 + threadIdx.x;
  if (e < EE) atomicAdd(&deg[ei[EE + e]], 1);
}

__global__ __launch_bounds__(1024) void k_scan(const int* __restrict__ deg, int* __restrict__ off){
  __shared__ int buf[1024];
  int tid = threadIdx.x;
  int start = tid*49;
  int v[49];
#pragma unroll
  for (int j = 0; j < 49; ++j) v[j] = deg[start + j];
  int s = 0;
#pragma unroll
  for (int j = 0; j < 49; ++j) s += v[j];
  buf[tid] = s;
  __syncthreads();
  for (int st = 1; st < 1024; st <<= 1){
    int t = (tid >= st) ? buf[tid - st] : 0;
    __syncthreads();
    buf[tid] += t;
    __syncthreads();
  }
  int run = buf[tid] - s;
#pragma unroll
  for (int j = 0; j < 49; ++j){
    int i = start + j;
    if (i < NN) off[i] = run;
    run += v[j];
  }
  if (tid == 1023) off[NN] = run;
}

__global__ __launch_bounds__(256) void k_self(const int* off, int* cur, int* csr){
  int v = blockIdx.x*256 + threadIdx.x;
  if (v < NN){ int o = off[v]; csr[o] = v; cur[v] = o + 1; }
}

__global__ __launch_bounds__(256) void k_scatter(const int* ei, int* cur, int* csr){
  int e = blockIdx.x*256 + threadIdx.x;
  if (e < EE){
    int d = ei[EE + e];
    int pos = atomicAdd(&cur[d], 1);
    csr[pos] = ei[e];
  }
}

// ---------------- F3: xp (blocks 0..99) || gemm1 (blocks 100..881) ----------------
__global__ __launch_bounds__(256) void k_g1xp(const short* __restrict__ x, const short* __restrict__ W1,
                                              const short* __restrict__ as1, const short* __restrict__ ad1,
                                              short* __restrict__ h1, float* __restrict__ a1s, float* __restrict__ a1d,
                                              const short* __restrict__ seq,
                                              const short* __restrict__ WihF, const short* __restrict__ bihF, const short* __restrict__ bhhF,
                                              const short* __restrict__ WihB, const short* __restrict__ bihB, const short* __restrict__ bhhB,
                                              float* __restrict__ Xp){
  int bid = blockIdx.x;
  int l = threadIdx.x & 63;
  if (bid < 100){
    // ---- xp: Xp in permuted gate order (small branch FIRST for early dispatch)
    int dir = bid / 50;
    int bx  = bid % 50;
    const short* Wih = dir ? WihB : WihF;
    const short* bih = dir ? bihB : bihF;
    const short* bhh = dir ? bhhB : bhhF;
    int wv = bx*4 + (threadIdx.x >> 6);
    int row = wv*16 + (l & 15);
    int koff = (l >> 4)*8;
    short8v a[2];
#pragma unroll
    for (int k = 0; k < 2; ++k) a[k] = *(const short8v*)(seq + (size_t)row*64 + k*32 + koff);
    int r0 = wv*16 + (l >> 4)*4;
    float* Xpd = Xp + (size_t)dir*TT*BB*256;
#pragma unroll
    for (int nt = 0; nt < 16; ++nt){
      f4v acc = {0.f,0.f,0.f,0.f};
#pragma unroll
      for (int k = 0; k < 2; ++k){
        short8v b = *(const short8v*)(Wih + (size_t)(nt*16 + (l & 15))*64 + k*32 + koff);
        acc = mfma16(a[k], b, acc);
      }
      int col = nt*16 + (l & 15);
      float bias = b2f(bih[col]) + b2f(bhh[col]);
      int gate = col >> 6, ch = col & 63;
      int pcol = ((ch>>5)*8 + ((ch>>4)&1)*4 + gate)*16 + (ch & 15);
#pragma unroll
      for (int r = 0; r < 4; ++r){
        int rr = r0 + r;
        int bidx = rr / TT, t = rr % TT;
        Xpd[((size_t)t*BB + bidx)*256 + pcol] = acc[r] + bias;
      }
    }
  } else {
    // ---- gemm1 + fused scores
    int wv = (bid - 100)*4 + (threadIdx.x >> 6);
    if (wv >= NN/16) return;
    int row = wv*16 + (l & 15);
    int koff = (l >> 4)*8;
    short8v a[4];
#pragma unroll
    for (int k = 0; k < 4; ++k) a[k] = *(const short8v*)(x + (size_t)row*128 + k*32 + koff);
    int r0 = wv*16 + (l >> 4)*4;
    float ssA[4][4], sdA[4][4];
#pragma unroll
    for (int h = 0; h < 4; ++h)
#pragma unroll
      for (int r = 0; r < 4; ++r){ ssA[h][r] = 0.f; sdA[h][r] = 0.f; }
#pragma unroll
    for (int nt = 0; nt < 16; ++nt){
      f4v acc = {0.f,0.f,0.f,0.f};
#pragma unroll
      for (int k = 0; k < 4; ++k){
        short8v b = *(const short8v*)(W1 + (size_t)(nt*16 + (l & 15))*128 + k*32 + koff);
        acc = mfma16(a[k], b, acc);
      }
      int col = nt*16 + (l & 15);
      float asv = b2f(as1[col]), adv = b2f(ad1[col]);
      int h = nt >> 2;
#pragma unroll
      for (int r = 0; r < 4; ++r){
        h1[(size_t)(r0 + r)*256 + col] = f2b(acc[r]);
        ssA[h][r] += acc[r]*asv;
        sdA[h][r] += acc[r]*adv;
      }
    }
#pragma unroll
    for (int m = 1; m < 16; m <<= 1){
#pragma unroll
      for (int h = 0; h < 4; ++h)
#pragma unroll
        for (int r = 0; r < 4; ++r){
          ssA[h][r] += __shfl_xor(ssA[h][r], m, 64);
          sdA[h][r] += __shfl_xor(sdA[h][r], m, 64);
        }
    }
    if ((l & 15) == 0){
#pragma unroll
      for (int r = 0; r < 4; ++r){
        f4v os, od;
        os[0]=ssA[0][r]; os[1]=ssA[1][r]; os[2]=ssA[2][r]; os[3]=ssA[3][r];
        od[0]=sdA[0][r]; od[1]=sdA[1][r]; od[2]=sdA[2][r]; od[3]=sdA[3][r];
        *(f4v*)(a1s + (size_t)(r0 + r)*4) = os;
        *(f4v*)(a1d + (size_t)(r0 + r)*4) = od;
      }
    }
  }
}

// ---------------- F4: lstm (blocks 0..7) || fagg1 (blocks 8..12507) ----------------
union ShF4 {
  struct { int s_u[4][64]; float s_p[4][64][4]; } agg;   // 5.1 KB
  struct { short hl[2][16][76]; } rec;                   // 4.9 KB, stride 38 words (16-bank spread)
};

__global__ __launch_bounds__(256) void k_f1ls(const int* __restrict__ off, const int* __restrict__ csr,
                                              const short* __restrict__ h1, const float* __restrict__ a1s,
                                              const float* __restrict__ a1d, const short* __restrict__ b1,
                                              short* __restrict__ g1,
                                              const float* __restrict__ Xp,
                                              const short* __restrict__ WhhF, const short* __restrict__ WhhB,
                                              short* __restrict__ lout){
  __shared__ ShF4 sh;
  int bid = blockIdx.x;
  int tid = threadIdx.x;
  int l = tid & 63;
  if (bid < 8){
    // ---- lstm FIRST (dispatches immediately, overlaps fagg1)
    int bg = bid & 3, dir = bid >> 2;
    const short* Whh = dir ? WhhB : WhhF;
    const float* Xpd = Xp + (size_t)dir*TT*BB*256 + (size_t)bg*16*256;
    for (int i = tid; i < 16*64; i += 256) sh.rec.hl[0][i>>6][i&63] = 0;

    int w = tid >> 6;
    int c16 = l & 15;
    int koff = (l >> 4)*8;
    int r0 = (l >> 4)*4;
    int ch = (w>>1)*32 + (w&1)*16 + c16;
    short8v wb0[4], wb1[4];
#pragma unroll
    for (int j = 0; j < 4; ++j){
      int nt = w*4 + j;
      int jj = nt & 7, half = nt >> 3;
      int gate = jj & 3, chx = half*32 + (jj>>2)*16 + c16;
      int src = gate*64 + chx;
      wb0[j] = *(const short8v*)(Whh + (size_t)src*64 + koff);
      wb1[j] = *(const short8v*)(Whh + (size_t)src*64 + 32 + koff);
    }
    float creg[4] = {0.f,0.f,0.f,0.f};

    float xg[4][4];
    {
      int t0 = dir ? (TT-1) : 0;
      const float* xpb = Xpd + (size_t)t0*BB*256;
#pragma unroll
      for (int j = 0; j < 4; ++j){
        int p = (w*4 + j)*16 + c16;
#pragma unroll
        for (int r = 0; r < 4; ++r) xg[j][r] = xpb[(size_t)(r0 + r)*256 + p];
      }
    }

    int cur = 0;
    for (int s = 0; s < TT; ++s){
      int t = dir ? (TT - 1 - s) : s;
      __syncthreads();
      float xgn[4][4];
      if (s + 1 < TT){
        int tn = dir ? (TT - 2 - s) : (s + 1);
        const float* xpb = Xpd + (size_t)tn*BB*256;
#pragma unroll
        for (int j = 0; j < 4; ++j){
          int p = (w*4 + j)*16 + c16;
#pragma unroll
          for (int r = 0; r < 4; ++r) xgn[j][r] = xpb[(size_t)(r0 + r)*256 + p];
        }
      }
      short8v a0 = *(const short8v*)&sh.rec.hl[cur][c16][koff];
      short8v a1 = *(const short8v*)&sh.rec.hl[cur][c16][32 + koff];
      f4v acc[4];
#pragma unroll
      for (int j = 0; j < 4; ++j){
        f4v z = {0.f,0.f,0.f,0.f};
        z = mfma16(a0, wb0[j], z);
        z = mfma16(a1, wb1[j], z);
        acc[j] = z;
      }
      int nxt = cur ^ 1;
#pragma unroll
      for (int r = 0; r < 4; ++r){
        float gi = acc[0][r] + xg[0][r];
        float gf = acc[1][r] + xg[1][r];
        float gg = acc[2][r] + xg[2][r];
        float go = acc[3][r] + xg[3][r];
        float cn = fsig(gf)*creg[r] + fsig(gi)*ftanh(gg);
        creg[r] = cn;
        float hv = fsig(go)*ftanh(cn);
        short hb = f2b(hv);
        int row = r0 + r;
        sh.rec.hl[nxt][row][ch] = hb;
        lout[((size_t)(bg*16 + row)*TT + t)*128 + dir*64 + ch] = hb;
      }
#pragma unroll
      for (int j = 0; j < 4; ++j)
#pragma unroll
        for (int r = 0; r < 4; ++r) xg[j][r] = xgn[j][r];
      cur = nxt;
    }
  } else {
    // ---- fagg1: PhaseA lane=edge; PhaseB 2 rows/iter 16B/lane
    int v = (bid - 8)*4 + (tid >> 6);
    if (v >= NN) return;
    int w = tid >> 6;
    int rp  = l >> 5;
    int ch8 = (l & 31)*8;
    int hh  = (l & 31) >> 3;
    const f4v ad4 = *(const f4v*)(a1d + v*4);
    int e0 = off[v], e1 = off[v+1];
    float s0=0.f,s1=0.f,s2=0.f,s3=0.f;
    float acc[8] = {0.f,0.f,0.f,0.f,0.f,0.f,0.f,0.f};

    for (int base = e0; base < e1; base += 64){
      int nc = e1 - base; if (nc > 64) nc = 64;
      int u = v;
      float p0=0.f,p1=0.f,p2=0.f,p3=0.f;
      if (l < nc){
        u = csr[base + l];
        f4v as4 = *(const f4v*)(a1s + u*4);
        float t0 = as4[0]+ad4[0]; t0 = (t0>=0.f)?t0:0.2f*t0; p0 = __expf(fminf(t0,30.f));
        float t1 = as4[1]+ad4[1]; t1 = (t1>=0.f)?t1:0.2f*t1; p1 = __expf(fminf(t1,30.f));
        float t2 = as4[2]+ad4[2]; t2 = (t2>=0.f)?t2:0.2f*t2; p2 = __expf(fminf(t2,30.f));
        float t3 = as4[3]+ad4[3]; t3 = (t3>=0.f)?t3:0.2f*t3; p3 = __expf(fminf(t3,30.f));
      }
      sh.agg.s_u[w][l] = u;
      f4v pv; pv[0]=p0; pv[1]=p1; pv[2]=p2; pv[3]=p3;
      *(f4v*)&sh.agg.s_p[w][l][0] = pv;
      float q0=p0,q1=p1,q2=p2,q3=p3;
#pragma unroll
      for (int st = 1; st < 64; st <<= 1){
        q0 += __shfl_xor(q0, st, 64);
        q1 += __shfl_xor(q1, st, 64);
        q2 += __shfl_xor(q2, st, 64);
        q3 += __shfl_xor(q3, st, 64);
      }
      s0 += q0; s1 += q1; s2 += q2; s3 += q3;
      asm volatile("s_waitcnt lgkmcnt(0)" ::: "memory");
      int nit = (nc + 1) >> 1;
#pragma unroll 4
      for (int i = 0; i < nit; ++i){
        int idx = i*2 + rp;
        int   ui = sh.agg.s_u[w][idx];
        float pi = sh.agg.s_p[w][idx][hh];
        short8v hv = *(const short8v*)(h1 + (size_t)ui*256 + ch8);
#pragma unroll
        for (int j = 0; j < 8; ++j) acc[j] += pi*b2f(hv[j]);
      }
      asm volatile("s_waitcnt lgkmcnt(0)" ::: "memory");
    }
#pragma unroll
    for (int j = 0; j < 8; ++j) acc[j] += __shfl_xor(acc[j], 32, 64);
    if (l < 32){
      float mys = (hh==0)?s0:((hh==1)?s1:((hh==2)?s2:s3));
      float inv = 1.f/mys;
      short8v bb = *(const short8v*)(b1 + ch8);
      short8v o;
#pragma unroll
      for (int j = 0; j < 8; ++j) o[j] = f2b(fmaxf(acc[j]*inv + b2f(bb[j]), 0.f));
      *(short8v*)(g1 + (size_t)v*256 + ch8) = o;
    }
  }
}

// ---------------- F5: qkv (blocks 0..49) || gemm2 (blocks 50..831) ----------------
__global__ __launch_bounds__(256) void k_g2qk(const short* __restrict__ g1, const short* __restrict__ W2,
                                              const short* __restrict__ as2, const short* __restrict__ ad2,
                                              short* __restrict__ h2, float* __restrict__ a2s, float* __restrict__ a2d,
                                              const short* __restrict__ lout, const short* __restrict__ Winw,
                                              const short* __restrict__ Winb, short* __restrict__ qkv){
  int bid = blockIdx.x;
  int l = threadIdx.x & 63;
  if (bid < 50){
    int wv = bid*4 + (threadIdx.x >> 6);
    int row = wv*16 + (l & 15);
    int koff = (l >> 4)*8;
    short8v a[4];
#pragma unroll
    for (int k = 0; k < 4; ++k) a[k] = *(const short8v*)(lout + (size_t)row*128 + k*32 + koff);
    int r0 = wv*16 + (l >> 4)*4;
#pragma unroll
    for (int nt = 0; nt < 24; ++nt){
      f4v acc = {0.f,0.f,0.f,0.f};
#pragma unroll
      for (int k = 0; k < 4; ++k){
        short8v b = *(const short8v*)(Winw + (size_t)(nt*16 + (l & 15))*128 + k*32 + koff);
        acc = mfma16(a[k], b, acc);
      }
      int col = nt*16 + (l & 15);
      float bv = b2f(Winb[col]);
#pragma unroll
      for (int r = 0; r < 4; ++r) qkv[(size_t)(r0 + r)*384 + col] = f2b(acc[r] + bv);
    }
  } else {
    int wv = (bid - 50)*4 + (threadIdx.x >> 6);
    if (wv >= NN/16) return;
    int row = wv*16 + (l & 15);
    int koff = (l >> 4)*8;
    short8v a[8];
#pragma unroll
    for (int k = 0; k < 8; ++k) a[k] = *(const short8v*)(g1 + (size_t)row*256 + k*32 + koff);
    int r0 = wv*16 + (l >> 4)*4;
    float ss[4] = {0.f,0.f,0.f,0.f}, sd[4] = {0.f,0.f,0.f,0.f};
#pragma unroll
    for (int nt = 0; nt < 4; ++nt){
      f4v acc = {0.f,0.f,0.f,0.f};
#pragma unroll
      for (int k = 0; k < 8; ++k){
        short8v b = *(const short8v*)(W2 + (size_t)(nt*16 + (l & 15))*256 + k*32 + koff);
        acc = mfma16(a[k], b, acc);
      }
      int col = nt*16 + (l & 15);
      float asv = b2f(as2[col]), adv = b2f(ad2[col]);
#pragma unroll
      for (int r = 0; r < 4; ++r){
        h2[(size_t)(r0 + r)*64 + col] = f2b(acc[r]);
        ss[r] += acc[r]*asv;
        sd[r] += acc[r]*adv;
      }
    }
#pragma unroll
    for (int m = 1; m < 16; m <<= 1){
#pragma unroll
      for (int r = 0; r < 4; ++r){
        ss[r] += __shfl_xor(ss[r], m, 64);
        sd[r] += __shfl_xor(sd[r], m, 64);
      }
    }
    if ((l & 15) == 0){
#pragma unroll
      for (int r = 0; r < 4; ++r){
        a2s[r0 + r] = ss[r];
        a2d[r0 + r] = sd[r];
      }
    }
  }
}

// ---- fused alpha+gather layer 2: PhaseB 8 rows/iter, 16B/lane
__global__ __launch_bounds__(256) void k_fagg2(const int* __restrict__ off, const int* __restrict__ csr,
                                               const short* __restrict__ h2, const float* __restrict__ a2s,
                                               const float* __restrict__ a2d, const short* __restrict__ b2,
                                               short* __restrict__ g2){
  __shared__ int   s_u[4][64];
  __shared__ float s_p[4][64];
  int v = blockIdx.x*4 + (threadIdx.x >> 6);
  if (v >= NN) return;
  int w = threadIdx.x >> 6;
  int l = threadIdx.x & 63;
  int rp  = l >> 3;
  int ch8 = (l & 7)*8;
  float adst = a2d[v];
  int e0 = off[v], e1 = off[v+1];
  float s = 0.f;
  float acc[8] = {0.f,0.f,0.f,0.f,0.f,0.f,0.f,0.f};

  for (int base = e0; base < e1; base += 64){
    int nc = e1 - base; if (nc > 64) nc = 64;
    int u = v;
    float p = 0.f;
    if (l < nc){
      u = csr[base + l];
      float t = a2s[u] + adst;
      t = (t>=0.f)?t:0.2f*t;
      p = __expf(fminf(t,30.f));
    }
    s_u[w][l] = u;
    s_p[w][l] = p;
    float q = p;
#pragma unroll
    for (int st = 1; st < 64; st <<= 1) q += __shfl_xor(q, st, 64);
    s += q;
    asm volatile("s_waitcnt lgkmcnt(0)" ::: "memory");
    int nit = (nc + 7) >> 3;
#pragma unroll 2
    for (int i = 0; i < nit; ++i){
      int idx = i*8 + rp;
      int   ui = s_u[w][idx];
      float pi = s_p[w][idx];
      short8v hv = *(const short8v*)(h2 + (size_t)ui*64 + ch8);
#pragma unroll
      for (int j = 0; j < 8; ++j) acc[j] += pi*b2f(hv[j]);
    }
    asm volatile("s_waitcnt lgkmcnt(0)" ::: "memory");
  }
#pragma unroll
  for (int m = 8; m < 64; m <<= 1)
#pragma unroll
    for (int j = 0; j < 8; ++j) acc[j] += __shfl_xor(acc[j], m, 64);
  if (l < 8){
    float inv = 1.f/s;
    short8v bb = *(const short8v*)(b2 + ch8);
    short8v o;
#pragma unroll
    for (int j = 0; j < 8; ++j) o[j] = f2b(fmaxf(acc[j]*inv + b2f(bb[j]), 0.f));
    *(short8v*)(g2 + (size_t)v*64 + ch8) = o;
  }
}

// ---------------- F6: pool (blocks 0..511) || attn (blocks 512..767, 256-thread) ----------------
union ShF6 {
  struct { int seg[2]; float red[4][64]; } pl;
  struct { float kl[50][32]; float vl[50][32]; float ol[50][32]; } at;
};

__global__ __launch_bounds__(256) void k_plat(const short* __restrict__ g2, const int* __restrict__ batch,
                                              float* __restrict__ pool, float* __restrict__ cntf,
                                              const short* __restrict__ qkv, float* __restrict__ omean){
  __shared__ ShF6 sh;
  int bid = blockIdx.x;
  int tid = threadIdx.x;
  if (bid < 512){
    int split = bid & 7;
    int b = bid >> 3;
    if (tid == 0){
      int lo = 0, hi = NN;
      while (lo < hi){ int mid = (lo+hi)>>1; if (batch[mid] < b) lo = mid+1; else hi = mid; }
      sh.pl.seg[0] = lo;
      lo = 0; hi = NN;
      while (lo < hi){ int mid = (lo+hi)>>1; if (batch[mid] < b+1) lo = mid+1; else hi = mid; }
      sh.pl.seg[1] = lo;
    }
    __syncthreads();
    int lo = sh.pl.seg[0], hi = sh.pl.seg[1];
    int c = tid & 63;
    int rg = tid >> 6;
    float acc = 0.f;
    for (int r = lo + split*4 + rg; r < hi; r += 32)
      acc += b2f(g2[(size_t)r*64 + c]);
    sh.pl.red[rg][c] = acc;
    __syncthreads();
    if (tid < 64){
      float sum = sh.pl.red[0][tid] + sh.pl.red[1][tid] + sh.pl.red[2][tid] + sh.pl.red[3][tid];
      atomicAdd(&pool[b*HD + tid], sum);
    }
    if (split == 0 && tid == 0) cntf[b] = (float)(hi - lo);
  } else {
    int bb = bid - 512;
    int b = bb >> 2, h = bb & 3;
    for (int i = tid; i < 1600; i += 256){
      int t = i >> 5, c = i & 31;
      sh.at.kl[t][c] = b2f(qkv[((size_t)b*TT + t)*384 + 128 + h*32 + c]);
      sh.at.vl[t][c] = b2f(qkv[((size_t)b*TT + t)*384 + 256 + h*32 + c]);
    }
    __syncthreads();
    if (tid < TT){
      float q[32];
#pragma unroll
      for (int qq = 0; qq < 4; ++qq){
        short8v vq = *(const short8v*)(qkv + ((size_t)b*TT + tid)*384 + h*32 + qq*8);
#pragma unroll
        for (int j = 0; j < 8; ++j) q[qq*8 + j] = b2f(vq[j]);
      }
      float sc[50];
      float mx = -1e30f;
      const float scale = 0.17677669529663687f;
#pragma unroll
      for (int j = 0; j < 50; ++j){
        float d = 0.f;
#pragma unroll
        for (int c = 0; c < 32; ++c) d += q[c]*sh.at.kl[j][c];
        d *= scale;
        sc[j] = d;
        mx = fmaxf(mx, d);
      }
      float sum = 0.f;
#pragma unroll
      for (int j = 0; j < 50; ++j){ float p = __expf(sc[j] - mx); sc[j] = p; sum += p; }
      float inv = 1.f/sum;
      float o[32];
#pragma unroll
      for (int c = 0; c < 32; ++c) o[c] = 0.f;
#pragma unroll
      for (int j = 0; j < 50; ++j){
        float p = sc[j]*inv;
#pragma unroll
        for (int c = 0; c < 32; ++c) o[c] += p*sh.at.vl[j][c];
      }
#pragma unroll
      for (int c = 0; c < 32; ++c) sh.at.ol[tid][c] = o[c];
    }
    __syncthreads();
    if (tid < 32){
      float s = 0.f;
#pragma unroll
      for (int t = 0; t < TT; ++t) s += sh.at.ol[t][tid];
      omean[(size_t)b*128 + h*32 + tid] = s*0.02f;
    }
  }
}

// final: combined = [pool/cnt (64), omean @ Wout^T + bout (128)]; out = combined @ fc^T + fcb
__global__ __launch_bounds__(192) void k_final(const float* __restrict__ pool, const float* __restrict__ cntf,
                                               const float* __restrict__ omean,
                                               const short* __restrict__ Woutw, const short* __restrict__ Woutb,
                                               const short* __restrict__ fcw, const short* __restrict__ fcb,
                                               const int* __restrict__ flag, void* __restrict__ outv){
  int b = blockIdx.x;
  int tid = threadIdx.x;
  __shared__ float comb[192];
  if (tid < 64){
    float cnt = cntf[b];
    comb[tid] = pool[b*HD + tid] / fmaxf(cnt, 1.f);
  } else {
    int e = tid - 64;
    float s = b2f(Woutb[e]);
    for (int j = 0; j < 128; ++j) s += omean[(size_t)b*128 + j]*b2f(Woutw[e*128 + j]);
    comb[tid] = s;
  }
  __syncthreads();
  if (tid < 2){
    float s = b2f(fcb[tid]);
    for (int j = 0; j < 192; ++j) s += comb[j]*b2f(fcw[tid*192 + j]);
    if (*flag) ((short*)outv)[b*2 + tid] = f2b(s);
    else       ((float*)outv)[b*2 + tid] = s;
  }
}

extern "C" void kernel_launch(void* const* d_in, const int* in_sizes, int n_in,
                              void* d_out, int out_size, void* d_ws, size_t ws_size,
                              hipStream_t stream){
  const int* ei    = (const int*)d_in[1];
  const int* batch = (const int*)d_in[2];

  char* ws = (char*)d_ws;
  size_t o = 0;
  auto alloc = [&](size_t bytes)->char*{
    char* r = ws + o;
    o = (o + bytes + 255) & ~(size_t)255;
    return r;
  };
  short* arena = (short*)alloc((size_t)6787912*2);
  int*   flag  = (int*)alloc(256);
  char*  bufA  = alloc((size_t)NN*256*2);   // h1, later h2+g2
  char*  bufB  = alloc((size_t)NN*256*2);   // g1
  float* a1s  = (float*)alloc((size_t)NN*4*4);
  float* a1d  = (float*)alloc((size_t)NN*4*4);
  float* a2s  = (float*)alloc((size_t)NN*4);
  float* a2d  = (float*)alloc((size_t)NN*4);
  int*   deg  = (int*)alloc((size_t)NPAD*4);
  int*   offv = (int*)alloc((size_t)(NN+1)*4);
  int*   cur  = (int*)alloc((size_t)NN*4);
  int*   csr  = (int*)alloc((size_t)ETOT*4);
  float* pool = (float*)alloc((size_t)BB*HD*4);
  float* cntf = (float*)alloc((size_t)BB*4);
  float* Xp   = (float*)alloc((size_t)2*TT*BB*256*4);
  short* lout = (short*)alloc((size_t)BB*TT*128*2);
  short* qkv  = (short*)alloc((size_t)BB*TT*384*2);
  float* omean= (float*)alloc((size_t)BB*128*4);

  short* h1 = (short*)bufA;                       // [NN][256]
  short* h2 = (short*)bufA;                       // [NN][64] overlay (h1 dead after k_f1ls)
  short* g2 = (short*)(bufA + 12800000);          // [NN][64] bf16
  short* g1 = (short*)bufB;

  // arena views
  const short* xb    = arena + 0;
  const short* seqb  = arena + 6400000;
  const short* w1b   = arena + 6604800;
  const short* as1b  = arena + 6637568;
  const short* ad1b  = arena + 6637824;
  const short* b1b   = arena + 6638080;
  const short* w2b   = arena + 6638336;
  const short* as2b  = arena + 6654720;
  const short* ad2b  = arena + 6654784;
  const short* b2b   = arena + 6654848;
  const short* wihFb = arena + 6654912;
  const short* whhFb = arena + 6671296;
  const short* bihFb = arena + 6687680;
  const short* bhhFb = arena + 6687936;
  const short* wihBb = arena + 6688192;
  const short* whhBb = arena + 6704576;
  const short* bihBb = arena + 6720960;
  const short* bhhBb = arena + 6721216;
  const short* winwb = arena + 6721472;
  const short* winbb = arena + 6770624;
  const short* woutwb= arena + 6771008;
  const short* woutbb= arena + 6787392;
  const short* fcwb  = arena + 6787520;
  const short* fcbb  = arena + 6787904;

  Ptrs P;
  P.p[0]=d_in[0];  P.p[1]=d_in[3];  P.p[2]=d_in[4];  P.p[3]=d_in[5];
  P.p[4]=d_in[6];  P.p[5]=d_in[7];  P.p[6]=d_in[8];  P.p[7]=d_in[9];
  P.p[8]=d_in[10]; P.p[9]=d_in[11]; P.p[10]=d_in[12];P.p[11]=d_in[13];
  P.p[12]=d_in[14];P.p[13]=d_in[15];P.p[14]=d_in[16];P.p[15]=d_in[17];
  P.p[16]=d_in[18];P.p[17]=d_in[19];P.p[18]=d_in[20];P.p[19]=d_in[21];
  P.p[20]=d_in[22];P.p[21]=d_in[23];P.p[22]=d_in[24];P.p[23]=d_in[25];

  // convert (+deg/pool init, dtype detect)
  k_cvt<<<2048, 256, 0, stream>>>(P, arena, flag, deg, pool);

  // CSR build
  k_count<<<(EE+255)/256, 256, 0, stream>>>(ei, deg);
  k_scan<<<1, 1024, 0, stream>>>(deg, offv);
  k_self<<<(NN+255)/256, 256, 0, stream>>>(offv, cur, csr);
  k_scatter<<<(EE+255)/256, 256, 0, stream>>>(ei, cur, csr);

  // F3: LSTM pre-GEMM || GAT1 GEMM
  k_g1xp<<<882, 256, 0, stream>>>(xb, w1b, as1b, ad1b, h1, a1s, a1d,
                                  seqb, wihFb, bihFb, bhhFb, wihBb, bihBb, bhhBb, Xp);
  // F4: LSTM recurrence || GAT1 aggregate
  k_f1ls<<<12508, 256, 0, stream>>>(offv, csr, h1, a1s, a1d, b1b, g1,
                                    Xp, whhFb, whhBb, lout);
  // F5: attention QKV || GAT2 GEMM
  k_g2qk<<<832, 256, 0, stream>>>(g1, w2b, as2b, ad2b, h2, a2s, a2d,
                                  lout, winwb, winbb, qkv);
  // GAT2 aggregate
  k_fagg2<<<(NN+3)/4, 256, 0, stream>>>(offv, csr, h2, a2s, a2d, b2b, g2);
  // F6: pool || attention softmax+mean
  k_plat<<<768, 256, 0, stream>>>(g2, batch, pool, cntf, qkv, omean);

  // final
  k_final<<<BB, 192, 0, stream>>>(pool, cntf, omean, woutwb, woutbb, fcwb, fcbb, flag, d_out);
}